// Round 6
// baseline (1547.904 us; speedup 1.0000x reference)
//
#include <hip/hip_runtime.h>
#include <hip/hip_bf16.h>

#define N_NODES 40000
#define N_EDGES 640000
#define DIM_H 512
#define QKV_STRIDE 1536   // Q | K | V concatenated per node row

typedef __attribute__((ext_vector_type(8))) short bf16x8_t;  // 8 bf16 = 4 VGPR
typedef __attribute__((ext_vector_type(4))) float f32x4_t;   // MFMA acc
typedef __attribute__((ext_vector_type(8))) unsigned short u16x8_t;

static __device__ __forceinline__ unsigned short f2bf(float f) {
    __hip_bfloat16 h = __float2bfloat16(f);
    return *reinterpret_cast<unsigned short*>(&h);
}

// ---------------------------------------------------------------------------
// K0a: cast x (f32) -> xb (bf16). 8 elems/thread, 16B stores.
// 20,480,000 / (256*8) = 10000 blocks exact.
// ---------------------------------------------------------------------------
__global__ __launch_bounds__(256)
void cast_x(const float* __restrict__ x, unsigned short* __restrict__ xb)
{
    const size_t i = ((size_t)blockIdx.x * 256 + threadIdx.x) * 8;
    const float4 v0 = *(const float4*)&x[i];
    const float4 v1 = *(const float4*)&x[i + 4];
    u16x8_t o;
    o[0] = f2bf(v0.x); o[1] = f2bf(v0.y); o[2] = f2bf(v0.z); o[3] = f2bf(v0.w);
    o[4] = f2bf(v1.x); o[5] = f2bf(v1.y); o[6] = f2bf(v1.z); o[7] = f2bf(v1.w);
    *(u16x8_t*)&xb[i] = o;
}

// ---------------------------------------------------------------------------
// K0b: cast+transpose W[k][n] (f32) -> Wt[m][n][k] (bf16), m in {q,k,v}.
// 32x32 LDS tile, coalesced both sides. grid (16,16,3), 256 threads.
// ---------------------------------------------------------------------------
__global__ __launch_bounds__(256)
void cast_wt(const float* __restrict__ Wq,
             const float* __restrict__ Wk,
             const float* __restrict__ Wv,
             unsigned short* __restrict__ Wt)
{
    __shared__ float tile[32][33];
    const float* W = (blockIdx.z == 0) ? Wq : (blockIdx.z == 1) ? Wk : Wv;
    unsigned short* Wo = Wt + (size_t)blockIdx.z * 512 * 512;
    const int k0 = blockIdx.x * 32, n0 = blockIdx.y * 32;
    const int tx = threadIdx.x & 31, ty0 = threadIdx.x >> 5;  // 8 rows/pass
    #pragma unroll
    for (int p = 0; p < 4; ++p) {
        const int r = ty0 + p * 8;
        tile[r][tx] = W[(size_t)(k0 + r) * 512 + n0 + tx];
    }
    __syncthreads();
    #pragma unroll
    for (int p = 0; p < 4; ++p) {
        const int r = ty0 + p * 8;
        Wo[(size_t)(n0 + r) * 512 + k0 + tx] = f2bf(tile[tx][r]);
    }
}

// ---------------------------------------------------------------------------
// K1: QKV GEMM, bf16 MFMA (mfma_f32_16x16x32_bf16).
// C[n,0:512]=x@Wq, [512:1024]=x@Wk, [1024:1536]=x@Wv; bf16 out.
// 64x64 tile, BK=32, 256 threads = 4 waves, each wave one 32x32 quadrant
// (2x2 fragments of 16x16). Fragment maps (guide §3, m89-verified):
//   A: row=l&15, k=(l>>4)*8+j   B: col=l&15, k=(l>>4)*8+j
//   D: col=l&15, row=(l>>4)*4+j
// LDS rows padded 32->40 shorts (80B stride -> ~2-way b128 conflicts, free).
// grid (24 n-tiles fast, 625 m-tiles): consecutive blocks share the A panel.
// ---------------------------------------------------------------------------
__global__ __launch_bounds__(256)
void qkv_gemm_mfma(const unsigned short* __restrict__ xb,
                   const unsigned short* __restrict__ Wt,
                   unsigned short* __restrict__ qkv)
{
    __shared__ short Asub[64][40];
    __shared__ short Bsub[64][40];
    const int n0g = blockIdx.x * 64;
    const int m0  = blockIdx.y * 64;
    const int wsel = n0g >> 9;         // which of Wq/Wk/Wv
    const int nc0  = n0g & 511;        // col within that W
    const int tid = threadIdx.x;
    const int l = tid & 63;
    const int w = tid >> 6;
    const int wr = w >> 1, wc = w & 1; // wave's 32x32 quadrant
    const int lr = l & 15;
    const int lk = (l >> 4) * 8;       // k-offset of this lane's fragment
    const int sr = tid >> 2;           // staging: row 0..63
    const int sc = (tid & 3) * 8;      // staging: k-chunk 0/8/16/24

    f32x4_t acc[2][2];
    #pragma unroll
    for (int i = 0; i < 2; ++i)
        #pragma unroll
        for (int j = 0; j < 2; ++j)
            acc[i][j] = {0.f, 0.f, 0.f, 0.f};

    const unsigned short* Wbase = Wt + (size_t)wsel * 262144;

    for (int k0 = 0; k0 < 512; k0 += 32) {
        *(bf16x8_t*)&Asub[sr][sc] =
            *(const bf16x8_t*)&xb[(size_t)(m0 + sr) * 512 + k0 + sc];
        *(bf16x8_t*)&Bsub[sr][sc] =
            *(const bf16x8_t*)&Wbase[(size_t)(nc0 + sr) * 512 + k0 + sc];
        __syncthreads();
        const bf16x8_t a0 = *(const bf16x8_t*)&Asub[wr * 32 + lr][lk];
        const bf16x8_t a1 = *(const bf16x8_t*)&Asub[wr * 32 + 16 + lr][lk];
        const bf16x8_t b0 = *(const bf16x8_t*)&Bsub[wc * 32 + lr][lk];
        const bf16x8_t b1 = *(const bf16x8_t*)&Bsub[wc * 32 + 16 + lr][lk];
        acc[0][0] = __builtin_amdgcn_mfma_f32_16x16x32_bf16(a0, b0, acc[0][0], 0, 0, 0);
        acc[0][1] = __builtin_amdgcn_mfma_f32_16x16x32_bf16(a0, b1, acc[0][1], 0, 0, 0);
        acc[1][0] = __builtin_amdgcn_mfma_f32_16x16x32_bf16(a1, b0, acc[1][0], 0, 0, 0);
        acc[1][1] = __builtin_amdgcn_mfma_f32_16x16x32_bf16(a1, b1, acc[1][1], 0, 0, 0);
        __syncthreads();
    }

    #pragma unroll
    for (int fm = 0; fm < 2; ++fm)
        #pragma unroll
        for (int fn = 0; fn < 2; ++fn)
            #pragma unroll
            for (int j = 0; j < 4; ++j) {
                const int row = m0 + wr * 32 + fm * 16 + (l >> 4) * 4 + j;
                const int col = n0g + wc * 32 + fn * 16 + lr;
                qkv[(size_t)row * QKV_STRIDE + col] = f2bf(acc[fm][fn][j]);
            }
}

// ---------------------------------------------------------------------------
// K2: per-edge attention. One 64-lane wave per edge.
// lane = dim-within-head; 8 heads per lane (dims h*64+lane).
// Butterfly-reduce head dots, exp(clip), atomic scatter s*V -> wv (=d_out),
// s -> z[dst][h].
// ---------------------------------------------------------------------------
__global__ __launch_bounds__(256)
void edge_attn(const unsigned short* __restrict__ qkv,
               const int* __restrict__ ei,
               float* __restrict__ wv,
               float* __restrict__ z)
{
    const int e    = (int)((blockIdx.x * 256u + threadIdx.x) >> 6);
    const int lane = threadIdx.x & 63;
    if (e >= N_EDGES) return;   // wave-uniform
    const int src = ei[e];
    const int dst = ei[N_EDGES + e];

    const __hip_bfloat16* Qr = (const __hip_bfloat16*)qkv + (size_t)dst * QKV_STRIDE;
    const __hip_bfloat16* Kr = (const __hip_bfloat16*)qkv + (size_t)src * QKV_STRIDE + 512;
    const __hip_bfloat16* Vr = (const __hip_bfloat16*)qkv + (size_t)src * QKV_STRIDE + 1024;

    float p[8], vv[8];
    #pragma unroll
    for (int h = 0; h < 8; ++h) {
        p[h]  = __bfloat162float(Kr[h * 64 + lane]) * __bfloat162float(Qr[h * 64 + lane]);
        vv[h] = __bfloat162float(Vr[h * 64 + lane]);
    }
    #pragma unroll
    for (int off = 32; off > 0; off >>= 1) {
        #pragma unroll
        for (int h = 0; h < 8; ++h) p[h] += __shfl_xor(p[h], off, 64);
    }
    const float scale = 0.125f;  // 1/sqrt(64)
    float s[8];
    #pragma unroll
    for (int h = 0; h < 8; ++h)
        s[h] = expf(fminf(fmaxf(p[h] * scale, -5.0f), 5.0f));

    float* outrow = wv + (size_t)dst * 512;
    #pragma unroll
    for (int h = 0; h < 8; ++h)
        atomicAdd(&outrow[h * 64 + lane], s[h] * vv[h]);
    if (lane == 0) {
        #pragma unroll
        for (int h = 0; h < 8; ++h) atomicAdd(&z[(size_t)dst * 8 + h], s[h]);
    }
}

// ---------------------------------------------------------------------------
// K3: h = x + wv/(z+1e-6) in place over d_out, accumulate BN column stats.
// thread = column, 80 rows/block -> 500 blocks, 2 atomics/col/block.
// ---------------------------------------------------------------------------
__global__ __launch_bounds__(512)
void residual_stats(const float* __restrict__ x,
                    const float* __restrict__ z,
                    float* __restrict__ hbuf,
                    float* __restrict__ stats)
{
    const int c  = threadIdx.x;
    const int r0 = blockIdx.x * 80;
    float sum = 0.f, sq = 0.f;
    for (int i = 0; i < 80; ++i) {
        const int r = r0 + i;
        const float zz = z[(size_t)r * 8 + (c >> 6)];
        const size_t idx = (size_t)r * 512 + c;
        const float hv = x[idx] + hbuf[idx] / (zz + 1e-6f);
        hbuf[idx] = hv;
        sum += hv; sq += hv * hv;
    }
    atomicAdd(&stats[c], sum);
    atomicAdd(&stats[512 + c], sq);
}

// ---------------------------------------------------------------------------
// K4: BatchNorm normalize in place. float4/thread, 20000 blocks exact.
// ---------------------------------------------------------------------------
__global__ __launch_bounds__(256)
void bn_norm(float* __restrict__ hbuf,
             const float* __restrict__ stats,
             const float* __restrict__ gamma,
             const float* __restrict__ beta)
{
    const size_t i4 = ((size_t)blockIdx.x * 256 + threadIdx.x) * 4;
    const int c = (int)(i4 & 511);
    const float invN = 1.0f / 40000.0f;
    float4 h = *(float4*)&hbuf[i4];
    float hv[4] = {h.x, h.y, h.z, h.w};
    float o[4];
    #pragma unroll
    for (int j = 0; j < 4; ++j) {
        const float mean = stats[c + j] * invN;
        const float var  = stats[512 + c + j] * invN - mean * mean;
        o[j] = (hv[j] - mean) * rsqrtf(var + 1e-5f) * gamma[c + j] + beta[c + j];
    }
    float4 out = {o[0], o[1], o[2], o[3]};
    *(float4*)&hbuf[i4] = out;
}

extern "C" void kernel_launch(void* const* d_in, const int* in_sizes, int n_in,
                              void* d_out, int out_size, void* d_ws, size_t ws_size,
                              hipStream_t stream)
{
    const float* x     = (const float*)d_in[0];
    const int*   ei    = (const int*)d_in[1];
    // d_in[2] virt_h, d_in[3] virt_edge_index unused (use_virt_nodes=False)
    const float* Wq    = (const float*)d_in[4];
    const float* Wk    = (const float*)d_in[5];
    const float* Wv    = (const float*)d_in[6];
    const float* gamma = (const float*)d_in[7];
    const float* beta  = (const float*)d_in[8];
    float* out = (float*)d_out;

    char* ws = (char*)d_ws;
    unsigned short* qkv = (unsigned short*)ws;                 // 122,880,000 B
    float* z     = (float*)(ws + 122880000);                   //   1,280,000 B
    float* stats = (float*)(ws + 124160000);                   //       4,096 B
    unsigned short* xb = (unsigned short*)(ws + 124164096);    //  40,960,000 B
    unsigned short* Wt = (unsigned short*)(ws + 165124096);    //   1,572,864 B
    // total ws use: 166,696,960 B

    // zero accumulators (d_out doubles as the wV accumulator)
    hipMemsetAsync(d_out, 0, (size_t)N_NODES * 512 * sizeof(float), stream);
    hipMemsetAsync(z,     0, (size_t)N_NODES * 8 * sizeof(float), stream);
    hipMemsetAsync(stats, 0, 1024 * sizeof(float), stream);

    cast_x<<<10000, 256, 0, stream>>>(x, xb);
    cast_wt<<<dim3(16, 16, 3), 256, 0, stream>>>(Wq, Wk, Wv, Wt);
    qkv_gemm_mfma<<<dim3(24, 625), 256, 0, stream>>>(xb, Wt, qkv);
    edge_attn<<<160000, 256, 0, stream>>>(qkv, ei, out, z);
    residual_stats<<<500, 512, 0, stream>>>(x, z, out, stats);
    bn_norm<<<20000, 256, 0, stream>>>(out, stats, gamma, beta);
}

// Round 8
// 566.114 us; speedup vs baseline: 2.7343x; 2.7343x over previous
//
#include <hip/hip_runtime.h>
#include <hip/hip_bf16.h>

#define N_NODES 40000
#define N_EDGES 640000
#define DIM_H 512
#define QKV_STRIDE 1536   // Q | K | V concatenated per node row

typedef __attribute__((ext_vector_type(8))) short bf16x8_t;  // 8 bf16 = 4 VGPR
typedef __attribute__((ext_vector_type(4))) float f32x4_t;   // MFMA acc
typedef __attribute__((ext_vector_type(8))) unsigned short u16x8_t;

static __device__ __forceinline__ unsigned short f2bf(float f) {
    __hip_bfloat16 h = __float2bfloat16(f);
    return *reinterpret_cast<unsigned short*>(&h);
}
static __device__ __forceinline__ float bf2f(unsigned short u) {
    return __uint_as_float(((unsigned)u) << 16);
}

// ---------------------------------------------------------------------------
// K0a: cast x (f32) -> xb (bf16). 8 elems/thread. 10000 blocks exact.
// ---------------------------------------------------------------------------
__global__ __launch_bounds__(256)
void cast_x(const float* __restrict__ x, unsigned short* __restrict__ xb)
{
    const size_t i = ((size_t)blockIdx.x * 256 + threadIdx.x) * 8;
    const float4 v0 = *(const float4*)&x[i];
    const float4 v1 = *(const float4*)&x[i + 4];
    u16x8_t o;
    o[0] = f2bf(v0.x); o[1] = f2bf(v0.y); o[2] = f2bf(v0.z); o[3] = f2bf(v0.w);
    o[4] = f2bf(v1.x); o[5] = f2bf(v1.y); o[6] = f2bf(v1.z); o[7] = f2bf(v1.w);
    *(u16x8_t*)&xb[i] = o;
}

// ---------------------------------------------------------------------------
// K0b: cast+transpose W[k][n] -> Wt[m][n][k] (bf16). grid (16,16,3).
// ---------------------------------------------------------------------------
__global__ __launch_bounds__(256)
void cast_wt(const float* __restrict__ Wq,
             const float* __restrict__ Wk,
             const float* __restrict__ Wv,
             unsigned short* __restrict__ Wt)
{
    __shared__ float tile[32][33];
    const float* W = (blockIdx.z == 0) ? Wq : (blockIdx.z == 1) ? Wk : Wv;
    unsigned short* Wo = Wt + (size_t)blockIdx.z * 512 * 512;
    const int k0 = blockIdx.x * 32, n0 = blockIdx.y * 32;
    const int tx = threadIdx.x & 31, ty0 = threadIdx.x >> 5;
    #pragma unroll
    for (int p = 0; p < 4; ++p) {
        const int r = ty0 + p * 8;
        tile[r][tx] = W[(size_t)(k0 + r) * 512 + n0 + tx];
    }
    __syncthreads();
    #pragma unroll
    for (int p = 0; p < 4; ++p) {
        const int r = ty0 + p * 8;
        Wo[(size_t)(n0 + r) * 512 + k0 + tx] = f2bf(tile[tx][r]);
    }
}

// ---------------------------------------------------------------------------
// K1: QKV GEMM, bf16 MFMA (16x16x32). 64x64 tile, BK=32, 4 waves/block.
// Fragment maps (m89-verified): A row=l&15,k=(l>>4)*8+j; B col=l&15,same k;
// D col=l&15,row=(l>>4)*4+j.
// ---------------------------------------------------------------------------
__global__ __launch_bounds__(256)
void qkv_gemm_mfma(const unsigned short* __restrict__ xb,
                   const unsigned short* __restrict__ Wt,
                   unsigned short* __restrict__ qkv)
{
    __shared__ short Asub[64][40];
    __shared__ short Bsub[64][40];
    const int n0g = blockIdx.x * 64;
    const int m0  = blockIdx.y * 64;
    const int wsel = n0g >> 9;
    const int nc0  = n0g & 511;
    const int tid = threadIdx.x;
    const int l = tid & 63;
    const int w = tid >> 6;
    const int wr = w >> 1, wc = w & 1;
    const int lr = l & 15;
    const int lk = (l >> 4) * 8;
    const int sr = tid >> 2;
    const int sc = (tid & 3) * 8;

    f32x4_t acc[2][2];
    #pragma unroll
    for (int i = 0; i < 2; ++i)
        #pragma unroll
        for (int j = 0; j < 2; ++j)
            acc[i][j] = {0.f, 0.f, 0.f, 0.f};

    const unsigned short* Wbase = Wt + (size_t)wsel * 262144;

    for (int k0 = 0; k0 < 512; k0 += 32) {
        *(bf16x8_t*)&Asub[sr][sc] =
            *(const bf16x8_t*)&xb[(size_t)(m0 + sr) * 512 + k0 + sc];
        *(bf16x8_t*)&Bsub[sr][sc] =
            *(const bf16x8_t*)&Wbase[(size_t)(nc0 + sr) * 512 + k0 + sc];
        __syncthreads();
        const bf16x8_t a0 = *(const bf16x8_t*)&Asub[wr * 32 + lr][lk];
        const bf16x8_t a1 = *(const bf16x8_t*)&Asub[wr * 32 + 16 + lr][lk];
        const bf16x8_t b0 = *(const bf16x8_t*)&Bsub[wc * 32 + lr][lk];
        const bf16x8_t b1 = *(const bf16x8_t*)&Bsub[wc * 32 + 16 + lr][lk];
        acc[0][0] = __builtin_amdgcn_mfma_f32_16x16x32_bf16(a0, b0, acc[0][0], 0, 0, 0);
        acc[0][1] = __builtin_amdgcn_mfma_f32_16x16x32_bf16(a0, b1, acc[0][1], 0, 0, 0);
        acc[1][0] = __builtin_amdgcn_mfma_f32_16x16x32_bf16(a1, b0, acc[1][0], 0, 0, 0);
        acc[1][1] = __builtin_amdgcn_mfma_f32_16x16x32_bf16(a1, b1, acc[1][1], 0, 0, 0);
        __syncthreads();
    }

    #pragma unroll
    for (int fm = 0; fm < 2; ++fm)
        #pragma unroll
        for (int fn = 0; fn < 2; ++fn)
            #pragma unroll
            for (int j = 0; j < 4; ++j) {
                const int row = m0 + wr * 32 + fm * 16 + (l >> 4) * 4 + j;
                const int col = n0g + wc * 32 + fn * 16 + lr;
                qkv[(size_t)row * QKV_STRIDE + col] = f2bf(acc[fm][fn][j]);
            }
}

// ---------------------------------------------------------------------------
// CSR build (by dst). hist: 640K int atomics on 40K counters.
// ---------------------------------------------------------------------------
__global__ __launch_bounds__(256)
void csr_hist(const int* __restrict__ ei, int* __restrict__ counts)
{
    const int e = blockIdx.x * 256 + threadIdx.x;   // 2500 blocks exact
    atomicAdd(&counts[ei[N_EDGES + e]], 1);
}

// exclusive scan of 40000 counts -> row_ptr[0..40000]. 1 block, 1024 threads,
// 40 elems/thread (40960 >= 40000), Hillis-Steele over 1024 partials.
__global__ __launch_bounds__(1024)
void csr_scan(const int* __restrict__ counts, int* __restrict__ row_ptr)
{
    __shared__ int part[1024];
    const int t = threadIdx.x;
    const int base = t * 40;
    int s = 0;
    for (int i = 0; i < 40; ++i) {
        const int idx = base + i;
        if (idx < N_NODES) s += counts[idx];
    }
    part[t] = s;
    __syncthreads();
    for (int off = 1; off < 1024; off <<= 1) {
        int v = (t >= off) ? part[t - off] : 0;
        __syncthreads();
        part[t] += v;
        __syncthreads();
    }
    int run = (t == 0) ? 0 : part[t - 1];
    for (int i = 0; i < 40; ++i) {
        const int idx = base + i;
        if (idx < N_NODES) { row_ptr[idx] = run; run += counts[idx]; }
    }
    if (t == 0) row_ptr[N_NODES] = part[1023];
}

// scatter src ids into buckets. src < 40000 < 65536 -> u16 col.
__global__ __launch_bounds__(256)
void csr_scatter(const int* __restrict__ ei, const int* __restrict__ row_ptr,
                 int* __restrict__ cursor, unsigned short* __restrict__ col)
{
    const int e = blockIdx.x * 256 + threadIdx.x;   // 2500 blocks exact
    const int dst = ei[N_EDGES + e];
    const int pos = atomicAdd(&cursor[dst], 1);
    col[row_ptr[dst] + pos] = (unsigned short)ei[e];
}

// ---------------------------------------------------------------------------
// K2: per-dst aggregation (replaces atomic scatter). One wave per dst node,
// 4 waves/block -> 10000 blocks exact. Lane owns 8 contiguous dims; head =
// lane>>3 (8 lanes/head) -> per-head dot = 8 local FMA + 3 shfl_xor. All
// QKV reads are 16B/lane coalesced gathers (QKV = 123MB, L3-resident).
// Fuses: score, exp(clip), weighted-V accumulate, Z, divide, residual.
// One clean 2KB store per node - ZERO float atomics.
// ---------------------------------------------------------------------------
__global__ __launch_bounds__(256)
void aggregate(const unsigned short* __restrict__ qkv,
               const int* __restrict__ row_ptr,
               const unsigned short* __restrict__ col,
               const float* __restrict__ x,
               float* __restrict__ out)
{
    const int node = blockIdx.x * 4 + (threadIdx.x >> 6);
    const int lane = threadIdx.x & 63;
    const int d0 = lane * 8;

    const u16x8_t q8 = *(const u16x8_t*)(qkv + (size_t)node * QKV_STRIDE + d0);
    float q[8];
    #pragma unroll
    for (int j = 0; j < 8; ++j) q[j] = bf2f(q8[j]);

    float acc[8] = {0.f, 0.f, 0.f, 0.f, 0.f, 0.f, 0.f, 0.f};
    float zsum = 0.f;
    const int start = row_ptr[node];
    const int end   = row_ptr[node + 1];

    int e = start;
    for (; e + 2 <= end; e += 2) {          // 2-deep MLP on the gathers
        const int s0 = col[e], s1 = col[e + 1];
        const unsigned short* B0 = qkv + (size_t)s0 * QKV_STRIDE + d0;
        const unsigned short* B1 = qkv + (size_t)s1 * QKV_STRIDE + d0;
        const u16x8_t kk0 = *(const u16x8_t*)(B0 + 512);
        const u16x8_t vv0 = *(const u16x8_t*)(B0 + 1024);
        const u16x8_t kk1 = *(const u16x8_t*)(B1 + 512);
        const u16x8_t vv1 = *(const u16x8_t*)(B1 + 1024);
        float p0 = 0.f, p1 = 0.f;
        #pragma unroll
        for (int j = 0; j < 8; ++j) {
            p0 = fmaf(bf2f(kk0[j]), q[j], p0);
            p1 = fmaf(bf2f(kk1[j]), q[j], p1);
        }
        p0 += __shfl_xor(p0, 1, 64); p0 += __shfl_xor(p0, 2, 64); p0 += __shfl_xor(p0, 4, 64);
        p1 += __shfl_xor(p1, 1, 64); p1 += __shfl_xor(p1, 2, 64); p1 += __shfl_xor(p1, 4, 64);
        const float sc0 = __expf(fminf(fmaxf(p0 * 0.125f, -5.f), 5.f));
        const float sc1 = __expf(fminf(fmaxf(p1 * 0.125f, -5.f), 5.f));
        zsum += sc0 + sc1;
        #pragma unroll
        for (int j = 0; j < 8; ++j) {
            acc[j] = fmaf(sc0, bf2f(vv0[j]), acc[j]);
            acc[j] = fmaf(sc1, bf2f(vv1[j]), acc[j]);
        }
    }
    if (e < end) {
        const int s0 = col[e];
        const unsigned short* B0 = qkv + (size_t)s0 * QKV_STRIDE + d0;
        const u16x8_t kk0 = *(const u16x8_t*)(B0 + 512);
        const u16x8_t vv0 = *(const u16x8_t*)(B0 + 1024);
        float p0 = 0.f;
        #pragma unroll
        for (int j = 0; j < 8; ++j) p0 = fmaf(bf2f(kk0[j]), q[j], p0);
        p0 += __shfl_xor(p0, 1, 64); p0 += __shfl_xor(p0, 2, 64); p0 += __shfl_xor(p0, 4, 64);
        const float sc0 = __expf(fminf(fmaxf(p0 * 0.125f, -5.f), 5.f));
        zsum += sc0;
        #pragma unroll
        for (int j = 0; j < 8; ++j) acc[j] = fmaf(sc0, bf2f(vv0[j]), acc[j]);
    }

    const float invz = 1.0f / (zsum + 1e-6f);
    const float* xr = x + (size_t)node * 512 + d0;
    const float4 x0 = *(const float4*)xr;
    const float4 x1 = *(const float4*)(xr + 4);
    float4 o0, o1;
    o0.x = x0.x + acc[0] * invz; o0.y = x0.y + acc[1] * invz;
    o0.z = x0.z + acc[2] * invz; o0.w = x0.w + acc[3] * invz;
    o1.x = x1.x + acc[4] * invz; o1.y = x1.y + acc[5] * invz;
    o1.z = x1.z + acc[6] * invz; o1.w = x1.w + acc[7] * invz;
    float* orow = out + (size_t)node * 512 + d0;
    *(float4*)orow = o0;
    *(float4*)(orow + 4) = o1;
}

// ---------------------------------------------------------------------------
// K3: BN column stats over final h (in d_out). thread=col, 80 rows/block.
// ---------------------------------------------------------------------------
__global__ __launch_bounds__(512)
void stats_pass(const float* __restrict__ hbuf, float* __restrict__ stats)
{
    const int c  = threadIdx.x;
    const int r0 = blockIdx.x * 80;
    float sum = 0.f, sq = 0.f;
    for (int i = 0; i < 80; ++i) {
        const float hv = hbuf[(size_t)(r0 + i) * 512 + c];
        sum += hv; sq += hv * hv;
    }
    atomicAdd(&stats[c], sum);
    atomicAdd(&stats[512 + c], sq);
}

// ---------------------------------------------------------------------------
// K4: BatchNorm normalize in place. float4/thread, 20000 blocks exact.
// ---------------------------------------------------------------------------
__global__ __launch_bounds__(256)
void bn_norm(float* __restrict__ hbuf,
             const float* __restrict__ stats,
             const float* __restrict__ gamma,
             const float* __restrict__ beta)
{
    const size_t i4 = ((size_t)blockIdx.x * 256 + threadIdx.x) * 4;
    const int c = (int)(i4 & 511);
    const float invN = 1.0f / 40000.0f;
    float4 h = *(float4*)&hbuf[i4];
    float hv[4] = {h.x, h.y, h.z, h.w};
    float o[4];
    #pragma unroll
    for (int j = 0; j < 4; ++j) {
        const float mean = stats[c + j] * invN;
        const float var  = stats[512 + c + j] * invN - mean * mean;
        o[j] = (hv[j] - mean) * rsqrtf(var + 1e-5f) * gamma[c + j] + beta[c + j];
    }
    float4 out = {o[0], o[1], o[2], o[3]};
    *(float4*)&hbuf[i4] = out;
}

extern "C" void kernel_launch(void* const* d_in, const int* in_sizes, int n_in,
                              void* d_out, int out_size, void* d_ws, size_t ws_size,
                              hipStream_t stream)
{
    const float* x     = (const float*)d_in[0];
    const int*   ei    = (const int*)d_in[1];
    // d_in[2] virt_h, d_in[3] virt_edge_index unused (use_virt_nodes=False)
    const float* Wq    = (const float*)d_in[4];
    const float* Wk    = (const float*)d_in[5];
    const float* Wv    = (const float*)d_in[6];
    const float* gamma = (const float*)d_in[7];
    const float* beta  = (const float*)d_in[8];
    float* out = (float*)d_out;

    char* ws = (char*)d_ws;
    unsigned short* qkv    = (unsigned short*)ws;                  // 122,880,000
    unsigned short* xb     = (unsigned short*)(ws + 122880000);    //  40,960,000
    unsigned short* Wt     = (unsigned short*)(ws + 163840000);    //   1,572,864
    int*            counts = (int*)           (ws + 165412864);    //     160,000
    int*            cursor = (int*)           (ws + 165572864);    //     160,000
    int*            row_ptr= (int*)           (ws + 165732864);    //     160,016
    unsigned short* col    = (unsigned short*)(ws + 165892880);    //   1,280,000
    float*          stats  = (float*)         (ws + 167172880);    //       4,096
    // total ws use: 167,176,976 B

    hipMemsetAsync(counts, 0, 160000, stream);
    hipMemsetAsync(cursor, 0, 160000, stream);
    hipMemsetAsync(stats,  0, 4096,   stream);

    cast_x<<<10000, 256, 0, stream>>>(x, xb);
    cast_wt<<<dim3(16, 16, 3), 256, 0, stream>>>(Wq, Wk, Wv, Wt);
    csr_hist<<<2500, 256, 0, stream>>>(ei, counts);
    csr_scan<<<1, 1024, 0, stream>>>(counts, row_ptr);
    csr_scatter<<<2500, 256, 0, stream>>>(ei, row_ptr, cursor, col);
    qkv_gemm_mfma<<<dim3(24, 625), 256, 0, stream>>>(xb, Wt, qkv);
    aggregate<<<10000, 256, 0, stream>>>(qkv, row_ptr, col, x, out);
    stats_pass<<<500, 512, 0, stream>>>(out, stats);
    bn_norm<<<20000, 256, 0, stream>>>(out, stats, gamma, beta);
}

// Round 9
// 532.142 us; speedup vs baseline: 2.9088x; 1.0638x over previous
//
#include <hip/hip_runtime.h>
#include <hip/hip_bf16.h>

#define N_NODES 40000
#define M_PAD   40064            // 313 * 128
#define N_EDGES 640000
#define DIM_H 512
#define QKV_STRIDE 1536          // Q | K | V concatenated per node row

typedef __attribute__((ext_vector_type(8))) short bf16x8_t;  // 8 bf16 = 4 VGPR
typedef __attribute__((ext_vector_type(4))) float f32x4_t;   // MFMA acc
typedef __attribute__((ext_vector_type(8))) unsigned short u16x8_t;

static __device__ __forceinline__ unsigned short f2bf(float f) {
    __hip_bfloat16 h = __float2bfloat16(f);
    return *reinterpret_cast<unsigned short*>(&h);
}
static __device__ __forceinline__ float bf2f(unsigned short u) {
    return __uint_as_float(((unsigned)u) << 16);
}
// async global->LDS, 16B per lane. LDS dest = wave-uniform base + lane*16,
// which matches our linear layouts exactly (per-lane addr is linear in lane).
static __device__ __forceinline__ void gll16(const void* g, void* l) {
    __builtin_amdgcn_global_load_lds(
        (const __attribute__((address_space(1))) unsigned int*)g,
        (__attribute__((address_space(3))) unsigned int*)l, 16, 0, 0);
}

// ---------------------------------------------------------------------------
// K0a: cast x (f32) -> xb (bf16). 8 elems/thread. 10000 blocks exact.
// (pad rows 40000..40063 of xb are zeroed by a memset in the launcher)
// ---------------------------------------------------------------------------
__global__ __launch_bounds__(256)
void cast_x(const float* __restrict__ x, unsigned short* __restrict__ xb)
{
    const size_t i = ((size_t)blockIdx.x * 256 + threadIdx.x) * 8;
    const float4 v0 = *(const float4*)&x[i];
    const float4 v1 = *(const float4*)&x[i + 4];
    u16x8_t o;
    o[0] = f2bf(v0.x); o[1] = f2bf(v0.y); o[2] = f2bf(v0.z); o[3] = f2bf(v0.w);
    o[4] = f2bf(v1.x); o[5] = f2bf(v1.y); o[6] = f2bf(v1.z); o[7] = f2bf(v1.w);
    *(u16x8_t*)&xb[i] = o;
}

// ---------------------------------------------------------------------------
// K0b: cast+transpose W[k][n] -> Wt[m][n][k] (bf16). grid (16,16,3).
// ---------------------------------------------------------------------------
__global__ __launch_bounds__(256)
void cast_wt(const float* __restrict__ Wq,
             const float* __restrict__ Wk,
             const float* __restrict__ Wv,
             unsigned short* __restrict__ Wt)
{
    __shared__ float tile[32][33];
    const float* W = (blockIdx.z == 0) ? Wq : (blockIdx.z == 1) ? Wk : Wv;
    unsigned short* Wo = Wt + (size_t)blockIdx.z * 512 * 512;
    const int k0 = blockIdx.x * 32, n0 = blockIdx.y * 32;
    const int tx = threadIdx.x & 31, ty0 = threadIdx.x >> 5;
    #pragma unroll
    for (int p = 0; p < 4; ++p) {
        const int r = ty0 + p * 8;
        tile[r][tx] = W[(size_t)(k0 + r) * 512 + n0 + tx];
    }
    __syncthreads();
    #pragma unroll
    for (int p = 0; p < 4; ++p) {
        const int r = ty0 + p * 8;
        Wo[(size_t)(n0 + r) * 512 + k0 + tx] = f2bf(tile[tx][r]);
    }
}

// ---------------------------------------------------------------------------
// K1: QKV GEMM, bf16 MFMA 16x16x32. m97-style: 128x128 tile, BK=32,
// 256 thr / 4 waves (each wave a 64x64 quadrant = 4x4 fragments),
// linear LDS [row][32] staged via global_load_lds width=16.
// Fragment maps (m89-verified, same as validated 64^2 kernel):
//   A row=l&15, k=(l>>4)*8+j ; B col=l&15, same k ; D col=l&15, row=(l>>4)*4+j
// grid (12 n-tiles, 313 m-tiles) on M_PAD=40064 rows.
// ---------------------------------------------------------------------------
__global__ __launch_bounds__(256)
void qkv_gemm_mfma(const unsigned short* __restrict__ xb,
                   const unsigned short* __restrict__ Wt,
                   unsigned short* __restrict__ qkv)
{
    __shared__ short Asub[128 * 32];
    __shared__ short Bsub[128 * 32];
    const int n0g = blockIdx.x * 128;
    const int m0  = blockIdx.y * 128;
    const int wsel = n0g >> 9;          // which of Wq/Wk/Wv
    const int nc0  = n0g & 511;         // col offset inside that W (0/128/256/384)
    const int tid = threadIdx.x;
    const int l = tid & 63;
    const int w = tid >> 6;
    const int wr = w >> 1, wc = w & 1;  // wave quadrant (64x64)
    const int lr = l & 15;
    const int lk = (l >> 4) * 8;

    // staging: tile = 128 rows x 32 cols shorts = 512 x 16B; 2 chunks/thread
    const int idx0 = tid, idx1 = 256 + tid;
    const int ar0 = idx0 >> 2, ac0 = (idx0 & 3) * 8;
    const int ar1 = idx1 >> 2, ac1 = (idx1 & 3) * 8;

    const unsigned short* Abase = xb + (size_t)m0 * 512;
    const unsigned short* Bbase = Wt + (size_t)wsel * 262144 + (size_t)nc0 * 512;

    f32x4_t acc[4][4];
    #pragma unroll
    for (int i = 0; i < 4; ++i)
        #pragma unroll
        for (int j = 0; j < 4; ++j)
            acc[i][j] = {0.f, 0.f, 0.f, 0.f};

    for (int k0 = 0; k0 < 512; k0 += 32) {
        gll16(Abase + (size_t)ar0 * 512 + k0 + ac0, &Asub[idx0 * 8]);
        gll16(Abase + (size_t)ar1 * 512 + k0 + ac1, &Asub[idx1 * 8]);
        gll16(Bbase + (size_t)ar0 * 512 + k0 + ac0, &Bsub[idx0 * 8]);
        gll16(Bbase + (size_t)ar1 * 512 + k0 + ac1, &Bsub[idx1 * 8]);
        __syncthreads();                 // drains vmcnt before LDS reads
        bf16x8_t a[4], b[4];
        #pragma unroll
        for (int fm = 0; fm < 4; ++fm)
            a[fm] = *(const bf16x8_t*)&Asub[(wr * 64 + fm * 16 + lr) * 32 + lk];
        #pragma unroll
        for (int fn = 0; fn < 4; ++fn)
            b[fn] = *(const bf16x8_t*)&Bsub[(wc * 64 + fn * 16 + lr) * 32 + lk];
        #pragma unroll
        for (int fm = 0; fm < 4; ++fm)
            #pragma unroll
            for (int fn = 0; fn < 4; ++fn)
                acc[fm][fn] = __builtin_amdgcn_mfma_f32_16x16x32_bf16(
                                  a[fm], b[fn], acc[fm][fn], 0, 0, 0);
        __syncthreads();                 // all reads done before next overwrite
    }

    #pragma unroll
    for (int fm = 0; fm < 4; ++fm)
        #pragma unroll
        for (int fn = 0; fn < 4; ++fn)
            #pragma unroll
            for (int j = 0; j < 4; ++j) {
                const int row = m0 + wr * 64 + fm * 16 + (l >> 4) * 4 + j;
                const int col = n0g + wc * 64 + fn * 16 + lr;
                qkv[(size_t)row * QKV_STRIDE + col] = f2bf(acc[fm][fn][j]);
            }
}

// ---------------------------------------------------------------------------
// CSR build (by dst).
// ---------------------------------------------------------------------------
__global__ __launch_bounds__(256)
void csr_hist(const int* __restrict__ ei, int* __restrict__ counts)
{
    const int e = blockIdx.x * 256 + threadIdx.x;   // 2500 blocks exact
    atomicAdd(&counts[ei[N_EDGES + e]], 1);
}

__global__ __launch_bounds__(1024)
void csr_scan(const int* __restrict__ counts, int* __restrict__ row_ptr)
{
    __shared__ int part[1024];
    const int t = threadIdx.x;
    const int base = t * 40;
    int s = 0;
    for (int i = 0; i < 40; ++i) {
        const int idx = base + i;
        if (idx < N_NODES) s += counts[idx];
    }
    part[t] = s;
    __syncthreads();
    for (int off = 1; off < 1024; off <<= 1) {
        int v = (t >= off) ? part[t - off] : 0;
        __syncthreads();
        part[t] += v;
        __syncthreads();
    }
    int run = (t == 0) ? 0 : part[t - 1];
    for (int i = 0; i < 40; ++i) {
        const int idx = base + i;
        if (idx < N_NODES) { row_ptr[idx] = run; run += counts[idx]; }
    }
    if (t == 0) row_ptr[N_NODES] = part[1023];
}

__global__ __launch_bounds__(256)
void csr_scatter(const int* __restrict__ ei, const int* __restrict__ row_ptr,
                 int* __restrict__ cursor, unsigned short* __restrict__ col)
{
    const int e = blockIdx.x * 256 + threadIdx.x;   // 2500 blocks exact
    const int dst = ei[N_EDGES + e];
    const int pos = atomicAdd(&cursor[dst], 1);
    col[row_ptr[dst] + pos] = (unsigned short)ei[e];
}

// ---------------------------------------------------------------------------
// K2: per-dst aggregation. One wave per dst node, unroll 4 edges/iter with
// UNCONDITIONAL gathers (col padded past 640000 with node-0 ids -> loads are
// always safe) and branchless masking of the accumulation. 8 x 16B loads in
// flight per wave (2x round-8 MLP) at ~55 VGPR -> still 8 waves/SIMD.
// ---------------------------------------------------------------------------
__global__ __launch_bounds__(256)
void aggregate(const unsigned short* __restrict__ qkv,
               const int* __restrict__ row_ptr,
               const unsigned short* __restrict__ col,
               const float* __restrict__ x,
               float* __restrict__ out)
{
    const int node = blockIdx.x * 4 + (threadIdx.x >> 6);
    const int lane = threadIdx.x & 63;
    const int d0 = lane * 8;

    const u16x8_t q8 = *(const u16x8_t*)(qkv + (size_t)node * QKV_STRIDE + d0);
    float q[8];
    #pragma unroll
    for (int j = 0; j < 8; ++j) q[j] = bf2f(q8[j]);

    float acc[8] = {0.f, 0.f, 0.f, 0.f, 0.f, 0.f, 0.f, 0.f};
    float zsum = 0.f;
    const int start = row_ptr[node];
    const int end   = row_ptr[node + 1];

    for (int e = start; e < end; e += 4) {
        const int s0 = col[e], s1 = col[e + 1], s2 = col[e + 2], s3 = col[e + 3];
        const unsigned short* B0 = qkv + (size_t)s0 * QKV_STRIDE + d0;
        const unsigned short* B1 = qkv + (size_t)s1 * QKV_STRIDE + d0;
        const unsigned short* B2 = qkv + (size_t)s2 * QKV_STRIDE + d0;
        const unsigned short* B3 = qkv + (size_t)s3 * QKV_STRIDE + d0;
        const u16x8_t kk0 = *(const u16x8_t*)(B0 + 512);
        const u16x8_t vv0 = *(const u16x8_t*)(B0 + 1024);
        const u16x8_t kk1 = *(const u16x8_t*)(B1 + 512);
        const u16x8_t vv1 = *(const u16x8_t*)(B1 + 1024);
        const u16x8_t kk2 = *(const u16x8_t*)(B2 + 512);
        const u16x8_t vv2 = *(const u16x8_t*)(B2 + 1024);
        const u16x8_t kk3 = *(const u16x8_t*)(B3 + 512);
        const u16x8_t vv3 = *(const u16x8_t*)(B3 + 1024);
        float p0 = 0.f, p1 = 0.f, p2 = 0.f, p3 = 0.f;
        #pragma unroll
        for (int j = 0; j < 8; ++j) {
            p0 = fmaf(bf2f(kk0[j]), q[j], p0);
            p1 = fmaf(bf2f(kk1[j]), q[j], p1);
            p2 = fmaf(bf2f(kk2[j]), q[j], p2);
            p3 = fmaf(bf2f(kk3[j]), q[j], p3);
        }
        p0 += __shfl_xor(p0, 1, 64); p0 += __shfl_xor(p0, 2, 64); p0 += __shfl_xor(p0, 4, 64);
        p1 += __shfl_xor(p1, 1, 64); p1 += __shfl_xor(p1, 2, 64); p1 += __shfl_xor(p1, 4, 64);
        p2 += __shfl_xor(p2, 1, 64); p2 += __shfl_xor(p2, 2, 64); p2 += __shfl_xor(p2, 4, 64);
        p3 += __shfl_xor(p3, 1, 64); p3 += __shfl_xor(p3, 2, 64); p3 += __shfl_xor(p3, 4, 64);
        float sc0 =  __expf(fminf(fmaxf(p0 * 0.125f, -5.f), 5.f));
        float sc1 = (e + 1 < end) ? __expf(fminf(fmaxf(p1 * 0.125f, -5.f), 5.f)) : 0.f;
        float sc2 = (e + 2 < end) ? __expf(fminf(fmaxf(p2 * 0.125f, -5.f), 5.f)) : 0.f;
        float sc3 = (e + 3 < end) ? __expf(fminf(fmaxf(p3 * 0.125f, -5.f), 5.f)) : 0.f;
        zsum += (sc0 + sc1) + (sc2 + sc3);
        #pragma unroll
        for (int j = 0; j < 8; ++j) {
            float a = acc[j];
            a = fmaf(sc0, bf2f(vv0[j]), a);
            a = fmaf(sc1, bf2f(vv1[j]), a);
            a = fmaf(sc2, bf2f(vv2[j]), a);
            a = fmaf(sc3, bf2f(vv3[j]), a);
            acc[j] = a;
        }
    }

    const float invz = 1.0f / (zsum + 1e-6f);
    const float* xr = x + (size_t)node * 512 + d0;
    const float4 x0 = *(const float4*)xr;
    const float4 x1 = *(const float4*)(xr + 4);
    float4 o0, o1;
    o0.x = x0.x + acc[0] * invz; o0.y = x0.y + acc[1] * invz;
    o0.z = x0.z + acc[2] * invz; o0.w = x0.w + acc[3] * invz;
    o1.x = x1.x + acc[4] * invz; o1.y = x1.y + acc[5] * invz;
    o1.z = x1.z + acc[6] * invz; o1.w = x1.w + acc[7] * invz;
    float* orow = out + (size_t)node * 512 + d0;
    *(float4*)orow = o0;
    *(float4*)(orow + 4) = o1;
}

// ---------------------------------------------------------------------------
// K3: BN column stats over final h (in d_out). thread=col, 80 rows/block.
// ---------------------------------------------------------------------------
__global__ __launch_bounds__(512)
void stats_pass(const float* __restrict__ hbuf, float* __restrict__ stats)
{
    const int c  = threadIdx.x;
    const int r0 = blockIdx.x * 80;
    float sum = 0.f, sq = 0.f;
    for (int i = 0; i < 80; ++i) {
        const float hv = hbuf[(size_t)(r0 + i) * 512 + c];
        sum += hv; sq += hv * hv;
    }
    atomicAdd(&stats[c], sum);
    atomicAdd(&stats[512 + c], sq);
}

// ---------------------------------------------------------------------------
// K4: BatchNorm normalize in place. float4/thread, 20000 blocks exact.
// ---------------------------------------------------------------------------
__global__ __launch_bounds__(256)
void bn_norm(float* __restrict__ hbuf,
             const float* __restrict__ stats,
             const float* __restrict__ gamma,
             const float* __restrict__ beta)
{
    const size_t i4 = ((size_t)blockIdx.x * 256 + threadIdx.x) * 4;
    const int c = (int)(i4 & 511);
    const float invN = 1.0f / 40000.0f;
    float4 h = *(float4*)&hbuf[i4];
    float hv[4] = {h.x, h.y, h.z, h.w};
    float o[4];
    #pragma unroll
    for (int j = 0; j < 4; ++j) {
        const float mean = stats[c + j] * invN;
        const float var  = stats[512 + c + j] * invN - mean * mean;
        o[j] = (hv[j] - mean) * rsqrtf(var + 1e-5f) * gamma[c + j] + beta[c + j];
    }
    float4 out = {o[0], o[1], o[2], o[3]};
    *(float4*)&hbuf[i4] = out;
}

extern "C" void kernel_launch(void* const* d_in, const int* in_sizes, int n_in,
                              void* d_out, int out_size, void* d_ws, size_t ws_size,
                              hipStream_t stream)
{
    const float* x     = (const float*)d_in[0];
    const int*   ei    = (const int*)d_in[1];
    // d_in[2] virt_h, d_in[3] virt_edge_index unused (use_virt_nodes=False)
    const float* Wq    = (const float*)d_in[4];
    const float* Wk    = (const float*)d_in[5];
    const float* Wv    = (const float*)d_in[6];
    const float* gamma = (const float*)d_in[7];
    const float* beta  = (const float*)d_in[8];
    float* out = (float*)d_out;

    char* ws = (char*)d_ws;
    unsigned short* qkv    = (unsigned short*)ws;                  // 123,076,608 (M_PAD rows)
    unsigned short* xb     = (unsigned short*)(ws + 123076608);    //  41,025,536 (M_PAD rows)
    unsigned short* Wt     = (unsigned short*)(ws + 164102144);    //   1,572,864
    int*            counts = (int*)           (ws + 165675008);    //     160,000
    int*            cursor = (int*)           (ws + 165835008);    //     160,000
    int*            row_ptr= (int*)           (ws + 165995008);    //     160,016
    unsigned short* col    = (unsigned short*)(ws + 166155024);    //   1,280,032 (+16 pad ids)
    float*          stats  = (float*)         (ws + 167435056);    //       4,096
    // total ws use: 167,439,152 B

    hipMemsetAsync(counts, 0, 160000, stream);
    hipMemsetAsync(cursor, 0, 160000, stream);
    hipMemsetAsync(stats,  0, 4096,   stream);
    hipMemsetAsync(xb + (size_t)N_NODES * 512, 0, (size_t)(M_PAD - N_NODES) * 512 * 2, stream);
    hipMemsetAsync(col + N_EDGES, 0, 32, stream);   // pad ids -> node 0 (safe loads)

    cast_x<<<10000, 256, 0, stream>>>(x, xb);
    cast_wt<<<dim3(16, 16, 3), 256, 0, stream>>>(Wq, Wk, Wv, Wt);
    csr_hist<<<2500, 256, 0, stream>>>(ei, counts);
    csr_scan<<<1, 1024, 0, stream>>>(counts, row_ptr);
    csr_scatter<<<2500, 256, 0, stream>>>(ei, row_ptr, cursor, col);
    qkv_gemm_mfma<<<dim3(12, 313), 256, 0, stream>>>(xb, Wt, qkv);
    aggregate<<<10000, 256, 0, stream>>>(qkv, row_ptr, col, x, out);
    stats_pass<<<500, 512, 0, stream>>>(out, stats);
    bn_norm<<<20000, 256, 0, stream>>>(out, stats, gamma, beta);
}

// Round 10
// 517.992 us; speedup vs baseline: 2.9883x; 1.0273x over previous
//
#include <hip/hip_runtime.h>
#include <hip/hip_bf16.h>

#define N_NODES 40000
#define M_PAD   40064            // 313 * 128
#define N_EDGES 640000
#define DIM_H 512
#define QKV_STRIDE 1536          // Q | K | V concatenated per node row

typedef __attribute__((ext_vector_type(8))) short bf16x8_t;  // 8 bf16 = 4 VGPR
typedef __attribute__((ext_vector_type(4))) float f32x4_t;   // MFMA acc
typedef __attribute__((ext_vector_type(8))) unsigned short u16x8_t;

static __device__ __forceinline__ unsigned short f2bf(float f) {
    __hip_bfloat16 h = __float2bfloat16(f);
    return *reinterpret_cast<unsigned short*>(&h);
}
static __device__ __forceinline__ float bf2f(unsigned short u) {
    return __uint_as_float(((unsigned)u) << 16);
}
// async global->LDS, 16B per lane (linear LDS dest = uniform base + lane*16).
static __device__ __forceinline__ void gll16(const void* g, void* l) {
    __builtin_amdgcn_global_load_lds(
        (const __attribute__((address_space(1))) unsigned int*)g,
        (__attribute__((address_space(3))) unsigned int*)l, 16, 0, 0);
}

// ---------------------------------------------------------------------------
// K0a: cast x (f32) -> xb (bf16). 8 elems/thread. 10000 blocks exact.
// ---------------------------------------------------------------------------
__global__ __launch_bounds__(256)
void cast_x(const float* __restrict__ x, unsigned short* __restrict__ xb)
{
    const size_t i = ((size_t)blockIdx.x * 256 + threadIdx.x) * 8;
    const float4 v0 = *(const float4*)&x[i];
    const float4 v1 = *(const float4*)&x[i + 4];
    u16x8_t o;
    o[0] = f2bf(v0.x); o[1] = f2bf(v0.y); o[2] = f2bf(v0.z); o[3] = f2bf(v0.w);
    o[4] = f2bf(v1.x); o[5] = f2bf(v1.y); o[6] = f2bf(v1.z); o[7] = f2bf(v1.w);
    *(u16x8_t*)&xb[i] = o;
}

// ---------------------------------------------------------------------------
// K0b: cast+transpose W[k][n] -> Wt[m][n][k] (bf16). grid (16,16,3).
// ---------------------------------------------------------------------------
__global__ __launch_bounds__(256)
void cast_wt(const float* __restrict__ Wq,
             const float* __restrict__ Wk,
             const float* __restrict__ Wv,
             unsigned short* __restrict__ Wt)
{
    __shared__ float tile[32][33];
    const float* W = (blockIdx.z == 0) ? Wq : (blockIdx.z == 1) ? Wk : Wv;
    unsigned short* Wo = Wt + (size_t)blockIdx.z * 512 * 512;
    const int k0 = blockIdx.x * 32, n0 = blockIdx.y * 32;
    const int tx = threadIdx.x & 31, ty0 = threadIdx.x >> 5;
    #pragma unroll
    for (int p = 0; p < 4; ++p) {
        const int r = ty0 + p * 8;
        tile[r][tx] = W[(size_t)(k0 + r) * 512 + n0 + tx];
    }
    __syncthreads();
    #pragma unroll
    for (int p = 0; p < 4; ++p) {
        const int r = ty0 + p * 8;
        Wo[(size_t)(n0 + r) * 512 + k0 + tx] = f2bf(tile[tx][r]);
    }
}

// ---------------------------------------------------------------------------
// K1: QKV GEMM, bf16 MFMA 16x16x32. 128x128 tile, BK=32, 4 waves (64x64
// quadrant each, 4x4 fragments), linear LDS via global_load_lds width=16.
// grid (12 n-tiles, 313 m-tiles) on M_PAD rows.
// ---------------------------------------------------------------------------
__global__ __launch_bounds__(256)
void qkv_gemm_mfma(const unsigned short* __restrict__ xb,
                   const unsigned short* __restrict__ Wt,
                   unsigned short* __restrict__ qkv)
{
    __shared__ short Asub[128 * 32];
    __shared__ short Bsub[128 * 32];
    const int n0g = blockIdx.x * 128;
    const int m0  = blockIdx.y * 128;
    const int wsel = n0g >> 9;
    const int nc0  = n0g & 511;
    const int tid = threadIdx.x;
    const int l = tid & 63;
    const int w = tid >> 6;
    const int wr = w >> 1, wc = w & 1;
    const int lr = l & 15;
    const int lk = (l >> 4) * 8;

    const int idx0 = tid, idx1 = 256 + tid;
    const int ar0 = idx0 >> 2, ac0 = (idx0 & 3) * 8;
    const int ar1 = idx1 >> 2, ac1 = (idx1 & 3) * 8;

    const unsigned short* Abase = xb + (size_t)m0 * 512;
    const unsigned short* Bbase = Wt + (size_t)wsel * 262144 + (size_t)nc0 * 512;

    f32x4_t acc[4][4];
    #pragma unroll
    for (int i = 0; i < 4; ++i)
        #pragma unroll
        for (int j = 0; j < 4; ++j)
            acc[i][j] = {0.f, 0.f, 0.f, 0.f};

    for (int k0 = 0; k0 < 512; k0 += 32) {
        gll16(Abase + (size_t)ar0 * 512 + k0 + ac0, &Asub[idx0 * 8]);
        gll16(Abase + (size_t)ar1 * 512 + k0 + ac1, &Asub[idx1 * 8]);
        gll16(Bbase + (size_t)ar0 * 512 + k0 + ac0, &Bsub[idx0 * 8]);
        gll16(Bbase + (size_t)ar1 * 512 + k0 + ac1, &Bsub[idx1 * 8]);
        __syncthreads();
        bf16x8_t a[4], b[4];
        #pragma unroll
        for (int fm = 0; fm < 4; ++fm)
            a[fm] = *(const bf16x8_t*)&Asub[(wr * 64 + fm * 16 + lr) * 32 + lk];
        #pragma unroll
        for (int fn = 0; fn < 4; ++fn)
            b[fn] = *(const bf16x8_t*)&Bsub[(wc * 64 + fn * 16 + lr) * 32 + lk];
        #pragma unroll
        for (int fm = 0; fm < 4; ++fm)
            #pragma unroll
            for (int fn = 0; fn < 4; ++fn)
                acc[fm][fn] = __builtin_amdgcn_mfma_f32_16x16x32_bf16(
                                  a[fm], b[fn], acc[fm][fn], 0, 0, 0);
        __syncthreads();
    }

    #pragma unroll
    for (int fm = 0; fm < 4; ++fm)
        #pragma unroll
        for (int fn = 0; fn < 4; ++fn)
            #pragma unroll
            for (int j = 0; j < 4; ++j) {
                const int row = m0 + wr * 64 + fm * 16 + (l >> 4) * 4 + j;
                const int col = n0g + wc * 64 + fn * 16 + lr;
                qkv[(size_t)row * QKV_STRIDE + col] = f2bf(acc[fm][fn][j]);
            }
}

// ---------------------------------------------------------------------------
// CSR build (by dst).
// ---------------------------------------------------------------------------
__global__ __launch_bounds__(256)
void csr_hist(const int* __restrict__ ei, int* __restrict__ counts)
{
    const int e = blockIdx.x * 256 + threadIdx.x;   // 2500 blocks exact
    atomicAdd(&counts[ei[N_EDGES + e]], 1);
}

__global__ __launch_bounds__(1024)
void csr_scan(const int* __restrict__ counts, int* __restrict__ row_ptr)
{
    __shared__ int part[1024];
    const int t = threadIdx.x;
    const int base = t * 40;
    int s = 0;
    for (int i = 0; i < 40; ++i) {
        const int idx = base + i;
        if (idx < N_NODES) s += counts[idx];
    }
    part[t] = s;
    __syncthreads();
    for (int off = 1; off < 1024; off <<= 1) {
        int v = (t >= off) ? part[t - off] : 0;
        __syncthreads();
        part[t] += v;
        __syncthreads();
    }
    int run = (t == 0) ? 0 : part[t - 1];
    for (int i = 0; i < 40; ++i) {
        const int idx = base + i;
        if (idx < N_NODES) { row_ptr[idx] = run; run += counts[idx]; }
    }
    if (t == 0) row_ptr[N_NODES] = part[1023];
}

__global__ __launch_bounds__(256)
void csr_scatter(const int* __restrict__ ei, const int* __restrict__ row_ptr,
                 int* __restrict__ cursor, unsigned short* __restrict__ col)
{
    const int e = blockIdx.x * 256 + threadIdx.x;   // 2500 blocks exact
    const int dst = ei[N_EDGES + e];
    const int pos = atomicAdd(&cursor[dst], 1);
    col[row_ptr[dst] + pos] = (unsigned short)ei[e];
}

// ---------------------------------------------------------------------------
// K2: per-dst aggregation. Round-8 body (2-edge MLP, 28 VGPR, best measured)
// + NON-TEMPORAL x loads / out stores / col loads so the streaming traffic
// doesn't evict the 82MB K/V gather working set from L2/L3.
// Diagnosis (r9): FETCH 732MB vs 165MB unique -> L3 thrash by streams.
// ---------------------------------------------------------------------------
__global__ __launch_bounds__(256)
void aggregate(const unsigned short* __restrict__ qkv,
               const int* __restrict__ row_ptr,
               const unsigned short* __restrict__ col,
               const float* __restrict__ x,
               float* __restrict__ out)
{
    const int node = blockIdx.x * 4 + (threadIdx.x >> 6);
    const int lane = threadIdx.x & 63;
    const int d0 = lane * 8;

    const u16x8_t q8 = *(const u16x8_t*)(qkv + (size_t)node * QKV_STRIDE + d0);
    float q[8];
    #pragma unroll
    for (int j = 0; j < 8; ++j) q[j] = bf2f(q8[j]);

    float acc[8] = {0.f, 0.f, 0.f, 0.f, 0.f, 0.f, 0.f, 0.f};
    float zsum = 0.f;
    const int start = row_ptr[node];
    const int end   = row_ptr[node + 1];

    int e = start;
    for (; e + 2 <= end; e += 2) {
        const int s0 = __builtin_nontemporal_load(&col[e]);
        const int s1 = __builtin_nontemporal_load(&col[e + 1]);
        const unsigned short* B0 = qkv + (size_t)s0 * QKV_STRIDE + d0;
        const unsigned short* B1 = qkv + (size_t)s1 * QKV_STRIDE + d0;
        const u16x8_t kk0 = *(const u16x8_t*)(B0 + 512);
        const u16x8_t vv0 = *(const u16x8_t*)(B0 + 1024);
        const u16x8_t kk1 = *(const u16x8_t*)(B1 + 512);
        const u16x8_t vv1 = *(const u16x8_t*)(B1 + 1024);
        float p0 = 0.f, p1 = 0.f;
        #pragma unroll
        for (int j = 0; j < 8; ++j) {
            p0 = fmaf(bf2f(kk0[j]), q[j], p0);
            p1 = fmaf(bf2f(kk1[j]), q[j], p1);
        }
        p0 += __shfl_xor(p0, 1, 64); p0 += __shfl_xor(p0, 2, 64); p0 += __shfl_xor(p0, 4, 64);
        p1 += __shfl_xor(p1, 1, 64); p1 += __shfl_xor(p1, 2, 64); p1 += __shfl_xor(p1, 4, 64);
        const float sc0 = __expf(fminf(fmaxf(p0 * 0.125f, -5.f), 5.f));
        const float sc1 = __expf(fminf(fmaxf(p1 * 0.125f, -5.f), 5.f));
        zsum += sc0 + sc1;
        #pragma unroll
        for (int j = 0; j < 8; ++j) {
            acc[j] = fmaf(sc0, bf2f(vv0[j]), acc[j]);
            acc[j] = fmaf(sc1, bf2f(vv1[j]), acc[j]);
        }
    }
    if (e < end) {
        const int s0 = __builtin_nontemporal_load(&col[e]);
        const unsigned short* B0 = qkv + (size_t)s0 * QKV_STRIDE + d0;
        const u16x8_t kk0 = *(const u16x8_t*)(B0 + 512);
        const u16x8_t vv0 = *(const u16x8_t*)(B0 + 1024);
        float p0 = 0.f;
        #pragma unroll
        for (int j = 0; j < 8; ++j) p0 = fmaf(bf2f(kk0[j]), q[j], p0);
        p0 += __shfl_xor(p0, 1, 64); p0 += __shfl_xor(p0, 2, 64); p0 += __shfl_xor(p0, 4, 64);
        const float sc0 = __expf(fminf(fmaxf(p0 * 0.125f, -5.f), 5.f));
        zsum += sc0;
        #pragma unroll
        for (int j = 0; j < 8; ++j) acc[j] = fmaf(sc0, bf2f(vv0[j]), acc[j]);
    }

    const float invz = 1.0f / (zsum + 1e-6f);
    const float* xr = x + (size_t)node * 512 + d0;
    float xv[8];
    #pragma unroll
    for (int j = 0; j < 8; ++j) xv[j] = __builtin_nontemporal_load(xr + j);
    float* orow = out + (size_t)node * 512 + d0;
    #pragma unroll
    for (int j = 0; j < 8; ++j)
        __builtin_nontemporal_store(xv[j] + acc[j] * invz, orow + j);
}

// ---------------------------------------------------------------------------
// K3: BN column stats over final h (in d_out). thread=col, 80 rows/block.
// ---------------------------------------------------------------------------
__global__ __launch_bounds__(512)
void stats_pass(const float* __restrict__ hbuf, float* __restrict__ stats)
{
    const int c  = threadIdx.x;
    const int r0 = blockIdx.x * 80;
    float sum = 0.f, sq = 0.f;
    for (int i = 0; i < 80; ++i) {
        const float hv = hbuf[(size_t)(r0 + i) * 512 + c];
        sum += hv; sq += hv * hv;
    }
    atomicAdd(&stats[c], sum);
    atomicAdd(&stats[512 + c], sq);
}

// ---------------------------------------------------------------------------
// K4: BatchNorm normalize in place. float4/thread, 20000 blocks exact.
// ---------------------------------------------------------------------------
__global__ __launch_bounds__(256)
void bn_norm(float* __restrict__ hbuf,
             const float* __restrict__ stats,
             const float* __restrict__ gamma,
             const float* __restrict__ beta)
{
    const size_t i4 = ((size_t)blockIdx.x * 256 + threadIdx.x) * 4;
    const int c = (int)(i4 & 511);
    const float invN = 1.0f / 40000.0f;
    float4 h = *(float4*)&hbuf[i4];
    float hv[4] = {h.x, h.y, h.z, h.w};
    float o[4];
    #pragma unroll
    for (int j = 0; j < 4; ++j) {
        const float mean = stats[c + j] * invN;
        const float var  = stats[512 + c + j] * invN - mean * mean;
        o[j] = (hv[j] - mean) * rsqrtf(var + 1e-5f) * gamma[c + j] + beta[c + j];
    }
    float4 out = {o[0], o[1], o[2], o[3]};
    *(float4*)&hbuf[i4] = out;
}

extern "C" void kernel_launch(void* const* d_in, const int* in_sizes, int n_in,
                              void* d_out, int out_size, void* d_ws, size_t ws_size,
                              hipStream_t stream)
{
    const float* x     = (const float*)d_in[0];
    const int*   ei    = (const int*)d_in[1];
    // d_in[2] virt_h, d_in[3] virt_edge_index unused (use_virt_nodes=False)
    const float* Wq    = (const float*)d_in[4];
    const float* Wk    = (const float*)d_in[5];
    const float* Wv    = (const float*)d_in[6];
    const float* gamma = (const float*)d_in[7];
    const float* beta  = (const float*)d_in[8];
    float* out = (float*)d_out;

    char* ws = (char*)d_ws;
    unsigned short* qkv    = (unsigned short*)ws;                  // 123,076,608 (M_PAD rows)
    unsigned short* xb     = (unsigned short*)(ws + 123076608);    //  41,025,536 (M_PAD rows)
    unsigned short* Wt     = (unsigned short*)(ws + 164102144);    //   1,572,864
    int*            counts = (int*)           (ws + 165675008);    //     160,000
    int*            cursor = (int*)           (ws + 165835008);    //     160,000
    int*            row_ptr= (int*)           (ws + 165995008);    //     160,016
    unsigned short* col    = (unsigned short*)(ws + 166155024);    //   1,280,032 (+16 pad ids)
    float*          stats  = (float*)         (ws + 167435056);    //       4,096
    // total ws use: 167,439,152 B

    hipMemsetAsync(counts, 0, 160000, stream);
    hipMemsetAsync(cursor, 0, 160000, stream);
    hipMemsetAsync(stats,  0, 4096,   stream);
    hipMemsetAsync(xb + (size_t)N_NODES * 512, 0, (size_t)(M_PAD - N_NODES) * 512 * 2, stream);
    hipMemsetAsync(col + N_EDGES, 0, 32, stream);   // pad ids -> node 0 (safe loads)

    cast_x<<<10000, 256, 0, stream>>>(x, xb);
    cast_wt<<<dim3(16, 16, 3), 256, 0, stream>>>(Wq, Wk, Wv, Wt);
    csr_hist<<<2500, 256, 0, stream>>>(ei, counts);
    csr_scan<<<1, 1024, 0, stream>>>(counts, row_ptr);
    csr_scatter<<<2500, 256, 0, stream>>>(ei, row_ptr, cursor, col);
    qkv_gemm_mfma<<<dim3(12, 313), 256, 0, stream>>>(xb, Wt, qkv);
    aggregate<<<10000, 256, 0, stream>>>(qkv, row_ptr, col, x, out);
    stats_pass<<<500, 512, 0, stream>>>(out, stats);
    bn_norm<<<20000, 256, 0, stream>>>(out, stats, gamma, beta);
}

// Round 11
// 514.722 us; speedup vs baseline: 3.0073x; 1.0064x over previous
//
#include <hip/hip_runtime.h>
#include <hip/hip_bf16.h>

#define N_NODES 40000
#define M_PAD   40064            // 313 * 128
#define N_EDGES 640000
#define DIM_H 512
#define QKV_STRIDE 1536          // Q | K | V concatenated per node row

typedef __attribute__((ext_vector_type(8))) short bf16x8_t;  // 8 bf16 = 4 VGPR
typedef __attribute__((ext_vector_type(4))) float f32x4_t;   // MFMA acc
typedef __attribute__((ext_vector_type(8))) unsigned short u16x8_t;

static __device__ __forceinline__ unsigned short f2bf(float f) {
    __hip_bfloat16 h = __float2bfloat16(f);
    return *reinterpret_cast<unsigned short*>(&h);
}
static __device__ __forceinline__ float bf2f(unsigned short u) {
    return __uint_as_float(((unsigned)u) << 16);
}
// async global->LDS, 16B per lane (linear LDS dest = uniform base + lane*16).
static __device__ __forceinline__ void gll16(const void* g, void* l) {
    __builtin_amdgcn_global_load_lds(
        (const __attribute__((address_space(1))) unsigned int*)g,
        (__attribute__((address_space(3))) unsigned int*)l, 16, 0, 0);
}

// ---------------------------------------------------------------------------
// K0a: cast x (f32) -> xb (bf16). 8 elems/thread. 10000 blocks exact.
// ---------------------------------------------------------------------------
__global__ __launch_bounds__(256)
void cast_x(const float* __restrict__ x, unsigned short* __restrict__ xb)
{
    const size_t i = ((size_t)blockIdx.x * 256 + threadIdx.x) * 8;
    const float4 v0 = *(const float4*)&x[i];
    const float4 v1 = *(const float4*)&x[i + 4];
    u16x8_t o;
    o[0] = f2bf(v0.x); o[1] = f2bf(v0.y); o[2] = f2bf(v0.z); o[3] = f2bf(v0.w);
    o[4] = f2bf(v1.x); o[5] = f2bf(v1.y); o[6] = f2bf(v1.z); o[7] = f2bf(v1.w);
    *(u16x8_t*)&xb[i] = o;
}

// ---------------------------------------------------------------------------
// K0b: cast+transpose W[k][n] -> Wt[m][n][k] (bf16). grid (16,16,3).
// ---------------------------------------------------------------------------
__global__ __launch_bounds__(256)
void cast_wt(const float* __restrict__ Wq,
             const float* __restrict__ Wk,
             const float* __restrict__ Wv,
             unsigned short* __restrict__ Wt)
{
    __shared__ float tile[32][33];
    const float* W = (blockIdx.z == 0) ? Wq : (blockIdx.z == 1) ? Wk : Wv;
    unsigned short* Wo = Wt + (size_t)blockIdx.z * 512 * 512;
    const int k0 = blockIdx.x * 32, n0 = blockIdx.y * 32;
    const int tx = threadIdx.x & 31, ty0 = threadIdx.x >> 5;
    #pragma unroll
    for (int p = 0; p < 4; ++p) {
        const int r = ty0 + p * 8;
        tile[r][tx] = W[(size_t)(k0 + r) * 512 + n0 + tx];
    }
    __syncthreads();
    #pragma unroll
    for (int p = 0; p < 4; ++p) {
        const int r = ty0 + p * 8;
        Wo[(size_t)(n0 + r) * 512 + k0 + tx] = f2bf(tile[tx][r]);
    }
}

// ---------------------------------------------------------------------------
// K1: QKV GEMM, bf16 MFMA 16x16x32. 128x128 tile, BK=32, 4 waves (64x64
// quadrant each, 4x4 fragments), linear LDS via global_load_lds width=16.
// grid (12 n-tiles, 313 m-tiles) on M_PAD rows.
// ---------------------------------------------------------------------------
__global__ __launch_bounds__(256)
void qkv_gemm_mfma(const unsigned short* __restrict__ xb,
                   const unsigned short* __restrict__ Wt,
                   unsigned short* __restrict__ qkv)
{
    __shared__ short Asub[128 * 32];
    __shared__ short Bsub[128 * 32];
    const int n0g = blockIdx.x * 128;
    const int m0  = blockIdx.y * 128;
    const int wsel = n0g >> 9;
    const int nc0  = n0g & 511;
    const int tid = threadIdx.x;
    const int l = tid & 63;
    const int w = tid >> 6;
    const int wr = w >> 1, wc = w & 1;
    const int lr = l & 15;
    const int lk = (l >> 4) * 8;

    const int idx0 = tid, idx1 = 256 + tid;
    const int ar0 = idx0 >> 2, ac0 = (idx0 & 3) * 8;
    const int ar1 = idx1 >> 2, ac1 = (idx1 & 3) * 8;

    const unsigned short* Abase = xb + (size_t)m0 * 512;
    const unsigned short* Bbase = Wt + (size_t)wsel * 262144 + (size_t)nc0 * 512;

    f32x4_t acc[4][4];
    #pragma unroll
    for (int i = 0; i < 4; ++i)
        #pragma unroll
        for (int j = 0; j < 4; ++j)
            acc[i][j] = {0.f, 0.f, 0.f, 0.f};

    for (int k0 = 0; k0 < 512; k0 += 32) {
        gll16(Abase + (size_t)ar0 * 512 + k0 + ac0, &Asub[idx0 * 8]);
        gll16(Abase + (size_t)ar1 * 512 + k0 + ac1, &Asub[idx1 * 8]);
        gll16(Bbase + (size_t)ar0 * 512 + k0 + ac0, &Bsub[idx0 * 8]);
        gll16(Bbase + (size_t)ar1 * 512 + k0 + ac1, &Bsub[idx1 * 8]);
        __syncthreads();
        bf16x8_t a[4], b[4];
        #pragma unroll
        for (int fm = 0; fm < 4; ++fm)
            a[fm] = *(const bf16x8_t*)&Asub[(wr * 64 + fm * 16 + lr) * 32 + lk];
        #pragma unroll
        for (int fn = 0; fn < 4; ++fn)
            b[fn] = *(const bf16x8_t*)&Bsub[(wc * 64 + fn * 16 + lr) * 32 + lk];
        #pragma unroll
        for (int fm = 0; fm < 4; ++fm)
            #pragma unroll
            for (int fn = 0; fn < 4; ++fn)
                acc[fm][fn] = __builtin_amdgcn_mfma_f32_16x16x32_bf16(
                                  a[fm], b[fn], acc[fm][fn], 0, 0, 0);
        __syncthreads();
    }

    #pragma unroll
    for (int fm = 0; fm < 4; ++fm)
        #pragma unroll
        for (int fn = 0; fn < 4; ++fn)
            #pragma unroll
            for (int j = 0; j < 4; ++j) {
                const int row = m0 + wr * 64 + fm * 16 + (l >> 4) * 4 + j;
                const int col = n0g + wc * 64 + fn * 16 + lr;
                qkv[(size_t)row * QKV_STRIDE + col] = f2bf(acc[fm][fn][j]);
            }
}

// ---------------------------------------------------------------------------
// CSR build (by dst).
// ---------------------------------------------------------------------------
__global__ __launch_bounds__(256)
void csr_hist(const int* __restrict__ ei, int* __restrict__ counts)
{
    const int e = blockIdx.x * 256 + threadIdx.x;   // 2500 blocks exact
    atomicAdd(&counts[ei[N_EDGES + e]], 1);
}

__global__ __launch_bounds__(1024)
void csr_scan(const int* __restrict__ counts, int* __restrict__ row_ptr)
{
    __shared__ int part[1024];
    const int t = threadIdx.x;
    const int base = t * 40;
    int s = 0;
    for (int i = 0; i < 40; ++i) {
        const int idx = base + i;
        if (idx < N_NODES) s += counts[idx];
    }
    part[t] = s;
    __syncthreads();
    for (int off = 1; off < 1024; off <<= 1) {
        int v = (t >= off) ? part[t - off] : 0;
        __syncthreads();
        part[t] += v;
        __syncthreads();
    }
    int run = (t == 0) ? 0 : part[t - 1];
    for (int i = 0; i < 40; ++i) {
        const int idx = base + i;
        if (idx < N_NODES) { row_ptr[idx] = run; run += counts[idx]; }
    }
    if (t == 0) row_ptr[N_NODES] = part[1023];
}

__global__ __launch_bounds__(256)
void csr_scatter(const int* __restrict__ ei, const int* __restrict__ row_ptr,
                 int* __restrict__ cursor, unsigned short* __restrict__ col)
{
    const int e = blockIdx.x * 256 + threadIdx.x;   // 2500 blocks exact
    const int dst = ei[N_EDGES + e];
    const int pos = atomicAdd(&cursor[dst], 1);
    col[row_ptr[dst] + pos] = (unsigned short)ei[e];
}

// ---------------------------------------------------------------------------
// K2a: score pass. One wave per dst node. Gathers K ONLY (41MB working set,
// L3-resident without the x/out streams). Per edge: dot, reduce over the
// 8-lane head group, exp(clip); writes s[e][h] and accumulates z[node][h].
// Split rationale (r10): single-pass hot set 244MB ~ L3 size -> thrash
// (FETCH 683MB vs 165MB unique). Each pass's set now ~60MB.
// ---------------------------------------------------------------------------
__global__ __launch_bounds__(256)
void score_pass(const unsigned short* __restrict__ qkv,
                const int* __restrict__ row_ptr,
                const unsigned short* __restrict__ col,
                float* __restrict__ s,
                float* __restrict__ z)
{
    const int node = blockIdx.x * 4 + (threadIdx.x >> 6);
    const int lane = threadIdx.x & 63;
    const int d0 = lane * 8;
    const int g = lane >> 3;              // head of this lane's dims
    const bool wlead = (lane & 7) == 0;   // one writer per head group

    const u16x8_t q8 = *(const u16x8_t*)(qkv + (size_t)node * QKV_STRIDE + d0);
    float q[8];
    #pragma unroll
    for (int j = 0; j < 8; ++j) q[j] = bf2f(q8[j]);

    float zsum = 0.f;
    const int start = row_ptr[node];
    const int end   = row_ptr[node + 1];

    int e = start;
    for (; e + 2 <= end; e += 2) {
        const int s0 = col[e], s1 = col[e + 1];
        const u16x8_t kk0 = *(const u16x8_t*)(qkv + (size_t)s0 * QKV_STRIDE + 512 + d0);
        const u16x8_t kk1 = *(const u16x8_t*)(qkv + (size_t)s1 * QKV_STRIDE + 512 + d0);
        float p0 = 0.f, p1 = 0.f;
        #pragma unroll
        for (int j = 0; j < 8; ++j) {
            p0 = fmaf(bf2f(kk0[j]), q[j], p0);
            p1 = fmaf(bf2f(kk1[j]), q[j], p1);
        }
        p0 += __shfl_xor(p0, 1, 64); p0 += __shfl_xor(p0, 2, 64); p0 += __shfl_xor(p0, 4, 64);
        p1 += __shfl_xor(p1, 1, 64); p1 += __shfl_xor(p1, 2, 64); p1 += __shfl_xor(p1, 4, 64);
        const float sc0 = __expf(fminf(fmaxf(p0 * 0.125f, -5.f), 5.f));
        const float sc1 = __expf(fminf(fmaxf(p1 * 0.125f, -5.f), 5.f));
        zsum += sc0 + sc1;
        if (wlead) {
            s[(size_t)e * 8 + g]       = sc0;
            s[(size_t)(e + 1) * 8 + g] = sc1;
        }
    }
    if (e < end) {
        const int s0 = col[e];
        const u16x8_t kk0 = *(const u16x8_t*)(qkv + (size_t)s0 * QKV_STRIDE + 512 + d0);
        float p0 = 0.f;
        #pragma unroll
        for (int j = 0; j < 8; ++j) p0 = fmaf(bf2f(kk0[j]), q[j], p0);
        p0 += __shfl_xor(p0, 1, 64); p0 += __shfl_xor(p0, 2, 64); p0 += __shfl_xor(p0, 4, 64);
        const float sc0 = __expf(fminf(fmaxf(p0 * 0.125f, -5.f), 5.f));
        zsum += sc0;
        if (wlead) s[(size_t)e * 8 + g] = sc0;
    }
    if (wlead) z[(size_t)node * 8 + g] = zsum;
}

// ---------------------------------------------------------------------------
// K2b: PV pass. One wave per dst node. Gathers V ONLY (41MB working set) +
// streams s/x/out. Fuses divide + residual; one clean 2KB store per node.
// ---------------------------------------------------------------------------
__global__ __launch_bounds__(256)
void pv_pass(const unsigned short* __restrict__ qkv,
             const int* __restrict__ row_ptr,
             const unsigned short* __restrict__ col,
             const float* __restrict__ s,
             const float* __restrict__ z,
             const float* __restrict__ x,
             float* __restrict__ out)
{
    const int node = blockIdx.x * 4 + (threadIdx.x >> 6);
    const int lane = threadIdx.x & 63;
    const int d0 = lane * 8;
    const int g = lane >> 3;

    const float invz = 1.0f / (z[(size_t)node * 8 + g] + 1e-6f);

    float acc[8] = {0.f, 0.f, 0.f, 0.f, 0.f, 0.f, 0.f, 0.f};
    const int start = row_ptr[node];
    const int end   = row_ptr[node + 1];

    int e = start;
    for (; e + 2 <= end; e += 2) {
        const int s0 = col[e], s1 = col[e + 1];
        const float sc0 = s[(size_t)e * 8 + g];
        const float sc1 = s[(size_t)(e + 1) * 8 + g];
        const u16x8_t vv0 = *(const u16x8_t*)(qkv + (size_t)s0 * QKV_STRIDE + 1024 + d0);
        const u16x8_t vv1 = *(const u16x8_t*)(qkv + (size_t)s1 * QKV_STRIDE + 1024 + d0);
        #pragma unroll
        for (int j = 0; j < 8; ++j) {
            acc[j] = fmaf(sc0, bf2f(vv0[j]), acc[j]);
            acc[j] = fmaf(sc1, bf2f(vv1[j]), acc[j]);
        }
    }
    if (e < end) {
        const int s0 = col[e];
        const float sc0 = s[(size_t)e * 8 + g];
        const u16x8_t vv0 = *(const u16x8_t*)(qkv + (size_t)s0 * QKV_STRIDE + 1024 + d0);
        #pragma unroll
        for (int j = 0; j < 8; ++j) acc[j] = fmaf(sc0, bf2f(vv0[j]), acc[j]);
    }

    const float* xr = x + (size_t)node * 512 + d0;
    float xv[8];
    #pragma unroll
    for (int j = 0; j < 8; ++j) xv[j] = __builtin_nontemporal_load(xr + j);
    float* orow = out + (size_t)node * 512 + d0;
    #pragma unroll
    for (int j = 0; j < 8; ++j)
        __builtin_nontemporal_store(xv[j] + acc[j] * invz, orow + j);
}

// ---------------------------------------------------------------------------
// K3: BN column stats over final h (in d_out). thread=col, 80 rows/block.
// ---------------------------------------------------------------------------
__global__ __launch_bounds__(512)
void stats_pass(const float* __restrict__ hbuf, float* __restrict__ stats)
{
    const int c  = threadIdx.x;
    const int r0 = blockIdx.x * 80;
    float sum = 0.f, sq = 0.f;
    for (int i = 0; i < 80; ++i) {
        const float hv = hbuf[(size_t)(r0 + i) * 512 + c];
        sum += hv; sq += hv * hv;
    }
    atomicAdd(&stats[c], sum);
    atomicAdd(&stats[512 + c], sq);
}

// ---------------------------------------------------------------------------
// K4: BatchNorm normalize in place. float4/thread, 20000 blocks exact.
// ---------------------------------------------------------------------------
__global__ __launch_bounds__(256)
void bn_norm(float* __restrict__ hbuf,
             const float* __restrict__ stats,
             const float* __restrict__ gamma,
             const float* __restrict__ beta)
{
    const size_t i4 = ((size_t)blockIdx.x * 256 + threadIdx.x) * 4;
    const int c = (int)(i4 & 511);
    const float invN = 1.0f / 40000.0f;
    float4 h = *(float4*)&hbuf[i4];
    float hv[4] = {h.x, h.y, h.z, h.w};
    float o[4];
    #pragma unroll
    for (int j = 0; j < 4; ++j) {
        const float mean = stats[c + j] * invN;
        const float var  = stats[512 + c + j] * invN - mean * mean;
        o[j] = (hv[j] - mean) * rsqrtf(var + 1e-5f) * gamma[c + j] + beta[c + j];
    }
    float4 out = {o[0], o[1], o[2], o[3]};
    *(float4*)&hbuf[i4] = out;
}

extern "C" void kernel_launch(void* const* d_in, const int* in_sizes, int n_in,
                              void* d_out, int out_size, void* d_ws, size_t ws_size,
                              hipStream_t stream)
{
    const float* x     = (const float*)d_in[0];
    const int*   ei    = (const int*)d_in[1];
    // d_in[2] virt_h, d_in[3] virt_edge_index unused (use_virt_nodes=False)
    const float* Wq    = (const float*)d_in[4];
    const float* Wk    = (const float*)d_in[5];
    const float* Wv    = (const float*)d_in[6];
    const float* gamma = (const float*)d_in[7];
    const float* beta  = (const float*)d_in[8];
    float* out = (float*)d_out;

    char* ws = (char*)d_ws;
    unsigned short* qkv    = (unsigned short*)ws;                  // 123,076,608 (M_PAD rows)
    unsigned short* xb     = (unsigned short*)(ws + 123076608);    //  41,025,536 (M_PAD rows)
    unsigned short* Wt     = (unsigned short*)(ws + 164102144);    //   1,572,864
    int*            counts = (int*)           (ws + 165675008);    //     160,000
    int*            cursor = (int*)           (ws + 165835008);    //     160,000
    int*            row_ptr= (int*)           (ws + 165995008);    //     160,016
    unsigned short* col    = (unsigned short*)(ws + 166155024);    //   1,280,032
    float*          stats  = (float*)         (ws + 167435056);    //       4,096
    // s and z ALIAS the xb region: xb is dead after qkv_gemm_mfma's last read,
    // and score_pass runs after it on the same stream.
    float* s = (float*)(ws + 123076608);               // 20,480,000 B (< 24MB)
    float* z = (float*)(ws + 123076608 + 24000000);    //  1,280,000 B (< 41MB end)
    // total ws use: 167,439,152 B (unchanged from r9/r10)

    hipMemsetAsync(counts, 0, 160000, stream);
    hipMemsetAsync(cursor, 0, 160000, stream);
    hipMemsetAsync(stats,  0, 4096,   stream);
    hipMemsetAsync(xb + (size_t)N_NODES * 512, 0, (size_t)(M_PAD - N_NODES) * 512 * 2, stream);

    cast_x<<<10000, 256, 0, stream>>>(x, xb);
    cast_wt<<<dim3(16, 16, 3), 256, 0, stream>>>(Wq, Wk, Wv, Wt);
    csr_hist<<<2500, 256, 0, stream>>>(ei, counts);
    csr_scan<<<1, 1024, 0, stream>>>(counts, row_ptr);
    csr_scatter<<<2500, 256, 0, stream>>>(ei, row_ptr, cursor, col);
    qkv_gemm_mfma<<<dim3(12, 313), 256, 0, stream>>>(xb, Wt, qkv);
    score_pass<<<10000, 256, 0, stream>>>(qkv, row_ptr, col, s, z);
    pv_pass<<<10000, 256, 0, stream>>>(qkv, row_ptr, col, s, z, x, out);
    stats_pass<<<500, 512, 0, stream>>>(out, stats);
    bn_norm<<<20000, 256, 0, stream>>>(out, stats, gamma, beta);
}

// Round 12
// 461.626 us; speedup vs baseline: 3.3532x; 1.1150x over previous
//
#include <hip/hip_runtime.h>
#include <hip/hip_bf16.h>

#define N_NODES 40000
#define M_PAD   40064            // 313 * 128
#define N_EDGES 640000
#define DIM_H 512
#define QKV_STRIDE 1536          // Q | K | V concatenated per node row (u16 units)
#define ROW_BYTES 3072

typedef __attribute__((ext_vector_type(8))) short bf16x8_t;  // 8 bf16 = 4 VGPR
typedef __attribute__((ext_vector_type(4))) float f32x4_t;   // MFMA acc
typedef __attribute__((ext_vector_type(8))) unsigned short u16x8_t;

static __device__ __forceinline__ unsigned short f2bf(float f) {
    __hip_bfloat16 h = __float2bfloat16(f);
    return *reinterpret_cast<unsigned short*>(&h);
}
static __device__ __forceinline__ float bf2f(unsigned short u) {
    return __uint_as_float(((unsigned)u) << 16);
}
// async global->LDS, 16B per lane (linear LDS dest = uniform base + lane*16).
static __device__ __forceinline__ void gll16(const void* g, void* l) {
    __builtin_amdgcn_global_load_lds(
        (const __attribute__((address_space(1))) unsigned int*)g,
        (__attribute__((address_space(3))) unsigned int*)l, 16, 0, 0);
}

// ---------------------------------------------------------------------------
// K0a: cast x (f32) -> xb (bf16). 8 elems/thread. 10000 blocks exact.
// ---------------------------------------------------------------------------
__global__ __launch_bounds__(256)
void cast_x(const float* __restrict__ x, unsigned short* __restrict__ xb)
{
    const size_t i = ((size_t)blockIdx.x * 256 + threadIdx.x) * 8;
    const float4 v0 = *(const float4*)&x[i];
    const float4 v1 = *(const float4*)&x[i + 4];
    u16x8_t o;
    o[0] = f2bf(v0.x); o[1] = f2bf(v0.y); o[2] = f2bf(v0.z); o[3] = f2bf(v0.w);
    o[4] = f2bf(v1.x); o[5] = f2bf(v1.y); o[6] = f2bf(v1.z); o[7] = f2bf(v1.w);
    *(u16x8_t*)&xb[i] = o;
}

// ---------------------------------------------------------------------------
// K0b: cast+transpose W[k][n] -> Wt[m][n][k] (bf16). grid (16,16,3).
// ---------------------------------------------------------------------------
__global__ __launch_bounds__(256)
void cast_wt(const float* __restrict__ Wq,
             const float* __restrict__ Wk,
             const float* __restrict__ Wv,
             unsigned short* __restrict__ Wt)
{
    __shared__ float tile[32][33];
    const float* W = (blockIdx.z == 0) ? Wq : (blockIdx.z == 1) ? Wk : Wv;
    unsigned short* Wo = Wt + (size_t)blockIdx.z * 512 * 512;
    const int k0 = blockIdx.x * 32, n0 = blockIdx.y * 32;
    const int tx = threadIdx.x & 31, ty0 = threadIdx.x >> 5;
    #pragma unroll
    for (int p = 0; p < 4; ++p) {
        const int r = ty0 + p * 8;
        tile[r][tx] = W[(size_t)(k0 + r) * 512 + n0 + tx];
    }
    __syncthreads();
    #pragma unroll
    for (int p = 0; p < 4; ++p) {
        const int r = ty0 + p * 8;
        Wo[(size_t)(n0 + r) * 512 + k0 + tx] = f2bf(tile[tx][r]);
    }
}

// ---------------------------------------------------------------------------
// K1: QKV GEMM, bf16 MFMA 16x16x32. 128x128 tile, BK=32, 4 waves (64x64
// quadrant each, 4x4 fragments), linear LDS via global_load_lds width=16.
// grid (12 n-tiles, 313 m-tiles) on M_PAD rows.
// ---------------------------------------------------------------------------
__global__ __launch_bounds__(256)
void qkv_gemm_mfma(const unsigned short* __restrict__ xb,
                   const unsigned short* __restrict__ Wt,
                   unsigned short* __restrict__ qkv)
{
    __shared__ short Asub[128 * 32];
    __shared__ short Bsub[128 * 32];
    const int n0g = blockIdx.x * 128;
    const int m0  = blockIdx.y * 128;
    const int wsel = n0g >> 9;
    const int nc0  = n0g & 511;
    const int tid = threadIdx.x;
    const int l = tid & 63;
    const int w = tid >> 6;
    const int wr = w >> 1, wc = w & 1;
    const int lr = l & 15;
    const int lk = (l >> 4) * 8;

    const int idx0 = tid, idx1 = 256 + tid;
    const int ar0 = idx0 >> 2, ac0 = (idx0 & 3) * 8;
    const int ar1 = idx1 >> 2, ac1 = (idx1 & 3) * 8;

    const unsigned short* Abase = xb + (size_t)m0 * 512;
    const unsigned short* Bbase = Wt + (size_t)wsel * 262144 + (size_t)nc0 * 512;

    f32x4_t acc[4][4];
    #pragma unroll
    for (int i = 0; i < 4; ++i)
        #pragma unroll
        for (int j = 0; j < 4; ++j)
            acc[i][j] = {0.f, 0.f, 0.f, 0.f};

    for (int k0 = 0; k0 < 512; k0 += 32) {
        gll16(Abase + (size_t)ar0 * 512 + k0 + ac0, &Asub[idx0 * 8]);
        gll16(Abase + (size_t)ar1 * 512 + k0 + ac1, &Asub[idx1 * 8]);
        gll16(Bbase + (size_t)ar0 * 512 + k0 + ac0, &Bsub[idx0 * 8]);
        gll16(Bbase + (size_t)ar1 * 512 + k0 + ac1, &Bsub[idx1 * 8]);
        __syncthreads();
        bf16x8_t a[4], b[4];
        #pragma unroll
        for (int fm = 0; fm < 4; ++fm)
            a[fm] = *(const bf16x8_t*)&Asub[(wr * 64 + fm * 16 + lr) * 32 + lk];
        #pragma unroll
        for (int fn = 0; fn < 4; ++fn)
            b[fn] = *(const bf16x8_t*)&Bsub[(wc * 64 + fn * 16 + lr) * 32 + lk];
        #pragma unroll
        for (int fm = 0; fm < 4; ++fm)
            #pragma unroll
            for (int fn = 0; fn < 4; ++fn)
                acc[fm][fn] = __builtin_amdgcn_mfma_f32_16x16x32_bf16(
                                  a[fm], b[fn], acc[fm][fn], 0, 0, 0);
        __syncthreads();
    }

    #pragma unroll
    for (int fm = 0; fm < 4; ++fm)
        #pragma unroll
        for (int fn = 0; fn < 4; ++fn)
            #pragma unroll
            for (int j = 0; j < 4; ++j) {
                const int row = m0 + wr * 64 + fm * 16 + (l >> 4) * 4 + j;
                const int col = n0g + wc * 64 + fn * 16 + lr;
                qkv[(size_t)row * QKV_STRIDE + col] = f2bf(acc[fm][fn][j]);
            }
}

// ---------------------------------------------------------------------------
// CSR build (by dst).
// ---------------------------------------------------------------------------
__global__ __launch_bounds__(256)
void csr_hist(const int* __restrict__ ei, int* __restrict__ counts)
{
    const int e = blockIdx.x * 256 + threadIdx.x;   // 2500 blocks exact
    atomicAdd(&counts[ei[N_EDGES + e]], 1);
}

__global__ __launch_bounds__(1024)
void csr_scan(const int* __restrict__ counts, int* __restrict__ row_ptr)
{
    __shared__ int part[1024];
    const int t = threadIdx.x;
    const int base = t * 40;
    int s = 0;
    for (int i = 0; i < 40; ++i) {
        const int idx = base + i;
        if (idx < N_NODES) s += counts[idx];
    }
    part[t] = s;
    __syncthreads();
    for (int off = 1; off < 1024; off <<= 1) {
        int v = (t >= off) ? part[t - off] : 0;
        __syncthreads();
        part[t] += v;
        __syncthreads();
    }
    int run = (t == 0) ? 0 : part[t - 1];
    for (int i = 0; i < 40; ++i) {
        const int idx = base + i;
        if (idx < N_NODES) { row_ptr[idx] = run; run += counts[idx]; }
    }
    if (t == 0) row_ptr[N_NODES] = part[1023];
}

__global__ __launch_bounds__(256)
void csr_scatter(const int* __restrict__ ei, const int* __restrict__ row_ptr,
                 int* __restrict__ cursor, unsigned short* __restrict__ col)
{
    const int e = blockIdx.x * 256 + threadIdx.x;   // 2500 blocks exact
    const int dst = ei[N_EDGES + e];
    const int pos = atomicAdd(&cursor[dst], 1);
    col[row_ptr[dst] + pos] = (unsigned short)ei[e];
}

// ---------------------------------------------------------------------------
// KQ: in-place int8 quantization of K and V (per-row scale). One wave/node.
// K8 row (512B) is written into bytes [1024,1536) of the row (first half of
// the dead bf16-K area); V8 into [2048,2560). Same-wave loads complete
// before stores (data dependency); each wave owns its row exclusively.
// Rationale (r11): gather refetch is intrinsic (655MB demand vs 41MB set,
// L3 ~50% hit) -> halve the bytes instead of fighting cache policy.
// ---------------------------------------------------------------------------
__global__ __launch_bounds__(256)
void quant_kv(unsigned short* __restrict__ qkv,
              float* __restrict__ kscale, float* __restrict__ vscale)
{
    const int node = blockIdx.x * 4 + (threadIdx.x >> 6);
    const int lane = threadIdx.x & 63;
    unsigned short* row = qkv + (size_t)node * QKV_STRIDE;

    const u16x8_t kk = *(const u16x8_t*)(row + 512 + lane * 8);
    const u16x8_t vv = *(const u16x8_t*)(row + 1024 + lane * 8);
    float kf[8], vf[8];
    float kamax = 0.f, vamax = 0.f;
    #pragma unroll
    for (int j = 0; j < 8; ++j) {
        kf[j] = bf2f(kk[j]); kamax = fmaxf(kamax, fabsf(kf[j]));
        vf[j] = bf2f(vv[j]); vamax = fmaxf(vamax, fabsf(vf[j]));
    }
    #pragma unroll
    for (int off = 1; off < 64; off <<= 1) {
        kamax = fmaxf(kamax, __shfl_xor(kamax, off, 64));
        vamax = fmaxf(vamax, __shfl_xor(vamax, off, 64));
    }
    const float kinv = (kamax > 0.f) ? 127.0f / kamax : 0.f;
    const float vinv = (vamax > 0.f) ? 127.0f / vamax : 0.f;

    unsigned int klo = 0, khi = 0, vlo = 0, vhi = 0;
    #pragma unroll
    for (int j = 0; j < 4; ++j) {
        const int kq = (int)rintf(kf[j] * kinv);
        const int vq = (int)rintf(vf[j] * vinv);
        klo |= ((unsigned)(unsigned char)(signed char)kq) << (8 * j);
        vlo |= ((unsigned)(unsigned char)(signed char)vq) << (8 * j);
    }
    #pragma unroll
    for (int j = 4; j < 8; ++j) {
        const int kq = (int)rintf(kf[j] * kinv);
        const int vq = (int)rintf(vf[j] * vinv);
        khi |= ((unsigned)(unsigned char)(signed char)kq) << (8 * (j - 4));
        vhi |= ((unsigned)(unsigned char)(signed char)vq) << (8 * (j - 4));
    }
    uint2 kp; kp.x = klo; kp.y = khi;
    uint2 vp; vp.x = vlo; vp.y = vhi;
    char* rowb = (char*)row;
    *(uint2*)(rowb + 1024 + lane * 8) = kp;
    *(uint2*)(rowb + 2048 + lane * 8) = vp;
    if (lane == 0) {
        kscale[node] = kamax * (1.0f / 127.0f);
        vscale[node] = vamax * (1.0f / 127.0f);
    }
}

// ---------------------------------------------------------------------------
// K2a: score pass. One wave per dst node; gathers K8 (int8, 512B/row,
// 20.5MB unique set). Per edge: int8 dot (f32 math), head-group reduce,
// apply kscale[src], exp(clip); writes s[e][h], z[node][h].
// ---------------------------------------------------------------------------
__global__ __launch_bounds__(256)
void score_pass(const unsigned short* __restrict__ qkv,
                const float* __restrict__ kscale,
                const int* __restrict__ row_ptr,
                const unsigned short* __restrict__ col,
                float* __restrict__ s,
                float* __restrict__ z)
{
    const int node = blockIdx.x * 4 + (threadIdx.x >> 6);
    const int lane = threadIdx.x & 63;
    const int g = lane >> 3;
    const bool wlead = (lane & 7) == 0;
    const int d0b = lane * 8;                    // byte offset of this lane's 8 dims

    const u16x8_t q8 = *(const u16x8_t*)(qkv + (size_t)node * QKV_STRIDE + lane * 8);
    float q[8];
    #pragma unroll
    for (int j = 0; j < 8; ++j) q[j] = bf2f(q8[j]);

    const char* qb = (const char*)qkv;
    float zsum = 0.f;
    const int start = row_ptr[node];
    const int end   = row_ptr[node + 1];

    int e = start;
    for (; e + 2 <= end; e += 2) {
        const int s0 = col[e], s1 = col[e + 1];
        const uint2 k0 = *(const uint2*)(qb + (size_t)s0 * ROW_BYTES + 1024 + d0b);
        const uint2 k1 = *(const uint2*)(qb + (size_t)s1 * ROW_BYTES + 1024 + d0b);
        const signed char* c0 = (const signed char*)&k0;
        const signed char* c1 = (const signed char*)&k1;
        float p0 = 0.f, p1 = 0.f;
        #pragma unroll
        for (int j = 0; j < 8; ++j) {
            p0 = fmaf((float)c0[j], q[j], p0);
            p1 = fmaf((float)c1[j], q[j], p1);
        }
        p0 += __shfl_xor(p0, 1, 64); p0 += __shfl_xor(p0, 2, 64); p0 += __shfl_xor(p0, 4, 64);
        p1 += __shfl_xor(p1, 1, 64); p1 += __shfl_xor(p1, 2, 64); p1 += __shfl_xor(p1, 4, 64);
        p0 *= kscale[s0] * 0.125f;
        p1 *= kscale[s1] * 0.125f;
        const float sc0 = __expf(fminf(fmaxf(p0, -5.f), 5.f));
        const float sc1 = __expf(fminf(fmaxf(p1, -5.f), 5.f));
        zsum += sc0 + sc1;
        if (wlead) {
            s[(size_t)e * 8 + g]       = sc0;
            s[(size_t)(e + 1) * 8 + g] = sc1;
        }
    }
    if (e < end) {
        const int s0 = col[e];
        const uint2 k0 = *(const uint2*)(qb + (size_t)s0 * ROW_BYTES + 1024 + d0b);
        const signed char* c0 = (const signed char*)&k0;
        float p0 = 0.f;
        #pragma unroll
        for (int j = 0; j < 8; ++j) p0 = fmaf((float)c0[j], q[j], p0);
        p0 += __shfl_xor(p0, 1, 64); p0 += __shfl_xor(p0, 2, 64); p0 += __shfl_xor(p0, 4, 64);
        p0 *= kscale[s0] * 0.125f;
        const float sc0 = __expf(fminf(fmaxf(p0, -5.f), 5.f));
        zsum += sc0;
        if (wlead) s[(size_t)e * 8 + g] = sc0;
    }
    if (wlead) z[(size_t)node * 8 + g] = zsum;
}

// ---------------------------------------------------------------------------
// K2b: PV pass. One wave per dst node; gathers V8 (int8, 20.5MB set) +
// streams s/x/out. vscale[src] folded into the score weight.
// ---------------------------------------------------------------------------
__global__ __launch_bounds__(256)
void pv_pass(const unsigned short* __restrict__ qkv,
             const float* __restrict__ vscale,
             const int* __restrict__ row_ptr,
             const unsigned short* __restrict__ col,
             const float* __restrict__ s,
             const float* __restrict__ z,
             const float* __restrict__ x,
             float* __restrict__ out)
{
    const int node = blockIdx.x * 4 + (threadIdx.x >> 6);
    const int lane = threadIdx.x & 63;
    const int g = lane >> 3;
    const int d0b = lane * 8;

    const float invz = 1.0f / (z[(size_t)node * 8 + g] + 1e-6f);
    const char* qb = (const char*)qkv;

    float acc[8] = {0.f, 0.f, 0.f, 0.f, 0.f, 0.f, 0.f, 0.f};
    const int start = row_ptr[node];
    const int end   = row_ptr[node + 1];

    int e = start;
    for (; e + 2 <= end; e += 2) {
        const int s0 = col[e], s1 = col[e + 1];
        const float scv0 = s[(size_t)e * 8 + g] * vscale[s0];
        const float scv1 = s[(size_t)(e + 1) * 8 + g] * vscale[s1];
        const uint2 v0 = *(const uint2*)(qb + (size_t)s0 * ROW_BYTES + 2048 + d0b);
        const uint2 v1 = *(const uint2*)(qb + (size_t)s1 * ROW_BYTES + 2048 + d0b);
        const signed char* c0 = (const signed char*)&v0;
        const signed char* c1 = (const signed char*)&v1;
        #pragma unroll
        for (int j = 0; j < 8; ++j) {
            acc[j] = fmaf(scv0, (float)c0[j], acc[j]);
            acc[j] = fmaf(scv1, (float)c1[j], acc[j]);
        }
    }
    if (e < end) {
        const int s0 = col[e];
        const float scv0 = s[(size_t)e * 8 + g] * vscale[s0];
        const uint2 v0 = *(const uint2*)(qb + (size_t)s0 * ROW_BYTES + 2048 + d0b);
        const signed char* c0 = (const signed char*)&v0;
        #pragma unroll
        for (int j = 0; j < 8; ++j) acc[j] = fmaf(scv0, (float)c0[j], acc[j]);
    }

    const float* xr = x + (size_t)node * 512 + lane * 8;
    float xv[8];
    #pragma unroll
    for (int j = 0; j < 8; ++j) xv[j] = __builtin_nontemporal_load(xr + j);
    float* orow = out + (size_t)node * 512 + lane * 8;
    #pragma unroll
    for (int j = 0; j < 8; ++j)
        __builtin_nontemporal_store(xv[j] + acc[j] * invz, orow + j);
}

// ---------------------------------------------------------------------------
// K3: BN column stats over final h (in d_out). thread=col, 80 rows/block.
// ---------------------------------------------------------------------------
__global__ __launch_bounds__(512)
void stats_pass(const float* __restrict__ hbuf, float* __restrict__ stats)
{
    const int c  = threadIdx.x;
    const int r0 = blockIdx.x * 80;
    float sum = 0.f, sq = 0.f;
    for (int i = 0; i < 80; ++i) {
        const float hv = hbuf[(size_t)(r0 + i) * 512 + c];
        sum += hv; sq += hv * hv;
    }
    atomicAdd(&stats[c], sum);
    atomicAdd(&stats[512 + c], sq);
}

// ---------------------------------------------------------------------------
// K4: BatchNorm normalize in place. float4/thread, 20000 blocks exact.
// ---------------------------------------------------------------------------
__global__ __launch_bounds__(256)
void bn_norm(float* __restrict__ hbuf,
             const float* __restrict__ stats,
             const float* __restrict__ gamma,
             const float* __restrict__ beta)
{
    const size_t i4 = ((size_t)blockIdx.x * 256 + threadIdx.x) * 4;
    const int c = (int)(i4 & 511);
    const float invN = 1.0f / 40000.0f;
    float4 h = *(float4*)&hbuf[i4];
    float hv[4] = {h.x, h.y, h.z, h.w};
    float o[4];
    #pragma unroll
    for (int j = 0; j < 4; ++j) {
        const float mean = stats[c + j] * invN;
        const float var  = stats[512 + c + j] * invN - mean * mean;
        o[j] = (hv[j] - mean) * rsqrtf(var + 1e-5f) * gamma[c + j] + beta[c + j];
    }
    float4 out = {o[0], o[1], o[2], o[3]};
    *(float4*)&hbuf[i4] = out;
}

extern "C" void kernel_launch(void* const* d_in, const int* in_sizes, int n_in,
                              void* d_out, int out_size, void* d_ws, size_t ws_size,
                              hipStream_t stream)
{
    const float* x     = (const float*)d_in[0];
    const int*   ei    = (const int*)d_in[1];
    // d_in[2] virt_h, d_in[3] virt_edge_index unused (use_virt_nodes=False)
    const float* Wq    = (const float*)d_in[4];
    const float* Wk    = (const float*)d_in[5];
    const float* Wv    = (const float*)d_in[6];
    const float* gamma = (const float*)d_in[7];
    const float* beta  = (const float*)d_in[8];
    float* out = (float*)d_out;

    char* ws = (char*)d_ws;
    unsigned short* qkv    = (unsigned short*)ws;                  // 123,076,608 (M_PAD rows)
    unsigned short* xb     = (unsigned short*)(ws + 123076608);    //  41,025,536 (M_PAD rows)
    unsigned short* Wt     = (unsigned short*)(ws + 164102144);    //   1,572,864
    int*            counts = (int*)           (ws + 165675008);    //     160,000
    int*            cursor = (int*)           (ws + 165835008);    //     160,000
    int*            row_ptr= (int*)           (ws + 165995008);    //     160,016
    unsigned short* col    = (unsigned short*)(ws + 166155024);    //   1,280,032
    float*          stats  = (float*)         (ws + 167435056);    //       4,096
    // s, z, kscale, vscale ALIAS the xb region (dead after qkv_gemm_mfma):
    float* s      = (float*)(ws + 123076608);               // 20,480,000 B
    float* z      = (float*)(ws + 123076608 + 24000000);    //  1,280,000 B
    float* kscale = (float*)(ws + 123076608 + 26000000);    //    160,000 B
    float* vscale = (float*)(ws + 123076608 + 26160000);    //    160,000 B
    // total ws use: 167,439,152 B (unchanged)

    hipMemsetAsync(counts, 0, 160000, stream);
    hipMemsetAsync(cursor, 0, 160000, stream);
    hipMemsetAsync(stats,  0, 4096,   stream);
    hipMemsetAsync(xb + (size_t)N_NODES * 512, 0, (size_t)(M_PAD - N_NODES) * 512 * 2, stream);

    cast_x<<<10000, 256, 0, stream>>>(x, xb);
    cast_wt<<<dim3(16, 16, 3), 256, 0, stream>>>(Wq, Wk, Wv, Wt);
    csr_hist<<<2500, 256, 0, stream>>>(ei, counts);
    csr_scan<<<1, 1024, 0, stream>>>(counts, row_ptr);
    csr_scatter<<<2500, 256, 0, stream>>>(ei, row_ptr, cursor, col);
    qkv_gemm_mfma<<<dim3(12, 313), 256, 0, stream>>>(xb, Wt, qkv);
    quant_kv<<<10000, 256, 0, stream>>>(qkv, kscale, vscale);
    score_pass<<<10000, 256, 0, stream>>>(qkv, kscale, row_ptr, col, s, z);
    pv_pass<<<10000, 256, 0, stream>>>(qkv, vscale, row_ptr, col, s, z, x, out);
    stats_pass<<<500, 512, 0, stream>>>(out, stats);
    bn_norm<<<20000, 256, 0, stream>>>(out, stats, gamma, beta);
}

// Round 13
// 451.122 us; speedup vs baseline: 3.4312x; 1.0233x over previous
//
#include <hip/hip_runtime.h>
#include <hip/hip_bf16.h>

#define N_NODES 40000
#define M_PAD   40064            // 313 * 128
#define N_EDGES 640000
#define DIM_H 512
#define QKV_STRIDE 1536          // Q | K | V concatenated per node row (u16 units)
#define ROW_BYTES 3072

typedef __attribute__((ext_vector_type(8))) short bf16x8_t;  // 8 bf16 = 4 VGPR
typedef __attribute__((ext_vector_type(4))) float f32x4_t;   // MFMA acc
typedef __attribute__((ext_vector_type(8))) unsigned short u16x8_t;

static __device__ __forceinline__ unsigned short f2bf(float f) {
    __hip_bfloat16 h = __float2bfloat16(f);
    return *reinterpret_cast<unsigned short*>(&h);
}
static __device__ __forceinline__ float bf2f(unsigned short u) {
    return __uint_as_float(((unsigned)u) << 16);
}
// async global->LDS, 16B per lane (linear LDS dest = uniform base + lane*16).
static __device__ __forceinline__ void gll16(const void* g, void* l) {
    __builtin_amdgcn_global_load_lds(
        (const __attribute__((address_space(1))) unsigned int*)g,
        (__attribute__((address_space(3))) unsigned int*)l, 16, 0, 0);
}

// ---------------------------------------------------------------------------
// K0a: cast x (f32) -> xb (bf16). 8 elems/thread. 10000 blocks exact.
// ---------------------------------------------------------------------------
__global__ __launch_bounds__(256)
void cast_x(const float* __restrict__ x, unsigned short* __restrict__ xb)
{
    const size_t i = ((size_t)blockIdx.x * 256 + threadIdx.x) * 8;
    const float4 v0 = *(const float4*)&x[i];
    const float4 v1 = *(const float4*)&x[i + 4];
    u16x8_t o;
    o[0] = f2bf(v0.x); o[1] = f2bf(v0.y); o[2] = f2bf(v0.z); o[3] = f2bf(v0.w);
    o[4] = f2bf(v1.x); o[5] = f2bf(v1.y); o[6] = f2bf(v1.z); o[7] = f2bf(v1.w);
    *(u16x8_t*)&xb[i] = o;
}

// ---------------------------------------------------------------------------
// K0b: cast+transpose W[k][n] -> Wt[m][n][k] (bf16). grid (16,16,3).
// ---------------------------------------------------------------------------
__global__ __launch_bounds__(256)
void cast_wt(const float* __restrict__ Wq,
             const float* __restrict__ Wk,
             const float* __restrict__ Wv,
             unsigned short* __restrict__ Wt)
{
    __shared__ float tile[32][33];
    const float* W = (blockIdx.z == 0) ? Wq : (blockIdx.z == 1) ? Wk : Wv;
    unsigned short* Wo = Wt + (size_t)blockIdx.z * 512 * 512;
    const int k0 = blockIdx.x * 32, n0 = blockIdx.y * 32;
    const int tx = threadIdx.x & 31, ty0 = threadIdx.x >> 5;
    #pragma unroll
    for (int p = 0; p < 4; ++p) {
        const int r = ty0 + p * 8;
        tile[r][tx] = W[(size_t)(k0 + r) * 512 + n0 + tx];
    }
    __syncthreads();
    #pragma unroll
    for (int p = 0; p < 4; ++p) {
        const int r = ty0 + p * 8;
        Wo[(size_t)(n0 + r) * 512 + k0 + tx] = f2bf(tile[tx][r]);
    }
}

// ---------------------------------------------------------------------------
// K1: QKV GEMM, bf16 MFMA 16x16x32. 128x128 tile, BK=32, 4 waves (64x64
// quadrant each, 4x4 fragments), linear LDS via global_load_lds width=16.
// r13 changes vs r12 (placement-only; math identical):
//  (a) LDS chunk swizzle: global 16B-chunk c of row r staged at position
//      c ^ ((r>>1)&3); reads XOR the same -> 8-way bank conflict becomes
//      2-way (free). Rule #21: linear LDS dest + inverse-swz SOURCE + swz READ.
//  (b) m204 bijective XCD remap (nwg=3756=8*469+4) so each XCD owns a
//      contiguous tile range -> A-panel reuse hits its own L2.
// ---------------------------------------------------------------------------
__global__ __launch_bounds__(256)
void qkv_gemm_mfma(const unsigned short* __restrict__ xb,
                   const unsigned short* __restrict__ Wt,
                   unsigned short* __restrict__ qkv)
{
    __shared__ short Asub[128 * 32];
    __shared__ short Bsub[128 * 32];

    // (b) XCD-contiguous remap: orig%8 ~ XCD id under round-robin dispatch.
    const int orig = blockIdx.x;             // 0..3755
    const int q = 469, rmod = 4;             // 3756 = 8*469 + 4
    const int xcd = orig & 7;
    const int sub = orig >> 3;
    const int wg = (xcd < rmod ? xcd * (q + 1) : rmod * (q + 1) + (xcd - rmod) * q) + sub;
    const int n0g = (wg % 12) * 128;
    const int m0  = (wg / 12) * 128;

    const int wsel = n0g >> 9;
    const int nc0  = n0g & 511;
    const int tid = threadIdx.x;
    const int l = tid & 63;
    const int w = tid >> 6;
    const int wr = w >> 1, wc = w & 1;
    const int lr = l & 15;
    const int lk = (l >> 4) * 8;             // chunk index = lk>>3 in {0..3}

    // staging: thread covers LDS 16B-slots idx and idx+256 (linear dest);
    // (a) source chunk = slot_chunk ^ ((row>>1)&3)  [involution]
    const int idx0 = tid, idx1 = 256 + tid;
    const int ar0 = idx0 >> 2, ac0 = (((idx0 & 3) ^ ((idx0 >> 3) & 3))) * 8;
    const int ar1 = idx1 >> 2, ac1 = (((idx1 & 3) ^ ((idx1 >> 3) & 3))) * 8;

    const unsigned short* Abase = xb + (size_t)m0 * 512;
    const unsigned short* Bbase = Wt + (size_t)wsel * 262144 + (size_t)nc0 * 512;

    f32x4_t acc[4][4];
    #pragma unroll
    for (int i = 0; i < 4; ++i)
        #pragma unroll
        for (int j = 0; j < 4; ++j)
            acc[i][j] = {0.f, 0.f, 0.f, 0.f};

    for (int k0 = 0; k0 < 512; k0 += 32) {
        gll16(Abase + (size_t)ar0 * 512 + k0 + ac0, &Asub[idx0 * 8]);
        gll16(Abase + (size_t)ar1 * 512 + k0 + ac1, &Asub[idx1 * 8]);
        gll16(Bbase + (size_t)ar0 * 512 + k0 + ac0, &Bsub[idx0 * 8]);
        gll16(Bbase + (size_t)ar1 * 512 + k0 + ac1, &Bsub[idx1 * 8]);
        __syncthreads();
        bf16x8_t a[4], b[4];
        #pragma unroll
        for (int fm = 0; fm < 4; ++fm) {
            const int Ra = wr * 64 + fm * 16 + lr;
            const int pa = (((lk >> 3) ^ ((Ra >> 1) & 3))) << 3;
            a[fm] = *(const bf16x8_t*)&Asub[Ra * 32 + pa];
        }
        #pragma unroll
        for (int fn = 0; fn < 4; ++fn) {
            const int Rb = wc * 64 + fn * 16 + lr;
            const int pb = (((lk >> 3) ^ ((Rb >> 1) & 3))) << 3;
            b[fn] = *(const bf16x8_t*)&Bsub[Rb * 32 + pb];
        }
        #pragma unroll
        for (int fm = 0; fm < 4; ++fm)
            #pragma unroll
            for (int fn = 0; fn < 4; ++fn)
                acc[fm][fn] = __builtin_amdgcn_mfma_f32_16x16x32_bf16(
                                  a[fm], b[fn], acc[fm][fn], 0, 0, 0);
        __syncthreads();
    }

    #pragma unroll
    for (int fm = 0; fm < 4; ++fm)
        #pragma unroll
        for (int fn = 0; fn < 4; ++fn)
            #pragma unroll
            for (int j = 0; j < 4; ++j) {
                const int row = m0 + wr * 64 + fm * 16 + (l >> 4) * 4 + j;
                const int col = n0g + wc * 64 + fn * 16 + lr;
                qkv[(size_t)row * QKV_STRIDE + col] = f2bf(acc[fm][fn][j]);
            }
}

// ---------------------------------------------------------------------------
// CSR build (by dst).
// ---------------------------------------------------------------------------
__global__ __launch_bounds__(256)
void csr_hist(const int* __restrict__ ei, int* __restrict__ counts)
{
    const int e = blockIdx.x * 256 + threadIdx.x;   // 2500 blocks exact
    atomicAdd(&counts[ei[N_EDGES + e]], 1);
}

__global__ __launch_bounds__(1024)
void csr_scan(const int* __restrict__ counts, int* __restrict__ row_ptr)
{
    __shared__ int part[1024];
    const int t = threadIdx.x;
    const int base = t * 40;
    int s = 0;
    for (int i = 0; i < 40; ++i) {
        const int idx = base + i;
        if (idx < N_NODES) s += counts[idx];
    }
    part[t] = s;
    __syncthreads();
    for (int off = 1; off < 1024; off <<= 1) {
        int v = (t >= off) ? part[t - off] : 0;
        __syncthreads();
        part[t] += v;
        __syncthreads();
    }
    int run = (t == 0) ? 0 : part[t - 1];
    for (int i = 0; i < 40; ++i) {
        const int idx = base + i;
        if (idx < N_NODES) { row_ptr[idx] = run; run += counts[idx]; }
    }
    if (t == 0) row_ptr[N_NODES] = part[1023];
}

__global__ __launch_bounds__(256)
void csr_scatter(const int* __restrict__ ei, const int* __restrict__ row_ptr,
                 int* __restrict__ cursor, unsigned short* __restrict__ col)
{
    const int e = blockIdx.x * 256 + threadIdx.x;   // 2500 blocks exact
    const int dst = ei[N_EDGES + e];
    const int pos = atomicAdd(&cursor[dst], 1);
    col[row_ptr[dst] + pos] = (unsigned short)ei[e];
}

// ---------------------------------------------------------------------------
// KQ: in-place int8 quantization of K and V (per-row scale). One wave/node.
// K8 row (512B) at bytes [1024,1536); V8 at [2048,2560).
// ---------------------------------------------------------------------------
__global__ __launch_bounds__(256)
void quant_kv(unsigned short* __restrict__ qkv,
              float* __restrict__ kscale, float* __restrict__ vscale)
{
    const int node = blockIdx.x * 4 + (threadIdx.x >> 6);
    const int lane = threadIdx.x & 63;
    unsigned short* row = qkv + (size_t)node * QKV_STRIDE;

    const u16x8_t kk = *(const u16x8_t*)(row + 512 + lane * 8);
    const u16x8_t vv = *(const u16x8_t*)(row + 1024 + lane * 8);
    float kf[8], vf[8];
    float kamax = 0.f, vamax = 0.f;
    #pragma unroll
    for (int j = 0; j < 8; ++j) {
        kf[j] = bf2f(kk[j]); kamax = fmaxf(kamax, fabsf(kf[j]));
        vf[j] = bf2f(vv[j]); vamax = fmaxf(vamax, fabsf(vf[j]));
    }
    #pragma unroll
    for (int off = 1; off < 64; off <<= 1) {
        kamax = fmaxf(kamax, __shfl_xor(kamax, off, 64));
        vamax = fmaxf(vamax, __shfl_xor(vamax, off, 64));
    }
    const float kinv = (kamax > 0.f) ? 127.0f / kamax : 0.f;
    const float vinv = (vamax > 0.f) ? 127.0f / vamax : 0.f;

    unsigned int klo = 0, khi = 0, vlo = 0, vhi = 0;
    #pragma unroll
    for (int j = 0; j < 4; ++j) {
        const int kq = (int)rintf(kf[j] * kinv);
        const int vq = (int)rintf(vf[j] * vinv);
        klo |= ((unsigned)(unsigned char)(signed char)kq) << (8 * j);
        vlo |= ((unsigned)(unsigned char)(signed char)vq) << (8 * j);
    }
    #pragma unroll
    for (int j = 4; j < 8; ++j) {
        const int kq = (int)rintf(kf[j] * kinv);
        const int vq = (int)rintf(vf[j] * vinv);
        khi |= ((unsigned)(unsigned char)(signed char)kq) << (8 * (j - 4));
        vhi |= ((unsigned)(unsigned char)(signed char)vq) << (8 * (j - 4));
    }
    uint2 kp; kp.x = klo; kp.y = khi;
    uint2 vp; vp.x = vlo; vp.y = vhi;
    char* rowb = (char*)row;
    *(uint2*)(rowb + 1024 + lane * 8) = kp;
    *(uint2*)(rowb + 2048 + lane * 8) = vp;
    if (lane == 0) {
        kscale[node] = kamax * (1.0f / 127.0f);
        vscale[node] = vamax * (1.0f / 127.0f);
    }
}

// ---------------------------------------------------------------------------
// K2a: score pass. One wave per dst node; gathers K8 (int8, 20.5MB set).
// ---------------------------------------------------------------------------
__global__ __launch_bounds__(256)
void score_pass(const unsigned short* __restrict__ qkv,
                const float* __restrict__ kscale,
                const int* __restrict__ row_ptr,
                const unsigned short* __restrict__ col,
                float* __restrict__ s,
                float* __restrict__ z)
{
    const int node = blockIdx.x * 4 + (threadIdx.x >> 6);
    const int lane = threadIdx.x & 63;
    const int g = lane >> 3;
    const bool wlead = (lane & 7) == 0;
    const int d0b = lane * 8;

    const u16x8_t q8 = *(const u16x8_t*)(qkv + (size_t)node * QKV_STRIDE + lane * 8);
    float q[8];
    #pragma unroll
    for (int j = 0; j < 8; ++j) q[j] = bf2f(q8[j]);

    const char* qb = (const char*)qkv;
    float zsum = 0.f;
    const int start = row_ptr[node];
    const int end   = row_ptr[node + 1];

    int e = start;
    for (; e + 2 <= end; e += 2) {
        const int s0 = col[e], s1 = col[e + 1];
        const uint2 k0 = *(const uint2*)(qb + (size_t)s0 * ROW_BYTES + 1024 + d0b);
        const uint2 k1 = *(const uint2*)(qb + (size_t)s1 * ROW_BYTES + 1024 + d0b);
        const signed char* c0 = (const signed char*)&k0;
        const signed char* c1 = (const signed char*)&k1;
        float p0 = 0.f, p1 = 0.f;
        #pragma unroll
        for (int j = 0; j < 8; ++j) {
            p0 = fmaf((float)c0[j], q[j], p0);
            p1 = fmaf((float)c1[j], q[j], p1);
        }
        p0 += __shfl_xor(p0, 1, 64); p0 += __shfl_xor(p0, 2, 64); p0 += __shfl_xor(p0, 4, 64);
        p1 += __shfl_xor(p1, 1, 64); p1 += __shfl_xor(p1, 2, 64); p1 += __shfl_xor(p1, 4, 64);
        p0 *= kscale[s0] * 0.125f;
        p1 *= kscale[s1] * 0.125f;
        const float sc0 = __expf(fminf(fmaxf(p0, -5.f), 5.f));
        const float sc1 = __expf(fminf(fmaxf(p1, -5.f), 5.f));
        zsum += sc0 + sc1;
        if (wlead) {
            s[(size_t)e * 8 + g]       = sc0;
            s[(size_t)(e + 1) * 8 + g] = sc1;
        }
    }
    if (e < end) {
        const int s0 = col[e];
        const uint2 k0 = *(const uint2*)(qb + (size_t)s0 * ROW_BYTES + 1024 + d0b);
        const signed char* c0 = (const signed char*)&k0;
        float p0 = 0.f;
        #pragma unroll
        for (int j = 0; j < 8; ++j) p0 = fmaf((float)c0[j], q[j], p0);
        p0 += __shfl_xor(p0, 1, 64); p0 += __shfl_xor(p0, 2, 64); p0 += __shfl_xor(p0, 4, 64);
        p0 *= kscale[s0] * 0.125f;
        const float sc0 = __expf(fminf(fmaxf(p0, -5.f), 5.f));
        zsum += sc0;
        if (wlead) s[(size_t)e * 8 + g] = sc0;
    }
    if (wlead) z[(size_t)node * 8 + g] = zsum;
}

// ---------------------------------------------------------------------------
// K2b: PV pass. One wave per dst node; gathers V8 + streams s/x/out.
// ---------------------------------------------------------------------------
__global__ __launch_bounds__(256)
void pv_pass(const unsigned short* __restrict__ qkv,
             const float* __restrict__ vscale,
             const int* __restrict__ row_ptr,
             const unsigned short* __restrict__ col,
             const float* __restrict__ s,
             const float* __restrict__ z,
             const float* __restrict__ x,
             float* __restrict__ out)
{
    const int node = blockIdx.x * 4 + (threadIdx.x >> 6);
    const int lane = threadIdx.x & 63;
    const int g = lane >> 3;
    const int d0b = lane * 8;

    const float invz = 1.0f / (z[(size_t)node * 8 + g] + 1e-6f);
    const char* qb = (const char*)qkv;

    float acc[8] = {0.f, 0.f, 0.f, 0.f, 0.f, 0.f, 0.f, 0.f};
    const int start = row_ptr[node];
    const int end   = row_ptr[node + 1];

    int e = start;
    for (; e + 2 <= end; e += 2) {
        const int s0 = col[e], s1 = col[e + 1];
        const float scv0 = s[(size_t)e * 8 + g] * vscale[s0];
        const float scv1 = s[(size_t)(e + 1) * 8 + g] * vscale[s1];
        const uint2 v0 = *(const uint2*)(qb + (size_t)s0 * ROW_BYTES + 2048 + d0b);
        const uint2 v1 = *(const uint2*)(qb + (size_t)s1 * ROW_BYTES + 2048 + d0b);
        const signed char* c0 = (const signed char*)&v0;
        const signed char* c1 = (const signed char*)&v1;
        #pragma unroll
        for (int j = 0; j < 8; ++j) {
            acc[j] = fmaf(scv0, (float)c0[j], acc[j]);
            acc[j] = fmaf(scv1, (float)c1[j], acc[j]);
        }
    }
    if (e < end) {
        const int s0 = col[e];
        const float scv0 = s[(size_t)e * 8 + g] * vscale[s0];
        const uint2 v0 = *(const uint2*)(qb + (size_t)s0 * ROW_BYTES + 2048 + d0b);
        const signed char* c0 = (const signed char*)&v0;
        #pragma unroll
        for (int j = 0; j < 8; ++j) acc[j] = fmaf(scv0, (float)c0[j], acc[j]);
    }

    const float* xr = x + (size_t)node * 512 + lane * 8;
    float xv[8];
    #pragma unroll
    for (int j = 0; j < 8; ++j) xv[j] = __builtin_nontemporal_load(xr + j);
    float* orow = out + (size_t)node * 512 + lane * 8;
    #pragma unroll
    for (int j = 0; j < 8; ++j)
        __builtin_nontemporal_store(xv[j] + acc[j] * invz, orow + j);
}

// ---------------------------------------------------------------------------
// K3: BN column stats over final h (in d_out). thread=col, 80 rows/block.
// ---------------------------------------------------------------------------
__global__ __launch_bounds__(512)
void stats_pass(const float* __restrict__ hbuf, float* __restrict__ stats)
{
    const int c  = threadIdx.x;
    const int r0 = blockIdx.x * 80;
    float sum = 0.f, sq = 0.f;
    for (int i = 0; i < 80; ++i) {
        const float hv = hbuf[(size_t)(r0 + i) * 512 + c];
        sum += hv; sq += hv * hv;
    }
    atomicAdd(&stats[c], sum);
    atomicAdd(&stats[512 + c], sq);
}

// ---------------------------------------------------------------------------
// K4: BatchNorm normalize in place. float4/thread, 20000 blocks exact.
// ---------------------------------------------------------------------------
__global__ __launch_bounds__(256)
void bn_norm(float* __restrict__ hbuf,
             const float* __restrict__ stats,
             const float* __restrict__ gamma,
             const float* __restrict__ beta)
{
    const size_t i4 = ((size_t)blockIdx.x * 256 + threadIdx.x) * 4;
    const int c = (int)(i4 & 511);
    const float invN = 1.0f / 40000.0f;
    float4 h = *(float4*)&hbuf[i4];
    float hv[4] = {h.x, h.y, h.z, h.w};
    float o[4];
    #pragma unroll
    for (int j = 0; j < 4; ++j) {
        const float mean = stats[c + j] * invN;
        const float var  = stats[512 + c + j] * invN - mean * mean;
        o[j] = (hv[j] - mean) * rsqrtf(var + 1e-5f) * gamma[c + j] + beta[c + j];
    }
    float4 out = {o[0], o[1], o[2], o[3]};
    *(float4*)&hbuf[i4] = out;
}

extern "C" void kernel_launch(void* const* d_in, const int* in_sizes, int n_in,
                              void* d_out, int out_size, void* d_ws, size_t ws_size,
                              hipStream_t stream)
{
    const float* x     = (const float*)d_in[0];
    const int*   ei    = (const int*)d_in[1];
    // d_in[2] virt_h, d_in[3] virt_edge_index unused (use_virt_nodes=False)
    const float* Wq    = (const float*)d_in[4];
    const float* Wk    = (const float*)d_in[5];
    const float* Wv    = (const float*)d_in[6];
    const float* gamma = (const float*)d_in[7];
    const float* beta  = (const float*)d_in[8];
    float* out = (float*)d_out;

    char* ws = (char*)d_ws;
    unsigned short* qkv    = (unsigned short*)ws;                  // 123,076,608 (M_PAD rows)
    unsigned short* xb     = (unsigned short*)(ws + 123076608);    //  41,025,536 (M_PAD rows)
    unsigned short* Wt     = (unsigned short*)(ws + 164102144);    //   1,572,864
    int*            counts = (int*)           (ws + 165675008);    //     160,000
    int*            cursor = (int*)           (ws + 165835008);    //     160,000
    int*            row_ptr= (int*)           (ws + 165995008);    //     160,016
    unsigned short* col    = (unsigned short*)(ws + 166155024);    //   1,280,032
    float*          stats  = (float*)         (ws + 167435056);    //       4,096
    // s, z, kscale, vscale ALIAS the xb region (dead after qkv_gemm_mfma):
    float* s      = (float*)(ws + 123076608);               // 20,480,000 B
    float* z      = (float*)(ws + 123076608 + 24000000);    //  1,280,000 B
    float* kscale = (float*)(ws + 123076608 + 26000000);    //    160,000 B
    float* vscale = (float*)(ws + 123076608 + 26160000);    //    160,000 B
    // total ws use: 167,439,152 B (unchanged)

    hipMemsetAsync(counts, 0, 160000, stream);
    hipMemsetAsync(cursor, 0, 160000, stream);
    hipMemsetAsync(stats,  0, 4096,   stream);
    hipMemsetAsync(xb + (size_t)N_NODES * 512, 0, (size_t)(M_PAD - N_NODES) * 512 * 2, stream);

    cast_x<<<10000, 256, 0, stream>>>(x, xb);
    cast_wt<<<dim3(16, 16, 3), 256, 0, stream>>>(Wq, Wk, Wv, Wt);
    csr_hist<<<2500, 256, 0, stream>>>(ei, counts);
    csr_scan<<<1, 1024, 0, stream>>>(counts, row_ptr);
    csr_scatter<<<2500, 256, 0, stream>>>(ei, row_ptr, cursor, col);
    qkv_gemm_mfma<<<3756, 256, 0, stream>>>(xb, Wt, qkv);
    quant_kv<<<10000, 256, 0, stream>>>(qkv, kscale, vscale);
    score_pass<<<10000, 256, 0, stream>>>(qkv, kscale, row_ptr, col, s, z);
    pv_pass<<<10000, 256, 0, stream>>>(qkv, vscale, row_ptr, col, s, z, x, out);
    stats_pass<<<500, 512, 0, stream>>>(out, stats);
    bn_norm<<<20000, 256, 0, stream>>>(out, stats, gamma, beta);
}

// Round 14
// 447.279 us; speedup vs baseline: 3.4607x; 1.0086x over previous
//
#include <hip/hip_runtime.h>
#include <hip/hip_bf16.h>

#define N_NODES 40000
#define M_PAD   40064            // 313 * 128
#define N_EDGES 640000
#define DIM_H 512
#define QKV_STRIDE 1536          // Q | K | V concatenated per node row (u16 units)
#define ROW_BYTES 3072

typedef __attribute__((ext_vector_type(8))) short bf16x8_t;  // 8 bf16 = 4 VGPR
typedef __attribute__((ext_vector_type(4))) float f32x4_t;   // MFMA acc
typedef __attribute__((ext_vector_type(8))) unsigned short u16x8_t;

static __device__ __forceinline__ unsigned short f2bf(float f) {
    __hip_bfloat16 h = __float2bfloat16(f);
    return *reinterpret_cast<unsigned short*>(&h);
}
static __device__ __forceinline__ float bf2f(unsigned short u) {
    return __uint_as_float(((unsigned)u) << 16);
}
// async global->LDS, 16B per lane (linear LDS dest = uniform base + lane*16).
static __device__ __forceinline__ void gll16(const void* g, void* l) {
    __builtin_amdgcn_global_load_lds(
        (const __attribute__((address_space(1))) unsigned int*)g,
        (__attribute__((address_space(3))) unsigned int*)l, 16, 0, 0);
}

// ---------------------------------------------------------------------------
// K0a: cast x (f32) -> xb (bf16). 8 elems/thread. 10000 blocks exact.
// ---------------------------------------------------------------------------
__global__ __launch_bounds__(256)
void cast_x(const float* __restrict__ x, unsigned short* __restrict__ xb)
{
    const size_t i = ((size_t)blockIdx.x * 256 + threadIdx.x) * 8;
    const float4 v0 = *(const float4*)&x[i];
    const float4 v1 = *(const float4*)&x[i + 4];
    u16x8_t o;
    o[0] = f2bf(v0.x); o[1] = f2bf(v0.y); o[2] = f2bf(v0.z); o[3] = f2bf(v0.w);
    o[4] = f2bf(v1.x); o[5] = f2bf(v1.y); o[6] = f2bf(v1.z); o[7] = f2bf(v1.w);
    *(u16x8_t*)&xb[i] = o;
}

// ---------------------------------------------------------------------------
// K0b: cast+transpose W[k][n] -> Wt[m][n][k] (bf16). grid (16,16,3).
// ---------------------------------------------------------------------------
__global__ __launch_bounds__(256)
void cast_wt(const float* __restrict__ Wq,
             const float* __restrict__ Wk,
             const float* __restrict__ Wv,
             unsigned short* __restrict__ Wt)
{
    __shared__ float tile[32][33];
    const float* W = (blockIdx.z == 0) ? Wq : (blockIdx.z == 1) ? Wk : Wv;
    unsigned short* Wo = Wt + (size_t)blockIdx.z * 512 * 512;
    const int k0 = blockIdx.x * 32, n0 = blockIdx.y * 32;
    const int tx = threadIdx.x & 31, ty0 = threadIdx.x >> 5;
    #pragma unroll
    for (int p = 0; p < 4; ++p) {
        const int r = ty0 + p * 8;
        tile[r][tx] = W[(size_t)(k0 + r) * 512 + n0 + tx];
    }
    __syncthreads();
    #pragma unroll
    for (int p = 0; p < 4; ++p) {
        const int r = ty0 + p * 8;
        Wo[(size_t)(n0 + r) * 512 + k0 + tx] = f2bf(tile[tx][r]);
    }
}

// ---------------------------------------------------------------------------
// K1: QKV GEMM, bf16 MFMA 16x16x32. 128x128 tile, 4 waves (64x64 quadrant,
// 4x4 fragments), linear LDS via global_load_lds width=16.
// r14: BK 32 -> 64 (8 K-iters instead of 16: halves barrier-drain events,
// doubles VMEM in flight per barrier). LDS 2x16KB. Swizzle: 16B-chunk at
// row r, slot-pos p sources chunk p^(r&7); reads XOR the same (involution).
// Bank check: each 16-lane group spans all 32 banks, 2-way only (free).
// MFMA K-order identical to r13 -> bit-identical output (absmax check).
// XCD remap (m204 bijective, nwg=3756=8*469+4) unchanged.
// ---------------------------------------------------------------------------
__global__ __launch_bounds__(256)
void qkv_gemm_mfma(const unsigned short* __restrict__ xb,
                   const unsigned short* __restrict__ Wt,
                   unsigned short* __restrict__ qkv)
{
    __shared__ short Asub[128 * 64];
    __shared__ short Bsub[128 * 64];

    const int orig = blockIdx.x;             // 0..3755
    const int q = 469, rmod = 4;             // 3756 = 8*469 + 4
    const int xcd = orig & 7;
    const int sub = orig >> 3;
    const int wg = (xcd < rmod ? xcd * (q + 1) : rmod * (q + 1) + (xcd - rmod) * q) + sub;
    const int n0g = (wg % 12) * 128;
    const int m0  = (wg / 12) * 128;

    const int wsel = n0g >> 9;
    const int nc0  = n0g & 511;
    const int tid = threadIdx.x;
    const int l = tid & 63;
    const int w = tid >> 6;
    const int wr = w >> 1, wc = w & 1;
    const int lr = l & 15;
    const int kc = l >> 4;                   // lane's k-chunk within a 32-k half

    // staging: tile = 128 rows x 64 shorts = 1024 16B-slots; thread covers
    // slots tid+256p. slot s: row=s>>3, pos=s&7, src chunk = pos^(row&7).
    int srow[4], scol[4];
    #pragma unroll
    for (int p = 0; p < 4; ++p) {
        const int s = tid + 256 * p;
        srow[p] = s >> 3;
        scol[p] = ((s & 7) ^ ((s >> 3) & 7)) * 8;
    }

    const unsigned short* Abase = xb + (size_t)m0 * 512;
    const unsigned short* Bbase = Wt + (size_t)wsel * 262144 + (size_t)nc0 * 512;

    f32x4_t acc[4][4];
    #pragma unroll
    for (int i = 0; i < 4; ++i)
        #pragma unroll
        for (int j = 0; j < 4; ++j)
            acc[i][j] = {0.f, 0.f, 0.f, 0.f};

    for (int k0 = 0; k0 < 512; k0 += 64) {
        #pragma unroll
        for (int p = 0; p < 4; ++p)
            gll16(Abase + (size_t)srow[p] * 512 + k0 + scol[p],
                  &Asub[(tid + 256 * p) * 8]);
        #pragma unroll
        for (int p = 0; p < 4; ++p)
            gll16(Bbase + (size_t)srow[p] * 512 + k0 + scol[p],
                  &Bsub[(tid + 256 * p) * 8]);
        __syncthreads();
        #pragma unroll
        for (int half = 0; half < 2; ++half) {
            bf16x8_t a[4], b[4];
            #pragma unroll
            for (int fm = 0; fm < 4; ++fm) {
                const int Ra = wr * 64 + fm * 16 + lr;
                const int pa = ((half * 4 + kc) ^ (Ra & 7)) * 8;
                a[fm] = *(const bf16x8_t*)&Asub[Ra * 64 + pa];
            }
            #pragma unroll
            for (int fn = 0; fn < 4; ++fn) {
                const int Rb = wc * 64 + fn * 16 + lr;
                const int pb = ((half * 4 + kc) ^ (Rb & 7)) * 8;
                b[fn] = *(const bf16x8_t*)&Bsub[Rb * 64 + pb];
            }
            #pragma unroll
            for (int fm = 0; fm < 4; ++fm)
                #pragma unroll
                for (int fn = 0; fn < 4; ++fn)
                    acc[fm][fn] = __builtin_amdgcn_mfma_f32_16x16x32_bf16(
                                      a[fm], b[fn], acc[fm][fn], 0, 0, 0);
        }
        __syncthreads();
    }

    #pragma unroll
    for (int fm = 0; fm < 4; ++fm)
        #pragma unroll
        for (int fn = 0; fn < 4; ++fn)
            #pragma unroll
            for (int j = 0; j < 4; ++j) {
                const int row = m0 + wr * 64 + fm * 16 + (l >> 4) * 4 + j;
                const int col = n0g + wc * 64 + fn * 16 + lr;
                qkv[(size_t)row * QKV_STRIDE + col] = f2bf(acc[fm][fn][j]);
            }
}

// ---------------------------------------------------------------------------
// CSR build (by dst).
// ---------------------------------------------------------------------------
__global__ __launch_bounds__(256)
void csr_hist(const int* __restrict__ ei, int* __restrict__ counts)
{
    const int e = blockIdx.x * 256 + threadIdx.x;   // 2500 blocks exact
    atomicAdd(&counts[ei[N_EDGES + e]], 1);
}

__global__ __launch_bounds__(1024)
void csr_scan(const int* __restrict__ counts, int* __restrict__ row_ptr)
{
    __shared__ int part[1024];
    const int t = threadIdx.x;
    const int base = t * 40;
    int s = 0;
    for (int i = 0; i < 40; ++i) {
        const int idx = base + i;
        if (idx < N_NODES) s += counts[idx];
    }
    part[t] = s;
    __syncthreads();
    for (int off = 1; off < 1024; off <<= 1) {
        int v = (t >= off) ? part[t - off] : 0;
        __syncthreads();
        part[t] += v;
        __syncthreads();
    }
    int run = (t == 0) ? 0 : part[t - 1];
    for (int i = 0; i < 40; ++i) {
        const int idx = base + i;
        if (idx < N_NODES) { row_ptr[idx] = run; run += counts[idx]; }
    }
    if (t == 0) row_ptr[N_NODES] = part[1023];
}

__global__ __launch_bounds__(256)
void csr_scatter(const int* __restrict__ ei, const int* __restrict__ row_ptr,
                 int* __restrict__ cursor, unsigned short* __restrict__ col)
{
    const int e = blockIdx.x * 256 + threadIdx.x;   // 2500 blocks exact
    const int dst = ei[N_EDGES + e];
    const int pos = atomicAdd(&cursor[dst], 1);
    col[row_ptr[dst] + pos] = (unsigned short)ei[e];
}

// ---------------------------------------------------------------------------
// KQ: in-place int8 quantization of K and V (per-row scale). One wave/node.
// K8 row (512B) at bytes [1024,1536); V8 at [2048,2560).
// ---------------------------------------------------------------------------
__global__ __launch_bounds__(256)
void quant_kv(unsigned short* __restrict__ qkv,
              float* __restrict__ kscale, float* __restrict__ vscale)
{
    const int node = blockIdx.x * 4 + (threadIdx.x >> 6);
    const int lane = threadIdx.x & 63;
    unsigned short* row = qkv + (size_t)node * QKV_STRIDE;

    const u16x8_t kk = *(const u16x8_t*)(row + 512 + lane * 8);
    const u16x8_t vv = *(const u16x8_t*)(row + 1024 + lane * 8);
    float kf[8], vf[8];
    float kamax = 0.f, vamax = 0.f;
    #pragma unroll
    for (int j = 0; j < 8; ++j) {
        kf[j] = bf2f(kk[j]); kamax = fmaxf(kamax, fabsf(kf[j]));
        vf[j] = bf2f(vv[j]); vamax = fmaxf(vamax, fabsf(vf[j]));
    }
    #pragma unroll
    for (int off = 1; off < 64; off <<= 1) {
        kamax = fmaxf(kamax, __shfl_xor(kamax, off, 64));
        vamax = fmaxf(vamax, __shfl_xor(vamax, off, 64));
    }
    const float kinv = (kamax > 0.f) ? 127.0f / kamax : 0.f;
    const float vinv = (vamax > 0.f) ? 127.0f / vamax : 0.f;

    unsigned int klo = 0, khi = 0, vlo = 0, vhi = 0;
    #pragma unroll
    for (int j = 0; j < 4; ++j) {
        const int kq = (int)rintf(kf[j] * kinv);
        const int vq = (int)rintf(vf[j] * vinv);
        klo |= ((unsigned)(unsigned char)(signed char)kq) << (8 * j);
        vlo |= ((unsigned)(unsigned char)(signed char)vq) << (8 * j);
    }
    #pragma unroll
    for (int j = 4; j < 8; ++j) {
        const int kq = (int)rintf(kf[j] * kinv);
        const int vq = (int)rintf(vf[j] * vinv);
        khi |= ((unsigned)(unsigned char)(signed char)kq) << (8 * (j - 4));
        vhi |= ((unsigned)(unsigned char)(signed char)vq) << (8 * (j - 4));
    }
    uint2 kp; kp.x = klo; kp.y = khi;
    uint2 vp; vp.x = vlo; vp.y = vhi;
    char* rowb = (char*)row;
    *(uint2*)(rowb + 1024 + lane * 8) = kp;
    *(uint2*)(rowb + 2048 + lane * 8) = vp;
    if (lane == 0) {
        kscale[node] = kamax * (1.0f / 127.0f);
        vscale[node] = vamax * (1.0f / 127.0f);
    }
}

// ---------------------------------------------------------------------------
// K2a: score pass. One wave per dst node; gathers K8 (int8, 20.5MB set).
// r14: 4-edge main loop (8 outstanding loads) + scalar tail. At int8 the
// unroll costs ~16 VGPR (uint2 loads), unlike r9's bf16 attempt.
// ---------------------------------------------------------------------------
__global__ __launch_bounds__(256)
void score_pass(const unsigned short* __restrict__ qkv,
                const float* __restrict__ kscale,
                const int* __restrict__ row_ptr,
                const unsigned short* __restrict__ col,
                float* __restrict__ s,
                float* __restrict__ z)
{
    const int node = blockIdx.x * 4 + (threadIdx.x >> 6);
    const int lane = threadIdx.x & 63;
    const int g = lane >> 3;
    const bool wlead = (lane & 7) == 0;
    const int d0b = lane * 8;

    const u16x8_t q8 = *(const u16x8_t*)(qkv + (size_t)node * QKV_STRIDE + lane * 8);
    float q[8];
    #pragma unroll
    for (int j = 0; j < 8; ++j) q[j] = bf2f(q8[j]);

    const char* qb = (const char*)qkv;
    float zsum = 0.f;
    const int start = row_ptr[node];
    const int end   = row_ptr[node + 1];

    int e = start;
    for (; e + 4 <= end; e += 4) {
        const int s0 = col[e], s1 = col[e + 1], s2 = col[e + 2], s3 = col[e + 3];
        const uint2 k0 = *(const uint2*)(qb + (size_t)s0 * ROW_BYTES + 1024 + d0b);
        const uint2 k1 = *(const uint2*)(qb + (size_t)s1 * ROW_BYTES + 1024 + d0b);
        const uint2 k2 = *(const uint2*)(qb + (size_t)s2 * ROW_BYTES + 1024 + d0b);
        const uint2 k3 = *(const uint2*)(qb + (size_t)s3 * ROW_BYTES + 1024 + d0b);
        const signed char* c0 = (const signed char*)&k0;
        const signed char* c1 = (const signed char*)&k1;
        const signed char* c2 = (const signed char*)&k2;
        const signed char* c3 = (const signed char*)&k3;
        float p0 = 0.f, p1 = 0.f, p2 = 0.f, p3 = 0.f;
        #pragma unroll
        for (int j = 0; j < 8; ++j) {
            p0 = fmaf((float)c0[j], q[j], p0);
            p1 = fmaf((float)c1[j], q[j], p1);
            p2 = fmaf((float)c2[j], q[j], p2);
            p3 = fmaf((float)c3[j], q[j], p3);
        }
        p0 += __shfl_xor(p0, 1, 64); p0 += __shfl_xor(p0, 2, 64); p0 += __shfl_xor(p0, 4, 64);
        p1 += __shfl_xor(p1, 1, 64); p1 += __shfl_xor(p1, 2, 64); p1 += __shfl_xor(p1, 4, 64);
        p2 += __shfl_xor(p2, 1, 64); p2 += __shfl_xor(p2, 2, 64); p2 += __shfl_xor(p2, 4, 64);
        p3 += __shfl_xor(p3, 1, 64); p3 += __shfl_xor(p3, 2, 64); p3 += __shfl_xor(p3, 4, 64);
        const float sc0 = __expf(fminf(fmaxf(p0 * kscale[s0] * 0.125f, -5.f), 5.f));
        const float sc1 = __expf(fminf(fmaxf(p1 * kscale[s1] * 0.125f, -5.f), 5.f));
        const float sc2 = __expf(fminf(fmaxf(p2 * kscale[s2] * 0.125f, -5.f), 5.f));
        const float sc3 = __expf(fminf(fmaxf(p3 * kscale[s3] * 0.125f, -5.f), 5.f));
        zsum += (sc0 + sc1) + (sc2 + sc3);
        if (wlead) {
            s[(size_t)e * 8 + g]       = sc0;
            s[(size_t)(e + 1) * 8 + g] = sc1;
            s[(size_t)(e + 2) * 8 + g] = sc2;
            s[(size_t)(e + 3) * 8 + g] = sc3;
        }
    }
    for (; e < end; ++e) {
        const int s0 = col[e];
        const uint2 k0 = *(const uint2*)(qb + (size_t)s0 * ROW_BYTES + 1024 + d0b);
        const signed char* c0 = (const signed char*)&k0;
        float p0 = 0.f;
        #pragma unroll
        for (int j = 0; j < 8; ++j) p0 = fmaf((float)c0[j], q[j], p0);
        p0 += __shfl_xor(p0, 1, 64); p0 += __shfl_xor(p0, 2, 64); p0 += __shfl_xor(p0, 4, 64);
        const float sc0 = __expf(fminf(fmaxf(p0 * kscale[s0] * 0.125f, -5.f), 5.f));
        zsum += sc0;
        if (wlead) s[(size_t)e * 8 + g] = sc0;
    }
    if (wlead) z[(size_t)node * 8 + g] = zsum;
}

// ---------------------------------------------------------------------------
// K2b: PV pass. One wave per dst node; gathers V8 + streams s/x/out.
// r14: 4-edge main loop + scalar tail.
// ---------------------------------------------------------------------------
__global__ __launch_bounds__(256)
void pv_pass(const unsigned short* __restrict__ qkv,
             const float* __restrict__ vscale,
             const int* __restrict__ row_ptr,
             const unsigned short* __restrict__ col,
             const float* __restrict__ s,
             const float* __restrict__ z,
             const float* __restrict__ x,
             float* __restrict__ out)
{
    const int node = blockIdx.x * 4 + (threadIdx.x >> 6);
    const int lane = threadIdx.x & 63;
    const int g = lane >> 3;
    const int d0b = lane * 8;

    const float invz = 1.0f / (z[(size_t)node * 8 + g] + 1e-6f);
    const char* qb = (const char*)qkv;

    float acc[8] = {0.f, 0.f, 0.f, 0.f, 0.f, 0.f, 0.f, 0.f};
    const int start = row_ptr[node];
    const int end   = row_ptr[node + 1];

    int e = start;
    for (; e + 4 <= end; e += 4) {
        const int s0 = col[e], s1 = col[e + 1], s2 = col[e + 2], s3 = col[e + 3];
        const float scv0 = s[(size_t)e * 8 + g] * vscale[s0];
        const float scv1 = s[(size_t)(e + 1) * 8 + g] * vscale[s1];
        const float scv2 = s[(size_t)(e + 2) * 8 + g] * vscale[s2];
        const float scv3 = s[(size_t)(e + 3) * 8 + g] * vscale[s3];
        const uint2 v0 = *(const uint2*)(qb + (size_t)s0 * ROW_BYTES + 2048 + d0b);
        const uint2 v1 = *(const uint2*)(qb + (size_t)s1 * ROW_BYTES + 2048 + d0b);
        const uint2 v2 = *(const uint2*)(qb + (size_t)s2 * ROW_BYTES + 2048 + d0b);
        const uint2 v3 = *(const uint2*)(qb + (size_t)s3 * ROW_BYTES + 2048 + d0b);
        const signed char* c0 = (const signed char*)&v0;
        const signed char* c1 = (const signed char*)&v1;
        const signed char* c2 = (const signed char*)&v2;
        const signed char* c3 = (const signed char*)&v3;
        #pragma unroll
        for (int j = 0; j < 8; ++j) {
            float a = acc[j];
            a = fmaf(scv0, (float)c0[j], a);
            a = fmaf(scv1, (float)c1[j], a);
            a = fmaf(scv2, (float)c2[j], a);
            a = fmaf(scv3, (float)c3[j], a);
            acc[j] = a;
        }
    }
    for (; e < end; ++e) {
        const int s0 = col[e];
        const float scv0 = s[(size_t)e * 8 + g] * vscale[s0];
        const uint2 v0 = *(const uint2*)(qb + (size_t)s0 * ROW_BYTES + 2048 + d0b);
        const signed char* c0 = (const signed char*)&v0;
        #pragma unroll
        for (int j = 0; j < 8; ++j) acc[j] = fmaf(scv0, (float)c0[j], acc[j]);
    }

    const float* xr = x + (size_t)node * 512 + lane * 8;
    float xv[8];
    #pragma unroll
    for (int j = 0; j < 8; ++j) xv[j] = __builtin_nontemporal_load(xr + j);
    float* orow = out + (size_t)node * 512 + lane * 8;
    #pragma unroll
    for (int j = 0; j < 8; ++j)
        __builtin_nontemporal_store(xv[j] + acc[j] * invz, orow + j);
}

// ---------------------------------------------------------------------------
// K3: BN column stats over final h (in d_out). thread=col, 80 rows/block.
// ---------------------------------------------------------------------------
__global__ __launch_bounds__(512)
void stats_pass(const float* __restrict__ hbuf, float* __restrict__ stats)
{
    const int c  = threadIdx.x;
    const int r0 = blockIdx.x * 80;
    float sum = 0.f, sq = 0.f;
    for (int i = 0; i < 80; ++i) {
        const float hv = hbuf[(size_t)(r0 + i) * 512 + c];
        sum += hv; sq += hv * hv;
    }
    atomicAdd(&stats[c], sum);
    atomicAdd(&stats[512 + c], sq);
}

// ---------------------------------------------------------------------------
// K4: BatchNorm normalize in place. float4/thread, 20000 blocks exact.
// ---------------------------------------------------------------------------
__global__ __launch_bounds__(256)
void bn_norm(float* __restrict__ hbuf,
             const float* __restrict__ stats,
             const float* __restrict__ gamma,
             const float* __restrict__ beta)
{
    const size_t i4 = ((size_t)blockIdx.x * 256 + threadIdx.x) * 4;
    const int c = (int)(i4 & 511);
    const float invN = 1.0f / 40000.0f;
    float4 h = *(float4*)&hbuf[i4];
    float hv[4] = {h.x, h.y, h.z, h.w};
    float o[4];
    #pragma unroll
    for (int j = 0; j < 4; ++j) {
        const float mean = stats[c + j] * invN;
        const float var  = stats[512 + c + j] * invN - mean * mean;
        o[j] = (hv[j] - mean) * rsqrtf(var + 1e-5f) * gamma[c + j] + beta[c + j];
    }
    float4 out = {o[0], o[1], o[2], o[3]};
    *(float4*)&hbuf[i4] = out;
}

extern "C" void kernel_launch(void* const* d_in, const int* in_sizes, int n_in,
                              void* d_out, int out_size, void* d_ws, size_t ws_size,
                              hipStream_t stream)
{
    const float* x     = (const float*)d_in[0];
    const int*   ei    = (const int*)d_in[1];
    // d_in[2] virt_h, d_in[3] virt_edge_index unused (use_virt_nodes=False)
    const float* Wq    = (const float*)d_in[4];
    const float* Wk    = (const float*)d_in[5];
    const float* Wv    = (const float*)d_in[6];
    const float* gamma = (const float*)d_in[7];
    const float* beta  = (const float*)d_in[8];
    float* out = (float*)d_out;

    char* ws = (char*)d_ws;
    unsigned short* qkv    = (unsigned short*)ws;                  // 123,076,608 (M_PAD rows)
    unsigned short* xb     = (unsigned short*)(ws + 123076608);    //  41,025,536 (M_PAD rows)
    unsigned short* Wt     = (unsigned short*)(ws + 164102144);    //   1,572,864
    int*            counts = (int*)           (ws + 165675008);    //     160,000
    int*            cursor = (int*)           (ws + 165835008);    //     160,000
    int*            row_ptr= (int*)           (ws + 165995008);    //     160,016
    unsigned short* col    = (unsigned short*)(ws + 166155024);    //   1,280,032
    float*          stats  = (float*)         (ws + 167435056);    //       4,096
    // s, z, kscale, vscale ALIAS the xb region (dead after qkv_gemm_mfma):
    float* s      = (float*)(ws + 123076608);               // 20,480,000 B
    float* z      = (float*)(ws + 123076608 + 24000000);    //  1,280,000 B
    float* kscale = (float*)(ws + 123076608 + 26000000);    //    160,000 B
    float* vscale = (float*)(ws + 123076608 + 26160000);    //    160,000 B
    // total ws use: 167,439,152 B (unchanged)

    hipMemsetAsync(counts, 0, 160000, stream);
    hipMemsetAsync(cursor, 0, 160000, stream);
    hipMemsetAsync(stats,  0, 4096,   stream);
    hipMemsetAsync(xb + (size_t)N_NODES * 512, 0, (size_t)(M_PAD - N_NODES) * 512 * 2, stream);

    cast_x<<<10000, 256, 0, stream>>>(x, xb);
    cast_wt<<<dim3(16, 16, 3), 256, 0, stream>>>(Wq, Wk, Wv, Wt);
    csr_hist<<<2500, 256, 0, stream>>>(ei, counts);
    csr_scan<<<1, 1024, 0, stream>>>(counts, row_ptr);
    csr_scatter<<<2500, 256, 0, stream>>>(ei, row_ptr, cursor, col);
    qkv_gemm_mfma<<<3756, 256, 0, stream>>>(xb, Wt, qkv);
    quant_kv<<<10000, 256, 0, stream>>>(qkv, kscale, vscale);
    score_pass<<<10000, 256, 0, stream>>>(qkv, kscale, row_ptr, col, s, z);
    pv_pass<<<10000, 256, 0, stream>>>(qkv, vscale, row_ptr, col, s, z, x, out);
    stats_pass<<<500, 512, 0, stream>>>(out, stats);
    bn_norm<<<20000, 256, 0, stream>>>(out, stats, gamma, beta);
}

// Round 15
// 446.003 us; speedup vs baseline: 3.4706x; 1.0029x over previous
//
#include <hip/hip_runtime.h>
#include <hip/hip_bf16.h>

#define N_NODES 40000
#define M_PAD   40064            // 313 * 128
#define N_EDGES 640000
#define DIM_H 512
#define QKV_STRIDE 1536          // Q | K | V concatenated per node row (u16 units)
#define ROW_BYTES 3072

typedef __attribute__((ext_vector_type(8))) short bf16x8_t;  // 8 bf16 = 4 VGPR
typedef __attribute__((ext_vector_type(4))) float f32x4_t;   // MFMA acc
typedef __attribute__((ext_vector_type(8))) unsigned short u16x8_t;

static __device__ __forceinline__ unsigned short f2bf(float f) {
    __hip_bfloat16 h = __float2bfloat16(f);
    return *reinterpret_cast<unsigned short*>(&h);
}
static __device__ __forceinline__ float bf2f(unsigned short u) {
    return __uint_as_float(((unsigned)u) << 16);
}
// async global->LDS, 16B per lane (linear LDS dest = uniform base + lane*16).
static __device__ __forceinline__ void gll16(const void* g, void* l) {
    __builtin_amdgcn_global_load_lds(
        (const __attribute__((address_space(1))) unsigned int*)g,
        (__attribute__((address_space(3))) unsigned int*)l, 16, 0, 0);
}

// ---------------------------------------------------------------------------
// K0a: cast x (f32) -> xb (bf16). 8 elems/thread. 10000 blocks exact.
// ---------------------------------------------------------------------------
__global__ __launch_bounds__(256)
void cast_x(const float* __restrict__ x, unsigned short* __restrict__ xb)
{
    const size_t i = ((size_t)blockIdx.x * 256 + threadIdx.x) * 8;
    const float4 v0 = *(const float4*)&x[i];
    const float4 v1 = *(const float4*)&x[i + 4];
    u16x8_t o;
    o[0] = f2bf(v0.x); o[1] = f2bf(v0.y); o[2] = f2bf(v0.z); o[3] = f2bf(v0.w);
    o[4] = f2bf(v1.x); o[5] = f2bf(v1.y); o[6] = f2bf(v1.z); o[7] = f2bf(v1.w);
    *(u16x8_t*)&xb[i] = o;
}

// ---------------------------------------------------------------------------
// K0b: cast+transpose W[k][n] -> Wt[m][n][k] (bf16). grid (16,16,3).
// ---------------------------------------------------------------------------
__global__ __launch_bounds__(256)
void cast_wt(const float* __restrict__ Wq,
             const float* __restrict__ Wk,
             const float* __restrict__ Wv,
             unsigned short* __restrict__ Wt)
{
    __shared__ float tile[32][33];
    const float* W = (blockIdx.z == 0) ? Wq : (blockIdx.z == 1) ? Wk : Wv;
    unsigned short* Wo = Wt + (size_t)blockIdx.z * 512 * 512;
    const int k0 = blockIdx.x * 32, n0 = blockIdx.y * 32;
    const int tx = threadIdx.x & 31, ty0 = threadIdx.x >> 5;
    #pragma unroll
    for (int p = 0; p < 4; ++p) {
        const int r = ty0 + p * 8;
        tile[r][tx] = W[(size_t)(k0 + r) * 512 + n0 + tx];
    }
    __syncthreads();
    #pragma unroll
    for (int p = 0; p < 4; ++p) {
        const int r = ty0 + p * 8;
        Wo[(size_t)(n0 + r) * 512 + k0 + tx] = f2bf(tile[tx][r]);
    }
}

// ---------------------------------------------------------------------------
// K1: QKV GEMM (r13 version, reverted from BK=64: r14 showed occupancy loss
// 30->19% outweighed fewer barriers). 128x128 tile, BK=32, 4 waves,
// chunk-swizzled staging (src chunk = pos^((row>>1)&3)), XCD-bijective remap.
// Proven 91us, MfmaUtil 29%, 0 bank conflicts, FETCH 48MB.
// ---------------------------------------------------------------------------
__global__ __launch_bounds__(256)
void qkv_gemm_mfma(const unsigned short* __restrict__ xb,
                   const unsigned short* __restrict__ Wt,
                   unsigned short* __restrict__ qkv)
{
    __shared__ short Asub[128 * 32];
    __shared__ short Bsub[128 * 32];

    const int orig = blockIdx.x;             // 0..3755
    const int q = 469, rmod = 4;             // 3756 = 8*469 + 4
    const int xcd = orig & 7;
    const int sub = orig >> 3;
    const int wg = (xcd < rmod ? xcd * (q + 1) : rmod * (q + 1) + (xcd - rmod) * q) + sub;
    const int n0g = (wg % 12) * 128;
    const int m0  = (wg / 12) * 128;

    const int wsel = n0g >> 9;
    const int nc0  = n0g & 511;
    const int tid = threadIdx.x;
    const int l = tid & 63;
    const int w = tid >> 6;
    const int wr = w >> 1, wc = w & 1;
    const int lr = l & 15;
    const int lk = (l >> 4) * 8;             // chunk index = lk>>3 in {0..3}

    const int idx0 = tid, idx1 = 256 + tid;
    const int ar0 = idx0 >> 2, ac0 = (((idx0 & 3) ^ ((idx0 >> 3) & 3))) * 8;
    const int ar1 = idx1 >> 2, ac1 = (((idx1 & 3) ^ ((idx1 >> 3) & 3))) * 8;

    const unsigned short* Abase = xb + (size_t)m0 * 512;
    const unsigned short* Bbase = Wt + (size_t)wsel * 262144 + (size_t)nc0 * 512;

    f32x4_t acc[4][4];
    #pragma unroll
    for (int i = 0; i < 4; ++i)
        #pragma unroll
        for (int j = 0; j < 4; ++j)
            acc[i][j] = {0.f, 0.f, 0.f, 0.f};

    for (int k0 = 0; k0 < 512; k0 += 32) {
        gll16(Abase + (size_t)ar0 * 512 + k0 + ac0, &Asub[idx0 * 8]);
        gll16(Abase + (size_t)ar1 * 512 + k0 + ac1, &Asub[idx1 * 8]);
        gll16(Bbase + (size_t)ar0 * 512 + k0 + ac0, &Bsub[idx0 * 8]);
        gll16(Bbase + (size_t)ar1 * 512 + k0 + ac1, &Bsub[idx1 * 8]);
        __syncthreads();
        bf16x8_t a[4], b[4];
        #pragma unroll
        for (int fm = 0; fm < 4; ++fm) {
            const int Ra = wr * 64 + fm * 16 + lr;
            const int pa = (((lk >> 3) ^ ((Ra >> 1) & 3))) << 3;
            a[fm] = *(const bf16x8_t*)&Asub[Ra * 32 + pa];
        }
        #pragma unroll
        for (int fn = 0; fn < 4; ++fn) {
            const int Rb = wc * 64 + fn * 16 + lr;
            const int pb = (((lk >> 3) ^ ((Rb >> 1) & 3))) << 3;
            b[fn] = *(const bf16x8_t*)&Bsub[Rb * 32 + pb];
        }
        #pragma unroll
        for (int fm = 0; fm < 4; ++fm)
            #pragma unroll
            for (int fn = 0; fn < 4; ++fn)
                acc[fm][fn] = __builtin_amdgcn_mfma_f32_16x16x32_bf16(
                                  a[fm], b[fn], acc[fm][fn], 0, 0, 0);
        __syncthreads();
    }

    #pragma unroll
    for (int fm = 0; fm < 4; ++fm)
        #pragma unroll
        for (int fn = 0; fn < 4; ++fn)
            #pragma unroll
            for (int j = 0; j < 4; ++j) {
                const int row = m0 + wr * 64 + fm * 16 + (l >> 4) * 4 + j;
                const int col = n0g + wc * 64 + fn * 16 + lr;
                qkv[(size_t)row * QKV_STRIDE + col] = f2bf(acc[fm][fn][j]);
            }
}

// ---------------------------------------------------------------------------
// CSR build (by dst).
// ---------------------------------------------------------------------------
__global__ __launch_bounds__(256)
void csr_hist(const int* __restrict__ ei, int* __restrict__ counts)
{
    const int e = blockIdx.x * 256 + threadIdx.x;   // 2500 blocks exact
    atomicAdd(&counts[ei[N_EDGES + e]], 1);
}

__global__ __launch_bounds__(1024)
void csr_scan(const int* __restrict__ counts, int* __restrict__ row_ptr)
{
    __shared__ int part[1024];
    const int t = threadIdx.x;
    const int base = t * 40;
    int s = 0;
    for (int i = 0; i < 40; ++i) {
        const int idx = base + i;
        if (idx < N_NODES) s += counts[idx];
    }
    part[t] = s;
    __syncthreads();
    for (int off = 1; off < 1024; off <<= 1) {
        int v = (t >= off) ? part[t - off] : 0;
        __syncthreads();
        part[t] += v;
        __syncthreads();
    }
    int run = (t == 0) ? 0 : part[t - 1];
    for (int i = 0; i < 40; ++i) {
        const int idx = base + i;
        if (idx < N_NODES) { row_ptr[idx] = run; run += counts[idx]; }
    }
    if (t == 0) row_ptr[N_NODES] = part[1023];
}

__global__ __launch_bounds__(256)
void csr_scatter(const int* __restrict__ ei, const int* __restrict__ row_ptr,
                 int* __restrict__ cursor, unsigned short* __restrict__ col)
{
    const int e = blockIdx.x * 256 + threadIdx.x;   // 2500 blocks exact
    const int dst = ei[N_EDGES + e];
    const int pos = atomicAdd(&cursor[dst], 1);
    col[row_ptr[dst] + pos] = (unsigned short)ei[e];
}

// ---------------------------------------------------------------------------
// KQ: in-place int8 quantization of K and V (per-row scale). One wave/node.
// K8 row (512B) at bytes [1024,1536); V8 at [2048,2560).
// ---------------------------------------------------------------------------
__global__ __launch_bounds__(256)
void quant_kv(unsigned short* __restrict__ qkv,
              float* __restrict__ kscale, float* __restrict__ vscale)
{
    const int node = blockIdx.x * 4 + (threadIdx.x >> 6);
    const int lane = threadIdx.x & 63;
    unsigned short* row = qkv + (size_t)node * QKV_STRIDE;

    const u16x8_t kk = *(const u16x8_t*)(row + 512 + lane * 8);
    const u16x8_t vv = *(const u16x8_t*)(row + 1024 + lane * 8);
    float kf[8], vf[8];
    float kamax = 0.f, vamax = 0.f;
    #pragma unroll
    for (int j = 0; j < 8; ++j) {
        kf[j] = bf2f(kk[j]); kamax = fmaxf(kamax, fabsf(kf[j]));
        vf[j] = bf2f(vv[j]); vamax = fmaxf(vamax, fabsf(vf[j]));
    }
    #pragma unroll
    for (int off = 1; off < 64; off <<= 1) {
        kamax = fmaxf(kamax, __shfl_xor(kamax, off, 64));
        vamax = fmaxf(vamax, __shfl_xor(vamax, off, 64));
    }
    const float kinv = (kamax > 0.f) ? 127.0f / kamax : 0.f;
    const float vinv = (vamax > 0.f) ? 127.0f / vamax : 0.f;

    unsigned int klo = 0, khi = 0, vlo = 0, vhi = 0;
    #pragma unroll
    for (int j = 0; j < 4; ++j) {
        const int kq = (int)rintf(kf[j] * kinv);
        const int vq = (int)rintf(vf[j] * vinv);
        klo |= ((unsigned)(unsigned char)(signed char)kq) << (8 * j);
        vlo |= ((unsigned)(unsigned char)(signed char)vq) << (8 * j);
    }
    #pragma unroll
    for (int j = 4; j < 8; ++j) {
        const int kq = (int)rintf(kf[j] * kinv);
        const int vq = (int)rintf(vf[j] * vinv);
        khi |= ((unsigned)(unsigned char)(signed char)kq) << (8 * (j - 4));
        vhi |= ((unsigned)(unsigned char)(signed char)vq) << (8 * (j - 4));
    }
    uint2 kp; kp.x = klo; kp.y = khi;
    uint2 vp; vp.x = vlo; vp.y = vhi;
    char* rowb = (char*)row;
    *(uint2*)(rowb + 1024 + lane * 8) = kp;
    *(uint2*)(rowb + 2048 + lane * 8) = vp;
    if (lane == 0) {
        kscale[node] = kamax * (1.0f / 127.0f);
        vscale[node] = vamax * (1.0f / 127.0f);
    }
}

// ---------------------------------------------------------------------------
// K2a: score pass. r15: 2-wave blocks (grid 20000) for degree load-balance
// (Poisson(16) degrees: max-of-4 waves ~ +25% idle, max-of-2 ~ +12%;
// 16 blk/CU x 2 waves = 32 waves/CU keeps full occupancy).
// 4-edge main loop + scalar tail (r14, kept).
// ---------------------------------------------------------------------------
__global__ __launch_bounds__(128)
void score_pass(const unsigned short* __restrict__ qkv,
                const float* __restrict__ kscale,
                const int* __restrict__ row_ptr,
                const unsigned short* __restrict__ col,
                float* __restrict__ s,
                float* __restrict__ z)
{
    const int node = blockIdx.x * 2 + (threadIdx.x >> 6);
    const int lane = threadIdx.x & 63;
    const int g = lane >> 3;
    const bool wlead = (lane & 7) == 0;
    const int d0b = lane * 8;

    const u16x8_t q8 = *(const u16x8_t*)(qkv + (size_t)node * QKV_STRIDE + lane * 8);
    float q[8];
    #pragma unroll
    for (int j = 0; j < 8; ++j) q[j] = bf2f(q8[j]);

    const char* qb = (const char*)qkv;
    float zsum = 0.f;
    const int start = row_ptr[node];
    const int end   = row_ptr[node + 1];

    int e = start;
    for (; e + 4 <= end; e += 4) {
        const int s0 = col[e], s1 = col[e + 1], s2 = col[e + 2], s3 = col[e + 3];
        const uint2 k0 = *(const uint2*)(qb + (size_t)s0 * ROW_BYTES + 1024 + d0b);
        const uint2 k1 = *(const uint2*)(qb + (size_t)s1 * ROW_BYTES + 1024 + d0b);
        const uint2 k2 = *(const uint2*)(qb + (size_t)s2 * ROW_BYTES + 1024 + d0b);
        const uint2 k3 = *(const uint2*)(qb + (size_t)s3 * ROW_BYTES + 1024 + d0b);
        const signed char* c0 = (const signed char*)&k0;
        const signed char* c1 = (const signed char*)&k1;
        const signed char* c2 = (const signed char*)&k2;
        const signed char* c3 = (const signed char*)&k3;
        float p0 = 0.f, p1 = 0.f, p2 = 0.f, p3 = 0.f;
        #pragma unroll
        for (int j = 0; j < 8; ++j) {
            p0 = fmaf((float)c0[j], q[j], p0);
            p1 = fmaf((float)c1[j], q[j], p1);
            p2 = fmaf((float)c2[j], q[j], p2);
            p3 = fmaf((float)c3[j], q[j], p3);
        }
        p0 += __shfl_xor(p0, 1, 64); p0 += __shfl_xor(p0, 2, 64); p0 += __shfl_xor(p0, 4, 64);
        p1 += __shfl_xor(p1, 1, 64); p1 += __shfl_xor(p1, 2, 64); p1 += __shfl_xor(p1, 4, 64);
        p2 += __shfl_xor(p2, 1, 64); p2 += __shfl_xor(p2, 2, 64); p2 += __shfl_xor(p2, 4, 64);
        p3 += __shfl_xor(p3, 1, 64); p3 += __shfl_xor(p3, 2, 64); p3 += __shfl_xor(p3, 4, 64);
        const float sc0 = __expf(fminf(fmaxf(p0 * kscale[s0] * 0.125f, -5.f), 5.f));
        const float sc1 = __expf(fminf(fmaxf(p1 * kscale[s1] * 0.125f, -5.f), 5.f));
        const float sc2 = __expf(fminf(fmaxf(p2 * kscale[s2] * 0.125f, -5.f), 5.f));
        const float sc3 = __expf(fminf(fmaxf(p3 * kscale[s3] * 0.125f, -5.f), 5.f));
        zsum += (sc0 + sc1) + (sc2 + sc3);
        if (wlead) {
            s[(size_t)e * 8 + g]       = sc0;
            s[(size_t)(e + 1) * 8 + g] = sc1;
            s[(size_t)(e + 2) * 8 + g] = sc2;
            s[(size_t)(e + 3) * 8 + g] = sc3;
        }
    }
    for (; e < end; ++e) {
        const int s0 = col[e];
        const uint2 k0 = *(const uint2*)(qb + (size_t)s0 * ROW_BYTES + 1024 + d0b);
        const signed char* c0 = (const signed char*)&k0;
        float p0 = 0.f;
        #pragma unroll
        for (int j = 0; j < 8; ++j) p0 = fmaf((float)c0[j], q[j], p0);
        p0 += __shfl_xor(p0, 1, 64); p0 += __shfl_xor(p0, 2, 64); p0 += __shfl_xor(p0, 4, 64);
        const float sc0 = __expf(fminf(fmaxf(p0 * kscale[s0] * 0.125f, -5.f), 5.f));
        zsum += sc0;
        if (wlead) s[(size_t)e * 8 + g] = sc0;
    }
    if (wlead) z[(size_t)node * 8 + g] = zsum;
}

// ---------------------------------------------------------------------------
// K2b: PV pass. r15: 2-wave blocks (grid 20000), 4-edge main loop + tail.
// ---------------------------------------------------------------------------
__global__ __launch_bounds__(128)
void pv_pass(const unsigned short* __restrict__ qkv,
             const float* __restrict__ vscale,
             const int* __restrict__ row_ptr,
             const unsigned short* __restrict__ col,
             const float* __restrict__ s,
             const float* __restrict__ z,
             const float* __restrict__ x,
             float* __restrict__ out)
{
    const int node = blockIdx.x * 2 + (threadIdx.x >> 6);
    const int lane = threadIdx.x & 63;
    const int g = lane >> 3;
    const int d0b = lane * 8;

    const float invz = 1.0f / (z[(size_t)node * 8 + g] + 1e-6f);
    const char* qb = (const char*)qkv;

    float acc[8] = {0.f, 0.f, 0.f, 0.f, 0.f, 0.f, 0.f, 0.f};
    const int start = row_ptr[node];
    const int end   = row_ptr[node + 1];

    int e = start;
    for (; e + 4 <= end; e += 4) {
        const int s0 = col[e], s1 = col[e + 1], s2 = col[e + 2], s3 = col[e + 3];
        const float scv0 = s[(size_t)e * 8 + g] * vscale[s0];
        const float scv1 = s[(size_t)(e + 1) * 8 + g] * vscale[s1];
        const float scv2 = s[(size_t)(e + 2) * 8 + g] * vscale[s2];
        const float scv3 = s[(size_t)(e + 3) * 8 + g] * vscale[s3];
        const uint2 v0 = *(const uint2*)(qb + (size_t)s0 * ROW_BYTES + 2048 + d0b);
        const uint2 v1 = *(const uint2*)(qb + (size_t)s1 * ROW_BYTES + 2048 + d0b);
        const uint2 v2 = *(const uint2*)(qb + (size_t)s2 * ROW_BYTES + 2048 + d0b);
        const uint2 v3 = *(const uint2*)(qb + (size_t)s3 * ROW_BYTES + 2048 + d0b);
        const signed char* c0 = (const signed char*)&v0;
        const signed char* c1 = (const signed char*)&v1;
        const signed char* c2 = (const signed char*)&v2;
        const signed char* c3 = (const signed char*)&v3;
        #pragma unroll
        for (int j = 0; j < 8; ++j) {
            float a = acc[j];
            a = fmaf(scv0, (float)c0[j], a);
            a = fmaf(scv1, (float)c1[j], a);
            a = fmaf(scv2, (float)c2[j], a);
            a = fmaf(scv3, (float)c3[j], a);
            acc[j] = a;
        }
    }
    for (; e < end; ++e) {
        const int s0 = col[e];
        const float scv0 = s[(size_t)e * 8 + g] * vscale[s0];
        const uint2 v0 = *(const uint2*)(qb + (size_t)s0 * ROW_BYTES + 2048 + d0b);
        const signed char* c0 = (const signed char*)&v0;
        #pragma unroll
        for (int j = 0; j < 8; ++j) acc[j] = fmaf(scv0, (float)c0[j], acc[j]);
    }

    const float* xr = x + (size_t)node * 512 + lane * 8;
    float xv[8];
    #pragma unroll
    for (int j = 0; j < 8; ++j) xv[j] = __builtin_nontemporal_load(xr + j);
    float* orow = out + (size_t)node * 512 + lane * 8;
    #pragma unroll
    for (int j = 0; j < 8; ++j)
        __builtin_nontemporal_store(xv[j] + acc[j] * invz, orow + j);
}

// ---------------------------------------------------------------------------
// K3: BN column stats over final h (in d_out). thread=col, 80 rows/block.
// ---------------------------------------------------------------------------
__global__ __launch_bounds__(512)
void stats_pass(const float* __restrict__ hbuf, float* __restrict__ stats)
{
    const int c  = threadIdx.x;
    const int r0 = blockIdx.x * 80;
    float sum = 0.f, sq = 0.f;
    for (int i = 0; i < 80; ++i) {
        const float hv = hbuf[(size_t)(r0 + i) * 512 + c];
        sum += hv; sq += hv * hv;
    }
    atomicAdd(&stats[c], sum);
    atomicAdd(&stats[512 + c], sq);
}

// ---------------------------------------------------------------------------
// K4: BatchNorm normalize in place. float4/thread, 20000 blocks exact.
// ---------------------------------------------------------------------------
__global__ __launch_bounds__(256)
void bn_norm(float* __restrict__ hbuf,
             const float* __restrict__ stats,
             const float* __restrict__ gamma,
             const float* __restrict__ beta)
{
    const size_t i4 = ((size_t)blockIdx.x * 256 + threadIdx.x) * 4;
    const int c = (int)(i4 & 511);
    const float invN = 1.0f / 40000.0f;
    float4 h = *(float4*)&hbuf[i4];
    float hv[4] = {h.x, h.y, h.z, h.w};
    float o[4];
    #pragma unroll
    for (int j = 0; j < 4; ++j) {
        const float mean = stats[c + j] * invN;
        const float var  = stats[512 + c + j] * invN - mean * mean;
        o[j] = (hv[j] - mean) * rsqrtf(var + 1e-5f) * gamma[c + j] + beta[c + j];
    }
    float4 out = {o[0], o[1], o[2], o[3]};
    *(float4*)&hbuf[i4] = out;
}

extern "C" void kernel_launch(void* const* d_in, const int* in_sizes, int n_in,
                              void* d_out, int out_size, void* d_ws, size_t ws_size,
                              hipStream_t stream)
{
    const float* x     = (const float*)d_in[0];
    const int*   ei    = (const int*)d_in[1];
    // d_in[2] virt_h, d_in[3] virt_edge_index unused (use_virt_nodes=False)
    const float* Wq    = (const float*)d_in[4];
    const float* Wk    = (const float*)d_in[5];
    const float* Wv    = (const float*)d_in[6];
    const float* gamma = (const float*)d_in[7];
    const float* beta  = (const float*)d_in[8];
    float* out = (float*)d_out;

    char* ws = (char*)d_ws;
    unsigned short* qkv    = (unsigned short*)ws;                  // 123,076,608 (M_PAD rows)
    unsigned short* xb     = (unsigned short*)(ws + 123076608);    //  41,025,536 (M_PAD rows)
    unsigned short* Wt     = (unsigned short*)(ws + 164102144);    //   1,572,864
    int*            counts = (int*)           (ws + 165675008);    //     160,000
    int*            cursor = (int*)           (ws + 165835008);    //     160,000
    int*            row_ptr= (int*)           (ws + 165995008);    //     160,016
    unsigned short* col    = (unsigned short*)(ws + 166155024);    //   1,280,032
    float*          stats  = (float*)         (ws + 167435056);    //       4,096
    // s, z, kscale, vscale ALIAS the xb region (dead after qkv_gemm_mfma):
    float* s      = (float*)(ws + 123076608);               // 20,480,000 B
    float* z      = (float*)(ws + 123076608 + 24000000);    //  1,280,000 B
    float* kscale = (float*)(ws + 123076608 + 26000000);    //    160,000 B
    float* vscale = (float*)(ws + 123076608 + 26160000);    //    160,000 B
    // total ws use: 167,439,152 B (unchanged)

    hipMemsetAsync(counts, 0, 160000, stream);
    hipMemsetAsync(cursor, 0, 160000, stream);
    hipMemsetAsync(stats,  0, 4096,   stream);
    hipMemsetAsync(xb + (size_t)N_NODES * 512, 0, (size_t)(M_PAD - N_NODES) * 512 * 2, stream);

    cast_x<<<10000, 256, 0, stream>>>(x, xb);
    cast_wt<<<dim3(16, 16, 3), 256, 0, stream>>>(Wq, Wk, Wv, Wt);
    csr_hist<<<2500, 256, 0, stream>>>(ei, counts);
    csr_scan<<<1, 1024, 0, stream>>>(counts, row_ptr);
    csr_scatter<<<2500, 256, 0, stream>>>(ei, row_ptr, cursor, col);
    qkv_gemm_mfma<<<3756, 256, 0, stream>>>(xb, Wt, qkv);
    quant_kv<<<10000, 256, 0, stream>>>(qkv, kscale, vscale);
    score_pass<<<20000, 128, 0, stream>>>(qkv, kscale, row_ptr, col, s, z);
    pv_pass<<<20000, 128, 0, stream>>>(qkv, vscale, row_ptr, col, s, z, x, out);
    stats_pass<<<500, 512, 0, stream>>>(out, stats);
    bn_norm<<<20000, 256, 0, stream>>>(out, stats, gamma, beta);
}

// Round 16
// 442.641 us; speedup vs baseline: 3.4970x; 1.0076x over previous
//
#include <hip/hip_runtime.h>
#include <hip/hip_bf16.h>

#define N_NODES 40000
#define M_PAD   40064            // 313 * 128
#define N_EDGES 640000
#define DIM_H 512
#define QKV_STRIDE 1536          // Q | K | V concatenated per node row (u16 units)
#define ROW_BYTES 3072

typedef __attribute__((ext_vector_type(8))) short bf16x8_t;  // 8 bf16 = 4 VGPR
typedef __attribute__((ext_vector_type(4))) float f32x4_t;   // MFMA acc
typedef __attribute__((ext_vector_type(8))) unsigned short u16x8_t;

static __device__ __forceinline__ unsigned short f2bf(float f) {
    __hip_bfloat16 h = __float2bfloat16(f);
    return *reinterpret_cast<unsigned short*>(&h);
}
static __device__ __forceinline__ float bf2f(unsigned short u) {
    return __uint_as_float(((unsigned)u) << 16);
}
// async global->LDS, 16B per lane (linear LDS dest = uniform base + lane*16).
static __device__ __forceinline__ void gll16(const void* g, void* l) {
    __builtin_amdgcn_global_load_lds(
        (const __attribute__((address_space(1))) unsigned int*)g,
        (__attribute__((address_space(3))) unsigned int*)l, 16, 0, 0);
}

// ---------------------------------------------------------------------------
// K0a: cast x (f32) -> xb (bf16). 8 elems/thread. 10000 blocks exact.
// ---------------------------------------------------------------------------
__global__ __launch_bounds__(256)
void cast_x(const float* __restrict__ x, unsigned short* __restrict__ xb)
{
    const size_t i = ((size_t)blockIdx.x * 256 + threadIdx.x) * 8;
    const float4 v0 = *(const float4*)&x[i];
    const float4 v1 = *(const float4*)&x[i + 4];
    u16x8_t o;
    o[0] = f2bf(v0.x); o[1] = f2bf(v0.y); o[2] = f2bf(v0.z); o[3] = f2bf(v0.w);
    o[4] = f2bf(v1.x); o[5] = f2bf(v1.y); o[6] = f2bf(v1.z); o[7] = f2bf(v1.w);
    *(u16x8_t*)&xb[i] = o;
}

// ---------------------------------------------------------------------------
// K0b: cast+transpose W[k][n] -> Wt[m][n][k] (bf16). grid (16,16,3).
// ---------------------------------------------------------------------------
__global__ __launch_bounds__(256)
void cast_wt(const float* __restrict__ Wq,
             const float* __restrict__ Wk,
             const float* __restrict__ Wv,
             unsigned short* __restrict__ Wt)
{
    __shared__ float tile[32][33];
    const float* W = (blockIdx.z == 0) ? Wq : (blockIdx.z == 1) ? Wk : Wv;
    unsigned short* Wo = Wt + (size_t)blockIdx.z * 512 * 512;
    const int k0 = blockIdx.x * 32, n0 = blockIdx.y * 32;
    const int tx = threadIdx.x & 31, ty0 = threadIdx.x >> 5;
    #pragma unroll
    for (int p = 0; p < 4; ++p) {
        const int r = ty0 + p * 8;
        tile[r][tx] = W[(size_t)(k0 + r) * 512 + n0 + tx];
    }
    __syncthreads();
    #pragma unroll
    for (int p = 0; p < 4; ++p) {
        const int r = ty0 + p * 8;
        Wo[(size_t)(n0 + r) * 512 + k0 + tx] = f2bf(tile[tx][r]);
    }
}

// ---------------------------------------------------------------------------
// K1: QKV GEMM (r13/r15 version — proven 91us, MfmaUtil 29%, 0 conflicts).
// 128x128 tile, BK=32, 4 waves, chunk-swizzled staging, XCD-bijective remap.
// ---------------------------------------------------------------------------
__global__ __launch_bounds__(256)
void qkv_gemm_mfma(const unsigned short* __restrict__ xb,
                   const unsigned short* __restrict__ Wt,
                   unsigned short* __restrict__ qkv)
{
    __shared__ short Asub[128 * 32];
    __shared__ short Bsub[128 * 32];

    const int orig = blockIdx.x;             // 0..3755
    const int q = 469, rmod = 4;             // 3756 = 8*469 + 4
    const int xcd = orig & 7;
    const int sub = orig >> 3;
    const int wg = (xcd < rmod ? xcd * (q + 1) : rmod * (q + 1) + (xcd - rmod) * q) + sub;
    const int n0g = (wg % 12) * 128;
    const int m0  = (wg / 12) * 128;

    const int wsel = n0g >> 9;
    const int nc0  = n0g & 511;
    const int tid = threadIdx.x;
    const int l = tid & 63;
    const int w = tid >> 6;
    const int wr = w >> 1, wc = w & 1;
    const int lr = l & 15;
    const int lk = (l >> 4) * 8;             // chunk index = lk>>3 in {0..3}

    const int idx0 = tid, idx1 = 256 + tid;
    const int ar0 = idx0 >> 2, ac0 = (((idx0 & 3) ^ ((idx0 >> 3) & 3))) * 8;
    const int ar1 = idx1 >> 2, ac1 = (((idx1 & 3) ^ ((idx1 >> 3) & 3))) * 8;

    const unsigned short* Abase = xb + (size_t)m0 * 512;
    const unsigned short* Bbase = Wt + (size_t)wsel * 262144 + (size_t)nc0 * 512;

    f32x4_t acc[4][4];
    #pragma unroll
    for (int i = 0; i < 4; ++i)
        #pragma unroll
        for (int j = 0; j < 4; ++j)
            acc[i][j] = {0.f, 0.f, 0.f, 0.f};

    for (int k0 = 0; k0 < 512; k0 += 32) {
        gll16(Abase + (size_t)ar0 * 512 + k0 + ac0, &Asub[idx0 * 8]);
        gll16(Abase + (size_t)ar1 * 512 + k0 + ac1, &Asub[idx1 * 8]);
        gll16(Bbase + (size_t)ar0 * 512 + k0 + ac0, &Bsub[idx0 * 8]);
        gll16(Bbase + (size_t)ar1 * 512 + k0 + ac1, &Bsub[idx1 * 8]);
        __syncthreads();
        bf16x8_t a[4], b[4];
        #pragma unroll
        for (int fm = 0; fm < 4; ++fm) {
            const int Ra = wr * 64 + fm * 16 + lr;
            const int pa = (((lk >> 3) ^ ((Ra >> 1) & 3))) << 3;
            a[fm] = *(const bf16x8_t*)&Asub[Ra * 32 + pa];
        }
        #pragma unroll
        for (int fn = 0; fn < 4; ++fn) {
            const int Rb = wc * 64 + fn * 16 + lr;
            const int pb = (((lk >> 3) ^ ((Rb >> 1) & 3))) << 3;
            b[fn] = *(const bf16x8_t*)&Bsub[Rb * 32 + pb];
        }
        #pragma unroll
        for (int fm = 0; fm < 4; ++fm)
            #pragma unroll
            for (int fn = 0; fn < 4; ++fn)
                acc[fm][fn] = __builtin_amdgcn_mfma_f32_16x16x32_bf16(
                                  a[fm], b[fn], acc[fm][fn], 0, 0, 0);
        __syncthreads();
    }

    #pragma unroll
    for (int fm = 0; fm < 4; ++fm)
        #pragma unroll
        for (int fn = 0; fn < 4; ++fn)
            #pragma unroll
            for (int j = 0; j < 4; ++j) {
                const int row = m0 + wr * 64 + fm * 16 + (l >> 4) * 4 + j;
                const int col = n0g + wc * 64 + fn * 16 + lr;
                qkv[(size_t)row * QKV_STRIDE + col] = f2bf(acc[fm][fn][j]);
            }
}

// ---------------------------------------------------------------------------
// CSR build (by dst).
// ---------------------------------------------------------------------------
__global__ __launch_bounds__(256)
void csr_hist(const int* __restrict__ ei, int* __restrict__ counts)
{
    const int e = blockIdx.x * 256 + threadIdx.x;   // 2500 blocks exact
    atomicAdd(&counts[ei[N_EDGES + e]], 1);
}

__global__ __launch_bounds__(1024)
void csr_scan(const int* __restrict__ counts, int* __restrict__ row_ptr)
{
    __shared__ int part[1024];
    const int t = threadIdx.x;
    const int base = t * 40;
    int s = 0;
    for (int i = 0; i < 40; ++i) {
        const int idx = base + i;
        if (idx < N_NODES) s += counts[idx];
    }
    part[t] = s;
    __syncthreads();
    for (int off = 1; off < 1024; off <<= 1) {
        int v = (t >= off) ? part[t - off] : 0;
        __syncthreads();
        part[t] += v;
        __syncthreads();
    }
    int run = (t == 0) ? 0 : part[t - 1];
    for (int i = 0; i < 40; ++i) {
        const int idx = base + i;
        if (idx < N_NODES) { row_ptr[idx] = run; run += counts[idx]; }
    }
    if (t == 0) row_ptr[N_NODES] = part[1023];
}

__global__ __launch_bounds__(256)
void csr_scatter(const int* __restrict__ ei, const int* __restrict__ row_ptr,
                 int* __restrict__ cursor, unsigned short* __restrict__ col)
{
    const int e = blockIdx.x * 256 + threadIdx.x;   // 2500 blocks exact
    const int dst = ei[N_EDGES + e];
    const int pos = atomicAdd(&cursor[dst], 1);
    col[row_ptr[dst] + pos] = (unsigned short)ei[e];
}

// ---------------------------------------------------------------------------
// KQ: in-place int8 quantization of K and V (per-row scale). One wave/node.
// K8 row (512B) at bytes [1024,1536); V8 at [2048,2560).
// ---------------------------------------------------------------------------
__global__ __launch_bounds__(256)
void quant_kv(unsigned short* __restrict__ qkv,
              float* __restrict__ kscale, float* __restrict__ vscale)
{
    const int node = blockIdx.x * 4 + (threadIdx.x >> 6);
    const int lane = threadIdx.x & 63;
    unsigned short* row = qkv + (size_t)node * QKV_STRIDE;

    const u16x8_t kk = *(const u16x8_t*)(row + 512 + lane * 8);
    const u16x8_t vv = *(const u16x8_t*)(row + 1024 + lane * 8);
    float kf[8], vf[8];
    float kamax = 0.f, vamax = 0.f;
    #pragma unroll
    for (int j = 0; j < 8; ++j) {
        kf[j] = bf2f(kk[j]); kamax = fmaxf(kamax, fabsf(kf[j]));
        vf[j] = bf2f(vv[j]); vamax = fmaxf(vamax, fabsf(vf[j]));
    }
    #pragma unroll
    for (int off = 1; off < 64; off <<= 1) {
        kamax = fmaxf(kamax, __shfl_xor(kamax, off, 64));
        vamax = fmaxf(vamax, __shfl_xor(vamax, off, 64));
    }
    const float kinv = (kamax > 0.f) ? 127.0f / kamax : 0.f;
    const float vinv = (vamax > 0.f) ? 127.0f / vamax : 0.f;

    unsigned int klo = 0, khi = 0, vlo = 0, vhi = 0;
    #pragma unroll
    for (int j = 0; j < 4; ++j) {
        const int kq = (int)rintf(kf[j] * kinv);
        const int vq = (int)rintf(vf[j] * vinv);
        klo |= ((unsigned)(unsigned char)(signed char)kq) << (8 * j);
        vlo |= ((unsigned)(unsigned char)(signed char)vq) << (8 * j);
    }
    #pragma unroll
    for (int j = 4; j < 8; ++j) {
        const int kq = (int)rintf(kf[j] * kinv);
        const int vq = (int)rintf(vf[j] * vinv);
        khi |= ((unsigned)(unsigned char)(signed char)kq) << (8 * (j - 4));
        vhi |= ((unsigned)(unsigned char)(signed char)vq) << (8 * (j - 4));
    }
    uint2 kp; kp.x = klo; kp.y = khi;
    uint2 vp; vp.x = vlo; vp.y = vhi;
    char* rowb = (char*)row;
    *(uint2*)(rowb + 1024 + lane * 8) = kp;
    *(uint2*)(rowb + 2048 + lane * 8) = vp;
    if (lane == 0) {
        kscale[node] = kamax * (1.0f / 127.0f);
        vscale[node] = vamax * (1.0f / 127.0f);
    }
}

// ---------------------------------------------------------------------------
// K2: FUSED edge pass (r16: score+pv re-fused; valid now that int8 shrank the
// gather set to 41MB << L3 — r10's bf16 thrash at 244MB no longer applies).
// One wave per dst node (2-wave blocks). Per edge: K8 dot, head-group reduce,
// exp(clip) (all 8 lanes of the group hold the score -> no z round-trip),
// accumulate sc*vscale*V8 and zsum. Saves s/z traffic (41MB), Q re-read
// (41MB), col re-read, and one pass's latency exposure.
// Accumulation order identical to the split pair -> bit-identical output.
// ---------------------------------------------------------------------------
__global__ __launch_bounds__(128)
void edge_fused(const unsigned short* __restrict__ qkv,
                const float* __restrict__ kscale,
                const float* __restrict__ vscale,
                const int* __restrict__ row_ptr,
                const unsigned short* __restrict__ col,
                const float* __restrict__ x,
                float* __restrict__ out)
{
    const int node = blockIdx.x * 2 + (threadIdx.x >> 6);
    const int lane = threadIdx.x & 63;
    const int d0b = lane * 8;

    const u16x8_t q8 = *(const u16x8_t*)(qkv + (size_t)node * QKV_STRIDE + lane * 8);
    float q[8];
    #pragma unroll
    for (int j = 0; j < 8; ++j) q[j] = bf2f(q8[j]);

    const char* qb = (const char*)qkv;
    float acc[8] = {0.f, 0.f, 0.f, 0.f, 0.f, 0.f, 0.f, 0.f};
    float zsum = 0.f;
    const int start = row_ptr[node];
    const int end   = row_ptr[node + 1];

    int e = start;
    for (; e + 4 <= end; e += 4) {
        const int s0 = col[e], s1 = col[e + 1], s2 = col[e + 2], s3 = col[e + 3];
        const uint2 k0 = *(const uint2*)(qb + (size_t)s0 * ROW_BYTES + 1024 + d0b);
        const uint2 k1 = *(const uint2*)(qb + (size_t)s1 * ROW_BYTES + 1024 + d0b);
        const uint2 k2 = *(const uint2*)(qb + (size_t)s2 * ROW_BYTES + 1024 + d0b);
        const uint2 k3 = *(const uint2*)(qb + (size_t)s3 * ROW_BYTES + 1024 + d0b);
        const uint2 v0 = *(const uint2*)(qb + (size_t)s0 * ROW_BYTES + 2048 + d0b);
        const uint2 v1 = *(const uint2*)(qb + (size_t)s1 * ROW_BYTES + 2048 + d0b);
        const uint2 v2 = *(const uint2*)(qb + (size_t)s2 * ROW_BYTES + 2048 + d0b);
        const uint2 v3 = *(const uint2*)(qb + (size_t)s3 * ROW_BYTES + 2048 + d0b);
        const signed char* ck0 = (const signed char*)&k0;
        const signed char* ck1 = (const signed char*)&k1;
        const signed char* ck2 = (const signed char*)&k2;
        const signed char* ck3 = (const signed char*)&k3;
        float p0 = 0.f, p1 = 0.f, p2 = 0.f, p3 = 0.f;
        #pragma unroll
        for (int j = 0; j < 8; ++j) {
            p0 = fmaf((float)ck0[j], q[j], p0);
            p1 = fmaf((float)ck1[j], q[j], p1);
            p2 = fmaf((float)ck2[j], q[j], p2);
            p3 = fmaf((float)ck3[j], q[j], p3);
        }
        p0 += __shfl_xor(p0, 1, 64); p0 += __shfl_xor(p0, 2, 64); p0 += __shfl_xor(p0, 4, 64);
        p1 += __shfl_xor(p1, 1, 64); p1 += __shfl_xor(p1, 2, 64); p1 += __shfl_xor(p1, 4, 64);
        p2 += __shfl_xor(p2, 1, 64); p2 += __shfl_xor(p2, 2, 64); p2 += __shfl_xor(p2, 4, 64);
        p3 += __shfl_xor(p3, 1, 64); p3 += __shfl_xor(p3, 2, 64); p3 += __shfl_xor(p3, 4, 64);
        const float sc0 = __expf(fminf(fmaxf(p0 * kscale[s0] * 0.125f, -5.f), 5.f));
        const float sc1 = __expf(fminf(fmaxf(p1 * kscale[s1] * 0.125f, -5.f), 5.f));
        const float sc2 = __expf(fminf(fmaxf(p2 * kscale[s2] * 0.125f, -5.f), 5.f));
        const float sc3 = __expf(fminf(fmaxf(p3 * kscale[s3] * 0.125f, -5.f), 5.f));
        zsum += (sc0 + sc1) + (sc2 + sc3);
        const float scv0 = sc0 * vscale[s0];
        const float scv1 = sc1 * vscale[s1];
        const float scv2 = sc2 * vscale[s2];
        const float scv3 = sc3 * vscale[s3];
        const signed char* cv0 = (const signed char*)&v0;
        const signed char* cv1 = (const signed char*)&v1;
        const signed char* cv2 = (const signed char*)&v2;
        const signed char* cv3 = (const signed char*)&v3;
        #pragma unroll
        for (int j = 0; j < 8; ++j) {
            float a = acc[j];
            a = fmaf(scv0, (float)cv0[j], a);
            a = fmaf(scv1, (float)cv1[j], a);
            a = fmaf(scv2, (float)cv2[j], a);
            a = fmaf(scv3, (float)cv3[j], a);
            acc[j] = a;
        }
    }
    for (; e < end; ++e) {
        const int s0 = col[e];
        const uint2 k0 = *(const uint2*)(qb + (size_t)s0 * ROW_BYTES + 1024 + d0b);
        const uint2 v0 = *(const uint2*)(qb + (size_t)s0 * ROW_BYTES + 2048 + d0b);
        const signed char* ck0 = (const signed char*)&k0;
        float p0 = 0.f;
        #pragma unroll
        for (int j = 0; j < 8; ++j) p0 = fmaf((float)ck0[j], q[j], p0);
        p0 += __shfl_xor(p0, 1, 64); p0 += __shfl_xor(p0, 2, 64); p0 += __shfl_xor(p0, 4, 64);
        const float sc0 = __expf(fminf(fmaxf(p0 * kscale[s0] * 0.125f, -5.f), 5.f));
        zsum += sc0;
        const float scv0 = sc0 * vscale[s0];
        const signed char* cv0 = (const signed char*)&v0;
        #pragma unroll
        for (int j = 0; j < 8; ++j) acc[j] = fmaf(scv0, (float)cv0[j], acc[j]);
    }

    const float invz = 1.0f / (zsum + 1e-6f);
    const float* xr = x + (size_t)node * 512 + lane * 8;
    float xv[8];
    #pragma unroll
    for (int j = 0; j < 8; ++j) xv[j] = __builtin_nontemporal_load(xr + j);
    float* orow = out + (size_t)node * 512 + lane * 8;
    #pragma unroll
    for (int j = 0; j < 8; ++j)
        __builtin_nontemporal_store(xv[j] + acc[j] * invz, orow + j);
}

// ---------------------------------------------------------------------------
// K3: BN column stats over final h (in d_out). thread=col, 80 rows/block.
// ---------------------------------------------------------------------------
__global__ __launch_bounds__(512)
void stats_pass(const float* __restrict__ hbuf, float* __restrict__ stats)
{
    const int c  = threadIdx.x;
    const int r0 = blockIdx.x * 80;
    float sum = 0.f, sq = 0.f;
    for (int i = 0; i < 80; ++i) {
        const float hv = hbuf[(size_t)(r0 + i) * 512 + c];
        sum += hv; sq += hv * hv;
    }
    atomicAdd(&stats[c], sum);
    atomicAdd(&stats[512 + c], sq);
}

// ---------------------------------------------------------------------------
// K4: BatchNorm normalize in place. float4/thread, 20000 blocks exact.
// ---------------------------------------------------------------------------
__global__ __launch_bounds__(256)
void bn_norm(float* __restrict__ hbuf,
             const float* __restrict__ stats,
             const float* __restrict__ gamma,
             const float* __restrict__ beta)
{
    const size_t i4 = ((size_t)blockIdx.x * 256 + threadIdx.x) * 4;
    const int c = (int)(i4 & 511);
    const float invN = 1.0f / 40000.0f;
    float4 h = *(float4*)&hbuf[i4];
    float hv[4] = {h.x, h.y, h.z, h.w};
    float o[4];
    #pragma unroll
    for (int j = 0; j < 4; ++j) {
        const float mean = stats[c + j] * invN;
        const float var  = stats[512 + c + j] * invN - mean * mean;
        o[j] = (hv[j] - mean) * rsqrtf(var + 1e-5f) * gamma[c + j] + beta[c + j];
    }
    float4 out = {o[0], o[1], o[2], o[3]};
    *(float4*)&hbuf[i4] = out;
}

extern "C" void kernel_launch(void* const* d_in, const int* in_sizes, int n_in,
                              void* d_out, int out_size, void* d_ws, size_t ws_size,
                              hipStream_t stream)
{
    const float* x     = (const float*)d_in[0];
    const int*   ei    = (const int*)d_in[1];
    // d_in[2] virt_h, d_in[3] virt_edge_index unused (use_virt_nodes=False)
    const float* Wq    = (const float*)d_in[4];
    const float* Wk    = (const float*)d_in[5];
    const float* Wv    = (const float*)d_in[6];
    const float* gamma = (const float*)d_in[7];
    const float* beta  = (const float*)d_in[8];
    float* out = (float*)d_out;

    char* ws = (char*)d_ws;
    unsigned short* qkv    = (unsigned short*)ws;                  // 123,076,608 (M_PAD rows)
    unsigned short* xb     = (unsigned short*)(ws + 123076608);    //  41,025,536 (M_PAD rows)
    unsigned short* Wt     = (unsigned short*)(ws + 164102144);    //   1,572,864
    int*            counts = (int*)           (ws + 165675008);    //     160,000
    int*            cursor = (int*)           (ws + 165835008);    //     160,000
    int*            row_ptr= (int*)           (ws + 165995008);    //     160,016
    unsigned short* col    = (unsigned short*)(ws + 166155024);    //   1,280,032
    float*          stats  = (float*)         (ws + 167435056);    //       4,096
    // kscale, vscale ALIAS the xb region (dead after qkv_gemm_mfma):
    float* kscale = (float*)(ws + 123076608 + 26000000);    //    160,000 B
    float* vscale = (float*)(ws + 123076608 + 26160000);    //    160,000 B
    // total ws use: 167,439,152 B (unchanged)

    hipMemsetAsync(counts, 0, 160000, stream);
    hipMemsetAsync(cursor, 0, 160000, stream);
    hipMemsetAsync(stats,  0, 4096,   stream);
    hipMemsetAsync(xb + (size_t)N_NODES * 512, 0, (size_t)(M_PAD - N_NODES) * 512 * 2, stream);

    cast_x<<<10000, 256, 0, stream>>>(x, xb);
    cast_wt<<<dim3(16, 16, 3), 256, 0, stream>>>(Wq, Wk, Wv, Wt);
    csr_hist<<<2500, 256, 0, stream>>>(ei, counts);
    csr_scan<<<1, 1024, 0, stream>>>(counts, row_ptr);
    csr_scatter<<<2500, 256, 0, stream>>>(ei, row_ptr, cursor, col);
    qkv_gemm_mfma<<<3756, 256, 0, stream>>>(xb, Wt, qkv);
    quant_kv<<<10000, 256, 0, stream>>>(qkv, kscale, vscale);
    edge_fused<<<20000, 128, 0, stream>>>(qkv, kscale, vscale, row_ptr, col, x, out);
    stats_pass<<<500, 512, 0, stream>>>(out, stats);
    bn_norm<<<20000, 256, 0, stream>>>(out, stats, gamma, beta);
}